// Round 10
// baseline (580.443 us; speedup 1.0000x reference)
//
#include <hip/hip_runtime.h>
#include <math.h>

#define HW 16384

typedef __attribute__((ext_vector_type(8))) short bf16x8;
typedef __attribute__((ext_vector_type(4))) float f32x4;

__device__ __forceinline__ unsigned f2bf_pk(float a, float b)
{
    unsigned ua = __float_as_uint(a), ub = __float_as_uint(b);
    ua = (ua + 0x7FFFu + ((ua >> 16) & 1u)) >> 16;   // RTN-even
    ub = (ub + 0x7FFFu + ((ub >> 16) & 1u)) >> 16;
    return (ua & 0xFFFFu) | (ub << 16);
}
__device__ __forceinline__ unsigned short f2bf(float a)
{
    unsigned ua = __float_as_uint(a);
    ua = (ua + 0x7FFFu + ((ua >> 16) & 1u)) >> 16;
    return (unsigned short)ua;
}
__device__ __forceinline__ float bf2f(unsigned short u)
{
    return __uint_as_float(((unsigned)u) << 16);
}
__device__ __forceinline__ int brev7(int v) { return (int)(__brev((unsigned)v) >> 25); }
__device__ __forceinline__ float sigmoidf_(float v) { return 1.f / (1.f + expf(-v)); }

// ---------------------------------------------------------------------------
// wprep: convert 7 weight matrices (128x128 fp32) to bf16 in pre-swizzled
// LDS chunk order: slot s holds rows o=s>>4, cols c16*8.. where
// c16 = (s&15) ^ (o&7). grid 56 (m = blk>>3, part = blk&7), block 256.
// ---------------------------------------------------------------------------
__global__ __launch_bounds__(256)
void wprep_k(const float* __restrict__ w0, const float* __restrict__ w1,
             const float* __restrict__ w2, const float* __restrict__ w3,
             const float* __restrict__ w4, const float* __restrict__ w5,
             const float* __restrict__ w6, int4* __restrict__ Wbf4)
{
    int m = blockIdx.x >> 3;
    int slot = (blockIdx.x & 7) * 256 + threadIdx.x;   // 0..2047
    const float* src;
    switch (m) {
        case 0: src = w0; break;
        case 1: src = w1; break;
        case 2: src = w2; break;
        case 3: src = w3; break;
        case 4: src = w4; break;
        case 5: src = w5; break;
        default: src = w6; break;
    }
    int o = slot >> 4;
    int c16 = (slot & 15) ^ (o & 7);
    const float* p = src + o * 128 + c16 * 8;
    int4 pk;
    pk.x = f2bf_pk(p[0], p[1]); pk.y = f2bf_pk(p[2], p[3]);
    pk.z = f2bf_pk(p[4], p[5]); pk.w = f2bf_pk(p[6], p[7]);
    Wbf4[m * 2048 + slot] = pk;
}

// ---------------------------------------------------------------------------
// MFMA conv1x1, fp32 in -> bf16 out, pre-swizzled bf16 weights.
// Tile O=128 x N=64, K=128.
// ---------------------------------------------------------------------------
__global__ __launch_bounds__(256)
void conv_mfma_k(const float* __restrict__ in, const int4* __restrict__ wbf,
                 unsigned short* __restrict__ out)
{
    __shared__ short WL[128 * 128];   // 32 KB
    __shared__ short XL[64 * 128];    // 16 KB
    int t = threadIdx.x;
    int gb = blockIdx.x;
    int b = gb >> 8;
    int n0 = (gb & 255) << 6;

    #pragma unroll
    for (int it = 0; it < 8; ++it)
        ((int4*)WL)[it * 256 + t] = wbf[it * 256 + t];

    const float* inb = in + (size_t)b * 128 * HW + n0;
    int nl = t & 63;
    #pragma unroll
    for (int it = 0; it < 4; ++it) {
        int c8 = (t >> 6) + it * 4;
        float v[8];
        #pragma unroll
        for (int j = 0; j < 8; ++j) v[j] = inb[(size_t)(c8 * 8 + j) * HW + nl];
        int4 p;
        p.x = f2bf_pk(v[0], v[1]); p.y = f2bf_pk(v[2], v[3]);
        p.z = f2bf_pk(v[4], v[5]); p.w = f2bf_pk(v[6], v[7]);
        ((int4*)XL)[nl * 16 + (c8 ^ (nl & 7))] = p;
    }
    __syncthreads();

    int l = t & 63, w = t >> 6, kg = l >> 4, l15 = l & 15, l7 = l15 & 7;
    f32x4 acc[2][4];
    #pragma unroll
    for (int mf = 0; mf < 2; ++mf)
        #pragma unroll
        for (int nf = 0; nf < 4; ++nf) acc[mf][nf] = (f32x4){0.f, 0.f, 0.f, 0.f};
    #pragma unroll
    for (int ks = 0; ks < 4; ++ks) {
        int ch = ks * 4 + kg;
        bf16x8 A0 = ((const bf16x8*)WL)[(w * 32 + l15) * 16 + (ch ^ l7)];
        bf16x8 A1 = ((const bf16x8*)WL)[(w * 32 + 16 + l15) * 16 + (ch ^ l7)];
        #pragma unroll
        for (int nf = 0; nf < 4; ++nf) {
            bf16x8 Bf = ((const bf16x8*)XL)[(nf * 16 + l15) * 16 + (ch ^ l7)];
            acc[0][nf] = __builtin_amdgcn_mfma_f32_16x16x32_bf16(A0, Bf, acc[0][nf], 0, 0, 0);
            acc[1][nf] = __builtin_amdgcn_mfma_f32_16x16x32_bf16(A1, Bf, acc[1][nf], 0, 0, 0);
        }
    }
    #pragma unroll
    for (int mf = 0; mf < 2; ++mf)
        #pragma unroll
        for (int nf = 0; nf < 4; ++nf)
            #pragma unroll
            for (int i = 0; i < 4; ++i) {
                int row = w * 32 + mf * 16 + kg * 4 + i;
                int col = n0 + nf * 16 + l15;
                out[((size_t)b * 128 + row) * HW + col] = f2bf(acc[mf][nf][i]);
            }
}

// ---------------------------------------------------------------------------
// depthwise 3x3 SAME, x4 vectorized, bf16 in -> bf16 out
// ---------------------------------------------------------------------------
__global__ __launch_bounds__(256)
void dwconv_k(const unsigned short* __restrict__ V, const float* __restrict__ Wdw,
              unsigned short* __restrict__ vcb)
{
    int tid = blockIdx.x * 256 + threadIdx.x;
    int e4 = tid & 4095;
    int bc = tid >> 12;
    int c = bc & 127;
    int y = e4 >> 5;
    int x0 = (e4 & 31) << 2;
    const unsigned short* vin = V + (size_t)bc * HW;
    float wf[9];
    #pragma unroll
    for (int i = 0; i < 9; ++i) wf[i] = Wdw[c * 9 + i];
    float a0 = 0.f, a1 = 0.f, a2 = 0.f, a3 = 0.f;
    #pragma unroll
    for (int dy = 0; dy < 3; ++dy) {
        int yy = y + dy - 1;
        if (yy < 0 || yy > 127) continue;
        const unsigned short* r = vin + yy * 128;
        uint2 mu = *(const uint2*)(r + x0);
        float m0 = bf2f((unsigned short)(mu.x & 0xFFFF));
        float m1 = bf2f((unsigned short)(mu.x >> 16));
        float m2 = bf2f((unsigned short)(mu.y & 0xFFFF));
        float m3 = bf2f((unsigned short)(mu.y >> 16));
        float left  = (x0 > 0)   ? bf2f(r[x0 - 1]) : 0.f;
        float right = (x0 < 124) ? bf2f(r[x0 + 4]) : 0.f;
        float w0 = wf[dy * 3], w1 = wf[dy * 3 + 1], w2 = wf[dy * 3 + 2];
        a0 += w0 * left + w1 * m0 + w2 * m1;
        a1 += w0 * m0   + w1 * m1 + w2 * m2;
        a2 += w0 * m1   + w1 * m2 + w2 * m3;
        a3 += w0 * m2   + w1 * m3 + w2 * right;
    }
    uint2 r2;
    r2.x = f2bf_pk(a0, a1);
    r2.y = f2bf_pk(a2, a3);
    *(uint2*)(vcb + (size_t)bc * HW + y * 128 + x0) = r2;
}

// ---------------------------------------------------------------------------
// MFMA Gram partials: 32 slices of 512 px. blk = b*32+ks. grid 256.
// ---------------------------------------------------------------------------
__global__ __launch_bounds__(256)
void gram_mfma_k(const float* __restrict__ x, float* __restrict__ Gp)
{
    __shared__ short XL[128 * 128];
    int t = threadIdx.x;
    int blk = blockIdx.x;
    int b = blk >> 5, ks = blk & 31;
    const float* xb = x + (size_t)b * 128 * HW + ks * 512;
    int l = t & 63, w = t >> 6, kg = l >> 4, l15 = l & 15, l7 = l15 & 7;

    f32x4 acc[2][8];
    #pragma unroll
    for (int mf = 0; mf < 2; ++mf)
        #pragma unroll
        for (int nf = 0; nf < 8; ++nf) acc[mf][nf] = (f32x4){0.f, 0.f, 0.f, 0.f};

    for (int kc = 0; kc < 4; ++kc) {
        __syncthreads();
        #pragma unroll
        for (int it = 0; it < 8; ++it) {
            int g = it * 256 + t;
            int row = g >> 4, oct = g & 15;
            const float* p = xb + (size_t)row * HW + kc * 128 + oct * 8;
            int4 pk;
            pk.x = f2bf_pk(p[0], p[1]); pk.y = f2bf_pk(p[2], p[3]);
            pk.z = f2bf_pk(p[4], p[5]); pk.w = f2bf_pk(p[6], p[7]);
            ((int4*)XL)[row * 16 + (oct ^ (row & 7))] = pk;
        }
        __syncthreads();
        #pragma unroll
        for (int s = 0; s < 4; ++s) {
            int oct = s * 4 + kg;
            bf16x8 A0 = ((const bf16x8*)XL)[(w * 32 + l15) * 16 + (oct ^ l7)];
            bf16x8 A1 = ((const bf16x8*)XL)[(w * 32 + 16 + l15) * 16 + (oct ^ l7)];
            #pragma unroll
            for (int nf = 0; nf < 8; ++nf) {
                bf16x8 Bf = ((const bf16x8*)XL)[(nf * 16 + l15) * 16 + (oct ^ l7)];
                acc[0][nf] = __builtin_amdgcn_mfma_f32_16x16x32_bf16(A0, Bf, acc[0][nf], 0, 0, 0);
                acc[1][nf] = __builtin_amdgcn_mfma_f32_16x16x32_bf16(A1, Bf, acc[1][nf], 0, 0, 0);
            }
        }
    }
    float* gp = Gp + (size_t)blk * 16384;
    #pragma unroll
    for (int mf = 0; mf < 2; ++mf)
        #pragma unroll
        for (int nf = 0; nf < 8; ++nf)
            #pragma unroll
            for (int i = 0; i < 4; ++i) {
                int row = w * 32 + mf * 16 + kg * 4 + i;
                int col = nf * 16 + l15;
                gp[row * 128 + col] = acc[mf][nf][i];
            }
}

__global__ void gram_reduce_k(const float* __restrict__ Gp, float* __restrict__ G)
{
    int idx = blockIdx.x * 256 + threadIdx.x;   // 8*16384
    int b = idx >> 14;
    int ij = idx & 16383;
    const float* gp = Gp + (size_t)(b * 32) * 16384 + ij;
    float s = 0.f;
    #pragma unroll
    for (int ks = 0; ks < 32; ++ks) s += gp[(size_t)ks * 16384];
    G[idx] = s;
}

// ---------------------------------------------------------------------------
// S_h = softmax( (Wq_h G Wk_h^T) * scale[h] )
// ---------------------------------------------------------------------------
__global__ __launch_bounds__(256)
void attn_s2_k(const float* __restrict__ G, const float* __restrict__ Wqkv,
               const float* __restrict__ scale, float* __restrict__ S)
{
    __shared__ float Wq[16][129];
    __shared__ float Wk[16][129];
    __shared__ float Ts[16][129];
    int bh = blockIdx.x;
    int b = bh >> 3, h = bh & 7;
    int t = threadIdx.x;
    #pragma unroll
    for (int i = 0; i < 8; ++i) {
        int idx = t + i * 256;
        int r = idx >> 7, ci = idx & 127;
        Wq[r][ci] = Wqkv[(size_t)(h * 16 + r) * 128 + ci];
        Wk[r][ci] = Wqkv[(size_t)(128 + h * 16 + r) * 128 + ci];
    }
    __syncthreads();
    const float* Gb = G + (size_t)b * 16384;
    #pragma unroll
    for (int i = 0; i < 8; ++i) {
        int idx = t + i * 256;
        int c = idx >> 7, col = idx & 127;
        float s = 0.f;
        #pragma unroll 8
        for (int ci = 0; ci < 128; ++ci)
            s += Wq[c][ci] * Gb[ci * 128 + col];
        Ts[c][col] = s;
    }
    __syncthreads();
    int c = t >> 4, d = t & 15;
    float s = 0.f;
    #pragma unroll 8
    for (int col = 0; col < 128; ++col)
        s += Ts[c][col] * Wk[d][col];
    s *= scale[h];
    float m = s;
    #pragma unroll
    for (int w = 1; w < 16; w <<= 1)
        m = fmaxf(m, __shfl_xor(m, w, 64));
    float e = expf(s - m);
    float sum = e;
    #pragma unroll
    for (int w = 1; w < 16; w <<= 1)
        sum += __shfl_xor(sum, w, 64);
    S[(size_t)bh * 256 + t] = e / sum;
}

// ---------------------------------------------------------------------------
// proj_s with fused PV: out_s = W_proj_s @ (PV(V) + vconv), bf16 in/out.
// ---------------------------------------------------------------------------
__global__ __launch_bounds__(256)
void proj_s_pv_k(const unsigned short* __restrict__ V,
                 const unsigned short* __restrict__ vcb,
                 const float* __restrict__ S, const int4* __restrict__ wbf,
                 unsigned short* __restrict__ out_s)
{
    __shared__ short WL[128 * 128];   // 32 KB
    __shared__ short XL[64 * 128];    // 16 KB
    __shared__ float SL[2048];        // 8 KB
    int t = threadIdx.x;
    int gb = blockIdx.x;
    int b = gb >> 8;
    int n0 = (gb & 255) << 6;

    #pragma unroll
    for (int it = 0; it < 8; ++it)
        ((int4*)WL)[it * 256 + t] = wbf[it * 256 + t];
    #pragma unroll
    for (int i = 0; i < 8; ++i)
        SL[i * 256 + t] = S[(size_t)b * 2048 + i * 256 + t];
    __syncthreads();

    int col = t & 63, w = t >> 6;
    #pragma unroll
    for (int hh = 0; hh < 2; ++hh) {
        int h = w * 2 + hh;
        float v[16];
        #pragma unroll
        for (int d = 0; d < 16; ++d)
            v[d] = bf2f(V[((size_t)(b * 128 + h * 16 + d)) * HW + n0 + col]);
        float o[16];
        #pragma unroll
        for (int c = 0; c < 16; ++c) {
            const float* sl = SL + h * 256 + c * 16;
            float s = 0.f;
            #pragma unroll
            for (int d = 0; d < 16; ++d) s += sl[d] * v[d];
            o[c] = s + bf2f(vcb[((size_t)(b * 128 + h * 16 + c)) * HW + n0 + col]);
        }
        #pragma unroll
        for (int oc = 0; oc < 2; ++oc) {
            int octet = h * 2 + oc;
            int4 p;
            p.x = f2bf_pk(o[oc * 8 + 0], o[oc * 8 + 1]);
            p.y = f2bf_pk(o[oc * 8 + 2], o[oc * 8 + 3]);
            p.z = f2bf_pk(o[oc * 8 + 4], o[oc * 8 + 5]);
            p.w = f2bf_pk(o[oc * 8 + 6], o[oc * 8 + 7]);
            ((int4*)XL)[col * 16 + (octet ^ (col & 7))] = p;
        }
    }
    __syncthreads();

    int l = t & 63, kg = l >> 4, l15 = l & 15, l7 = l15 & 7;
    f32x4 acc[2][4];
    #pragma unroll
    for (int mf = 0; mf < 2; ++mf)
        #pragma unroll
        for (int nf = 0; nf < 4; ++nf) acc[mf][nf] = (f32x4){0.f, 0.f, 0.f, 0.f};
    #pragma unroll
    for (int ks = 0; ks < 4; ++ks) {
        int ch = ks * 4 + kg;
        bf16x8 A0 = ((const bf16x8*)WL)[(w * 32 + l15) * 16 + (ch ^ l7)];
        bf16x8 A1 = ((const bf16x8*)WL)[(w * 32 + 16 + l15) * 16 + (ch ^ l7)];
        #pragma unroll
        for (int nf = 0; nf < 4; ++nf) {
            bf16x8 Bf = ((const bf16x8*)XL)[(nf * 16 + l15) * 16 + (ch ^ l7)];
            acc[0][nf] = __builtin_amdgcn_mfma_f32_16x16x32_bf16(A0, Bf, acc[0][nf], 0, 0, 0);
            acc[1][nf] = __builtin_amdgcn_mfma_f32_16x16x32_bf16(A1, Bf, acc[1][nf], 0, 0, 0);
        }
    }
    #pragma unroll
    for (int mf = 0; mf < 2; ++mf)
        #pragma unroll
        for (int nf = 0; nf < 4; ++nf)
            #pragma unroll
            for (int i = 0; i < 4; ++i) {
                int row = w * 32 + mf * 16 + kg * 4 + i;
                int colg = n0 + nf * 16 + l15;
                out_s[((size_t)b * 128 + row) * HW + colg] = f2bf(acc[mf][nf][i]);
            }
}

// ---------------------------------------------------------------------------
// fused ff1 (GELU) + ff2: swb = W_ff2 @ gelu(W_ff1 @ x). bf16 out.
// ---------------------------------------------------------------------------
__global__ __launch_bounds__(256)
void ff_fused_k(const float* __restrict__ x, const int4* __restrict__ w1bf,
                const int4* __restrict__ w2bf, unsigned short* __restrict__ outp)
{
    __shared__ short WL[128 * 128];   // 32 KB (W1 then W2)
    __shared__ short XL[64 * 128];    // 16 KB (x^T then gelu(mid)^T)
    int t = threadIdx.x;
    int gb = blockIdx.x;
    int b = gb >> 8;
    int n0 = (gb & 255) << 6;

    #pragma unroll
    for (int it = 0; it < 8; ++it)
        ((int4*)WL)[it * 256 + t] = w1bf[it * 256 + t];

    const float* inb = x + (size_t)b * 128 * HW + n0;
    int nl = t & 63;
    #pragma unroll
    for (int it = 0; it < 4; ++it) {
        int c8 = (t >> 6) + it * 4;
        float v[8];
        #pragma unroll
        for (int j = 0; j < 8; ++j) v[j] = inb[(size_t)(c8 * 8 + j) * HW + nl];
        int4 p;
        p.x = f2bf_pk(v[0], v[1]); p.y = f2bf_pk(v[2], v[3]);
        p.z = f2bf_pk(v[4], v[5]); p.w = f2bf_pk(v[6], v[7]);
        ((int4*)XL)[nl * 16 + (c8 ^ (nl & 7))] = p;
    }
    __syncthreads();

    int l = t & 63, w = t >> 6, kg = l >> 4, l15 = l & 15, l7 = l15 & 7;
    f32x4 acc[2][4];
    #pragma unroll
    for (int mf = 0; mf < 2; ++mf)
        #pragma unroll
        for (int nf = 0; nf < 4; ++nf) acc[mf][nf] = (f32x4){0.f, 0.f, 0.f, 0.f};
    #pragma unroll
    for (int ks = 0; ks < 4; ++ks) {
        int ch = ks * 4 + kg;
        bf16x8 A0 = ((const bf16x8*)WL)[(w * 32 + l15) * 16 + (ch ^ l7)];
        bf16x8 A1 = ((const bf16x8*)WL)[(w * 32 + 16 + l15) * 16 + (ch ^ l7)];
        #pragma unroll
        for (int nf = 0; nf < 4; ++nf) {
            bf16x8 Bf = ((const bf16x8*)XL)[(nf * 16 + l15) * 16 + (ch ^ l7)];
            acc[0][nf] = __builtin_amdgcn_mfma_f32_16x16x32_bf16(A0, Bf, acc[0][nf], 0, 0, 0);
            acc[1][nf] = __builtin_amdgcn_mfma_f32_16x16x32_bf16(A1, Bf, acc[1][nf], 0, 0, 0);
        }
    }
    __syncthreads();   // all GEMM1 LDS reads done

    #pragma unroll
    for (int it = 0; it < 8; ++it)
        ((int4*)WL)[it * 256 + t] = w2bf[it * 256 + t];
    #pragma unroll
    for (int mf = 0; mf < 2; ++mf)
        #pragma unroll
        for (int nf = 0; nf < 4; ++nf) {
            float g4[4];
            #pragma unroll
            for (int i = 0; i < 4; ++i) {
                float v = acc[mf][nf][i];
                g4[i] = 0.5f * v * (1.0f + erff(v * 0.70710678118654752f));
            }
            int col = nf * 16 + l15;
            int r0 = w * 32 + mf * 16 + kg * 4;
            int octet = r0 >> 3;
            uint2 pk2;
            pk2.x = f2bf_pk(g4[0], g4[1]);
            pk2.y = f2bf_pk(g4[2], g4[3]);
            ((uint2*)XL)[(col * 16 + (octet ^ (col & 7))) * 2 + (kg & 1)] = pk2;
        }
    __syncthreads();

    f32x4 acc2[2][4];
    #pragma unroll
    for (int mf = 0; mf < 2; ++mf)
        #pragma unroll
        for (int nf = 0; nf < 4; ++nf) acc2[mf][nf] = (f32x4){0.f, 0.f, 0.f, 0.f};
    #pragma unroll
    for (int ks = 0; ks < 4; ++ks) {
        int ch = ks * 4 + kg;
        bf16x8 A0 = ((const bf16x8*)WL)[(w * 32 + l15) * 16 + (ch ^ l7)];
        bf16x8 A1 = ((const bf16x8*)WL)[(w * 32 + 16 + l15) * 16 + (ch ^ l7)];
        #pragma unroll
        for (int nf = 0; nf < 4; ++nf) {
            bf16x8 Bf = ((const bf16x8*)XL)[(nf * 16 + l15) * 16 + (ch ^ l7)];
            acc2[0][nf] = __builtin_amdgcn_mfma_f32_16x16x32_bf16(A0, Bf, acc2[0][nf], 0, 0, 0);
            acc2[1][nf] = __builtin_amdgcn_mfma_f32_16x16x32_bf16(A1, Bf, acc2[1][nf], 0, 0, 0);
        }
    }
    #pragma unroll
    for (int mf = 0; mf < 2; ++mf)
        #pragma unroll
        for (int nf = 0; nf < 4; ++nf)
            #pragma unroll
            for (int i = 0; i < 4; ++i) {
                int row = w * 32 + mf * 16 + kg * 4 + i;
                int col = n0 + nf * 16 + l15;
                outp[((size_t)b * 128 + row) * HW + col] = f2bf(acc2[mf][nf][i]);
            }
}

// ---------------------------------------------------------------------------
// fused gates + final (merged halves): stage X once, loop half=0,1.
// out = x + out_s*sigmoid(Wgfs@out_f+bgfs) + out_f*sigmoid(Wgsf@out_s+bgsf)
// ---------------------------------------------------------------------------
__global__ __launch_bounds__(256)
void fuse2_k(const float* __restrict__ x, const unsigned short* __restrict__ outs,
             const unsigned short* __restrict__ outf,
             const int4* __restrict__ wgsf_bf, const float* __restrict__ bgsf,
             const int4* __restrict__ wgfs_bf, const float* __restrict__ bgfs,
             float* __restrict__ out)
{
    __shared__ short WS[64 * 128];  // 16 KB (current half of W_gsf)
    __shared__ short WF[64 * 128];  // 16 KB
    __shared__ short XS[64 * 128];  // 16 KB out_s^T tile (all 128 ch)
    __shared__ short XF[64 * 128];  // 16 KB out_f^T tile
    int t = threadIdx.x;
    int gb = blockIdx.x;
    int b = gb >> 8;
    int n0 = (gb & 255) << 6;

    const unsigned short* sb = outs + (size_t)b * 128 * HW + n0;
    const unsigned short* fb = outf + (size_t)b * 128 * HW + n0;
    int nl = t & 63;
    #pragma unroll
    for (int it = 0; it < 4; ++it) {
        int c8 = (t >> 6) + it * 4;
        unsigned us[8], uf[8];
        #pragma unroll
        for (int j = 0; j < 8; ++j) {
            size_t a = (size_t)(c8 * 8 + j) * HW + nl;
            us[j] = sb[a];
            uf[j] = fb[a];
        }
        int4 ps, pf;
        ps.x = (int)(us[0] | (us[1] << 16)); ps.y = (int)(us[2] | (us[3] << 16));
        ps.z = (int)(us[4] | (us[5] << 16)); ps.w = (int)(us[6] | (us[7] << 16));
        pf.x = (int)(uf[0] | (uf[1] << 16)); pf.y = (int)(uf[2] | (uf[3] << 16));
        pf.z = (int)(uf[4] | (uf[5] << 16)); pf.w = (int)(uf[6] | (uf[7] << 16));
        ((int4*)XS)[nl * 16 + (c8 ^ (nl & 7))] = ps;
        ((int4*)XF)[nl * 16 + (c8 ^ (nl & 7))] = pf;
    }

    int l = t & 63, w = t >> 6, kg = l >> 4, l15 = l & 15, l7 = l15 & 7;
    for (int half = 0; half < 2; ++half) {
        #pragma unroll
        for (int it = 0; it < 4; ++it) {
            ((int4*)WS)[it * 256 + t] = wgsf_bf[half * 1024 + it * 256 + t];
            ((int4*)WF)[it * 256 + t] = wgfs_bf[half * 1024 + it * 256 + t];
        }
        __syncthreads();

        f32x4 aS[4], aF[4];
        #pragma unroll
        for (int nf = 0; nf < 4; ++nf) {
            aS[nf] = (f32x4){0.f, 0.f, 0.f, 0.f};
            aF[nf] = (f32x4){0.f, 0.f, 0.f, 0.f};
        }
        #pragma unroll
        for (int ks = 0; ks < 4; ++ks) {
            int ch = ks * 4 + kg;
            bf16x8 As = ((const bf16x8*)WS)[(w * 16 + l15) * 16 + (ch ^ l7)];
            bf16x8 Af = ((const bf16x8*)WF)[(w * 16 + l15) * 16 + (ch ^ l7)];
            #pragma unroll
            for (int nf = 0; nf < 4; ++nf) {
                bf16x8 Bs = ((const bf16x8*)XS)[(nf * 16 + l15) * 16 + (ch ^ l7)];
                bf16x8 Bf = ((const bf16x8*)XF)[(nf * 16 + l15) * 16 + (ch ^ l7)];
                aS[nf] = __builtin_amdgcn_mfma_f32_16x16x32_bf16(As, Bs, aS[nf], 0, 0, 0);
                aF[nf] = __builtin_amdgcn_mfma_f32_16x16x32_bf16(Af, Bf, aF[nf], 0, 0, 0);
            }
        }
        #pragma unroll
        for (int nf = 0; nf < 4; ++nf)
            #pragma unroll
            for (int i = 0; i < 4; ++i) {
                int row = half * 64 + w * 16 + kg * 4 + i;
                int cc = nf * 16 + l15;
                float gf = sigmoidf_(aS[nf][i] + bgsf[row]);   // gates out_f
                float gs = sigmoidf_(aF[nf][i] + bgfs[row]);   // gates out_s
                size_t gi = ((size_t)(b * 128) + row) * HW + n0 + cc;
                float os = bf2f(outs[gi]);
                float of = bf2f(outf[gi]);
                out[gi] = x[gi] + os * gs + of * gf;
            }
        __syncthreads();   // all WS/WF reads done before restage
    }
}

// ---------------------------------------------------------------------------
// FFT: radix-2 128-pt, LDS twiddles
// ---------------------------------------------------------------------------
__device__ __forceinline__ void fft_build_tw(float2* tw, int t)
{
    if (t < 64) {
        float ang = 0.049087385212340519f * (float)t;
        float sn, cs; sincosf(ang, &sn, &cs);
        tw[t] = make_float2(cs, sn);
    }
}

__device__ __forceinline__ void fft_stage_dif(float2 (*buf)[128], const float2* tw,
                                              int t, int s)
{
    int mh = 64 >> s;
    #pragma unroll
    for (int i = 0; i < 4; ++i) {
        int idx = t + i * 256;
        int rl = idx >> 6;
        int bf = idx & 63;
        int blk = bf >> (6 - s);
        int jj = bf & (mh - 1);
        int base = (blk << (7 - s)) + jj;
        float2 a = buf[rl][base];
        float2 b = buf[rl][base + mh];
        float2 w = tw[jj << s];
        float cs = w.x, sn = -w.y;
        float dx = a.x - b.x, dy = a.y - b.y;
        buf[rl][base] = make_float2(a.x + b.x, a.y + b.y);
        buf[rl][base + mh] = make_float2(dx * cs - dy * sn, dx * sn + dy * cs);
    }
}

__device__ __forceinline__ void fft_stage_dit(float2 (*buf)[128], const float2* tw,
                                              int t, int s)
{
    int mh = 64 >> s;
    #pragma unroll
    for (int i = 0; i < 4; ++i) {
        int idx = t + i * 256;
        int rl = idx >> 6;
        int bf = idx & 63;
        int blk = bf >> (6 - s);
        int jj = bf & (mh - 1);
        int base = (blk << (7 - s)) + jj;
        float2 a = buf[rl][base];
        float2 b = buf[rl][base + mh];
        float2 w = tw[jj << s];
        float cs = w.x, sn = w.y;
        float tx = b.x * cs - b.y * sn, ty = b.x * sn + b.y * cs;
        buf[rl][base] = make_float2(a.x + tx, a.y + ty);
        buf[rl][base + mh] = make_float2(a.x - tx, a.y - ty);
    }
}

__device__ __forceinline__ void fft16_fwd(float2 (*buf)[128], const float2* tw, int t)
{
    for (int s = 0; s < 7; ++s) { __syncthreads(); fft_stage_dif(buf, tw, t, s); }
    __syncthreads();
}
__device__ __forceinline__ void fft16_inv(float2 (*buf)[128], const float2* tw, int t)
{
    for (int s = 6; s >= 0; --s) { __syncthreads(); fft_stage_dit(buf, tw, t, s); }
    __syncthreads();
}

__global__ __launch_bounds__(256)
void fft_p1_k(const float* __restrict__ x, const unsigned short* __restrict__ sw,
              float2* __restrict__ A)
{
    __shared__ float2 buf[16][128];
    __shared__ float2 tw[64];
    int t = threadIdx.x;
    fft_build_tw(tw, t);
    int ch = blockIdx.x >> 3;
    int rg = blockIdx.x & 7;
    size_t base = (size_t)ch * HW + rg * 2048;
    #pragma unroll
    for (int i = 0; i < 8; ++i) {
        int idx = t + i * 256;
        int rl = idx >> 7, cc = idx & 127;
        buf[rl][cc] = make_float2(x[base + rl * 128 + cc],
                                  bf2f(sw[base + rl * 128 + cc]));
    }
    fft16_fwd(buf, tw, t);
    size_t abase = (size_t)ch * HW + rg * 16;
    #pragma unroll
    for (int i = 0; i < 8; ++i) {
        int idx = t + i * 256;
        int rl = idx & 15, k1 = idx >> 4;
        A[abase + (size_t)k1 * 128 + rl] = buf[rl][k1];
    }
}

__global__ __launch_bounds__(256)
void fft_p234_k(float2* __restrict__ A)
{
    __shared__ float2 buf[16][128];
    __shared__ float2 tw[64];
    int t = threadIdx.x;
    fft_build_tw(tw, t);
    int ch = blockIdx.x >> 3;
    int rg = blockIdx.x & 7;
    size_t cb = (size_t)ch * HW;

    #pragma unroll
    for (int i = 0; i < 8; ++i) {
        int idx = t + i * 256;
        int l = idx >> 7, cc = idx & 127;
        int k1l;
        if (rg == 0) k1l = (l < 2) ? l * 64 : (l < 9 ? l - 1 : 128 - (l - 8));
        else         k1l = (l < 8) ? 8 * rg + l : 128 - (8 * rg + l - 8);
        buf[l][cc] = A[cb + (size_t)brev7(k1l) * 128 + cc];
    }
    fft16_fwd(buf, tw, t);

    int nItems = (rg == 0) ? 1026 : 1024;
    for (int item = t; item < nItems; item += 256) {
        int lA, lB, k2;
        if (rg == 0) {
            if (item < 896) { int s = item >> 7; k2 = item & 127; lA = 2 + s; lB = 9 + s; }
            else            { int r = item - 896; lA = lB = r / 65; k2 = r % 65; }
        } else {
            int s = item >> 7; k2 = item & 127; lA = s; lB = 8 + s;
        }
        int i2 = brev7(k2), j2 = brev7((128 - k2) & 127);
        float2 z1 = buf[lA][i2];
        float2 z2 = buf[lB][j2];
        float2 X = make_float2(0.5f * (z1.x + z2.x), 0.5f * (z1.y - z2.y));
        float Dx = z1.x - z2.x, Dy = z1.y + z2.y;
        float2 Wf = make_float2(0.5f * Dy, -0.5f * Dx);
        float2 Y = make_float2(X.x * Wf.x - X.y * Wf.y, X.x * Wf.y + X.y * Wf.x);
        buf[lA][i2] = Y;
        buf[lB][j2] = make_float2(Y.x, -Y.y);
    }
    fft16_inv(buf, tw, t);

    #pragma unroll
    for (int i = 0; i < 8; ++i) {
        int idx = t + i * 256;
        int l = idx >> 7, cc = idx & 127;
        int k1l;
        if (rg == 0) k1l = (l < 2) ? l * 64 : (l < 9 ? l - 1 : 128 - (l - 8));
        else         k1l = (l < 8) ? 8 * rg + l : 128 - (8 * rg + l - 8);
        A[cb + (size_t)brev7(k1l) * 128 + cc] = buf[l][cc];
    }
}

__global__ __launch_bounds__(256)
void fft_p5_k(const float2* __restrict__ A, float* __restrict__ outp)
{
    __shared__ float2 buf[16][128];
    __shared__ float2 tw[64];
    int t = threadIdx.x;
    fft_build_tw(tw, t);
    int ch = blockIdx.x >> 3;
    int rg = blockIdx.x & 7;
    size_t abase = (size_t)ch * HW + rg * 16;
    #pragma unroll
    for (int i = 0; i < 8; ++i) {
        int idx = t + i * 256;
        int rl = idx & 15, i1 = idx >> 4;
        buf[rl][i1] = A[abase + (size_t)i1 * 128 + rl];
    }
    fft16_inv(buf, tw, t);
    const float scale = 1.f / 2097152.f;
    size_t obase = (size_t)ch * HW + rg * 2048;
    #pragma unroll
    for (int i = 0; i < 8; ++i) {
        int idx = t + i * 256;
        int rl = idx >> 7, cc = idx & 127;
        outp[obase + rl * 128 + cc] = buf[rl][cc].x * scale;
    }
}

// ---------------------------------------------------------------------------
// Workspace plan (128 MiB ws + d_out scratch):
//  ws[0,32):  V bf16 (phase A) -> out_f bf16 (phase B)
//  ws[32,64): out_s bf16
//  ws[64,96): swb bf16
//  ws[96,96.25): Wbf 7x32KB pre-swizzled bf16 weights (persistent)
//  d_out: vcb bf16 [0,32) / Gp [32,48) / G,S [48,48.6) (phase A);
//         A [0,32) / pre [32,48) (phase B); final output (fuse2).
// ---------------------------------------------------------------------------
extern "C" void kernel_launch(void* const* d_in, const int* in_sizes, int n_in,
                              void* d_out, int out_size, void* d_ws, size_t ws_size,
                              hipStream_t stream)
{
    const float* x        = (const float*)d_in[0];
    const float* W_qkv    = (const float*)d_in[1];
    const float* W_dw     = (const float*)d_in[2];
    const float* W_proj_s = (const float*)d_in[3];
    const float* scale_s  = (const float*)d_in[4];
    const float* W_ff1    = (const float*)d_in[5];
    const float* W_ff2    = (const float*)d_in[6];
    const float* W_proj_f = (const float*)d_in[7];
    const float* W_gsf    = (const float*)d_in[8];
    const float* b_gsf    = (const float*)d_in[9];
    const float* W_gfs    = (const float*)d_in[10];
    const float* b_gfs    = (const float*)d_in[11];
    float* out = (float*)d_out;

    char* ws = (char*)d_ws;
    const size_t MB32 = 33554432ull;
    const size_t MB64 = 67108864ull;
    const size_t MB96 = 100663296ull;
    unsigned short* V     = (unsigned short*)(ws);          // 32 MiB phase A
    unsigned short* out_s = (unsigned short*)(ws + MB32);   // 32 MiB
    unsigned short* swb   = (unsigned short*)(ws + MB64);   // 32 MiB bf16
    unsigned short* out_fp= (unsigned short*)(ws);          // 32 MiB (V dead)
    int4* Wbf4            = (int4*)(ws + MB96);             // 224 KiB
    unsigned short* vcb   = (unsigned short*)out;           // 32 MiB d_out lo
    float* Gp  = out + 8388608;                             // 16 MiB d_out[32,48)
    float* G   = out + 8388608 + 4194304;                   // 512 KiB
    float* S   = G + 131072;                                // 64 KiB
    float2* A  = (float2*)out;                              // 32 MiB phase B
    float* pre = out + 8388608;                             // 16 MiB phase B

    // --- weight pre-conversion (bf16, pre-swizzled) ---
    // slices: 0=W_v 1=W_proj_s 2=W_ff1 3=W_ff2 4=W_proj_f 5=W_gsf 6=W_gfs
    wprep_k<<<56, 256, 0, stream>>>(W_qkv + 256 * 128, W_proj_s, W_ff1, W_ff2,
                                    W_proj_f, W_gsf, W_gfs, Wbf4);

    // --- spatial attention branch ---
    conv_mfma_k<<<2048, 256, 0, stream>>>(x, Wbf4 + 0 * 2048, V);
    dwconv_k<<<16384, 256, 0, stream>>>(V, W_dw, vcb);
    gram_mfma_k<<<256, 256, 0, stream>>>(x, Gp);
    gram_reduce_k<<<512, 256, 0, stream>>>(Gp, G);
    attn_s2_k<<<64, 256, 0, stream>>>(G, W_qkv, scale_s, S);
    proj_s_pv_k<<<2048, 256, 0, stream>>>(V, vcb, S, Wbf4 + 1 * 2048, out_s);

    // --- frequency branch ---
    ff_fused_k<<<2048, 256, 0, stream>>>(x, Wbf4 + 2 * 2048, Wbf4 + 3 * 2048, swb);
    for (int chunk = 0; chunk < 4; ++chunk) {
        const float* xc  = x   + (size_t)chunk * 4194304;
        const unsigned short* swc = swb + (size_t)chunk * 4194304;
        unsigned short* ofc = out_fp + (size_t)chunk * 4194304;
        fft_p1_k<<<2048, 256, 0, stream>>>(xc, swc, A);
        fft_p234_k<<<2048, 256, 0, stream>>>(A);
        fft_p5_k<<<2048, 256, 0, stream>>>(A, pre);
        conv_mfma_k<<<512, 256, 0, stream>>>(pre, Wbf4 + 4 * 2048, ofc);
    }

    // --- fused gates + final output ---
    fuse2_k<<<2048, 256, 0, stream>>>(x, out_s, out_fp,
                                      Wbf4 + 5 * 2048, b_gsf,
                                      Wbf4 + 6 * 2048, b_gfs, out);
}

// Round 11
// 540.129 us; speedup vs baseline: 1.0746x; 1.0746x over previous
//
#include <hip/hip_runtime.h>
#include <math.h>

#define HW 16384

typedef __attribute__((ext_vector_type(8))) short bf16x8;
typedef __attribute__((ext_vector_type(4))) float f32x4;

__device__ __forceinline__ unsigned f2bf_pk(float a, float b)
{
    unsigned ua = __float_as_uint(a), ub = __float_as_uint(b);
    ua = (ua + 0x7FFFu + ((ua >> 16) & 1u)) >> 16;   // RTN-even
    ub = (ub + 0x7FFFu + ((ub >> 16) & 1u)) >> 16;
    return (ua & 0xFFFFu) | (ub << 16);
}
__device__ __forceinline__ unsigned short f2bf(float a)
{
    unsigned ua = __float_as_uint(a);
    ua = (ua + 0x7FFFu + ((ua >> 16) & 1u)) >> 16;
    return (unsigned short)ua;
}
__device__ __forceinline__ float bf2f(unsigned short u)
{
    return __uint_as_float(((unsigned)u) << 16);
}
__device__ __forceinline__ int brev7(int v) { return (int)(__brev((unsigned)v) >> 25); }
__device__ __forceinline__ float sigmoidf_(float v) { return 1.f / (1.f + expf(-v)); }

// ---------------------------------------------------------------------------
// wprep: convert 7 weight matrices (128x128 fp32) to bf16 in pre-swizzled
// LDS chunk order: slot s holds row o=s>>4, col-octet c16 = (s&15) ^ (o&7).
// ---------------------------------------------------------------------------
__global__ __launch_bounds__(256)
void wprep_k(const float* __restrict__ w0, const float* __restrict__ w1,
             const float* __restrict__ w2, const float* __restrict__ w3,
             const float* __restrict__ w4, const float* __restrict__ w5,
             const float* __restrict__ w6, int4* __restrict__ Wbf4)
{
    int m = blockIdx.x >> 3;
    int slot = (blockIdx.x & 7) * 256 + threadIdx.x;   // 0..2047
    const float* src;
    switch (m) {
        case 0: src = w0; break;
        case 1: src = w1; break;
        case 2: src = w2; break;
        case 3: src = w3; break;
        case 4: src = w4; break;
        case 5: src = w5; break;
        default: src = w6; break;
    }
    int o = slot >> 4;
    int c16 = (slot & 15) ^ (o & 7);
    const float* p = src + o * 128 + c16 * 8;
    int4 pk;
    pk.x = f2bf_pk(p[0], p[1]); pk.y = f2bf_pk(p[2], p[3]);
    pk.z = f2bf_pk(p[4], p[5]); pk.w = f2bf_pk(p[6], p[7]);
    Wbf4[m * 2048 + slot] = pk;
}

// ---------------------------------------------------------------------------
// MFMA conv1x1, fp32 in -> bf16 out, pre-swizzled bf16 weights.
// Tile O=128 x N=64, K=128.
// ---------------------------------------------------------------------------
__global__ __launch_bounds__(256)
void conv_mfma_k(const float* __restrict__ in, const int4* __restrict__ wbf,
                 unsigned short* __restrict__ out)
{
    __shared__ short WL[128 * 128];   // 32 KB
    __shared__ short XL[64 * 128];    // 16 KB
    int t = threadIdx.x;
    int gb = blockIdx.x;
    int b = gb >> 8;
    int n0 = (gb & 255) << 6;

    #pragma unroll
    for (int it = 0; it < 8; ++it)
        ((int4*)WL)[it * 256 + t] = wbf[it * 256 + t];

    const float* inb = in + (size_t)b * 128 * HW + n0;
    int nl = t & 63;
    #pragma unroll
    for (int it = 0; it < 4; ++it) {
        int c8 = (t >> 6) + it * 4;
        float v[8];
        #pragma unroll
        for (int j = 0; j < 8; ++j) v[j] = inb[(size_t)(c8 * 8 + j) * HW + nl];
        int4 p;
        p.x = f2bf_pk(v[0], v[1]); p.y = f2bf_pk(v[2], v[3]);
        p.z = f2bf_pk(v[4], v[5]); p.w = f2bf_pk(v[6], v[7]);
        ((int4*)XL)[nl * 16 + (c8 ^ (nl & 7))] = p;
    }
    __syncthreads();

    int l = t & 63, w = t >> 6, kg = l >> 4, l15 = l & 15, l7 = l15 & 7;
    f32x4 acc[2][4];
    #pragma unroll
    for (int mf = 0; mf < 2; ++mf)
        #pragma unroll
        for (int nf = 0; nf < 4; ++nf) acc[mf][nf] = (f32x4){0.f, 0.f, 0.f, 0.f};
    #pragma unroll
    for (int ks = 0; ks < 4; ++ks) {
        int ch = ks * 4 + kg;
        bf16x8 A0 = ((const bf16x8*)WL)[(w * 32 + l15) * 16 + (ch ^ l7)];
        bf16x8 A1 = ((const bf16x8*)WL)[(w * 32 + 16 + l15) * 16 + (ch ^ l7)];
        #pragma unroll
        for (int nf = 0; nf < 4; ++nf) {
            bf16x8 Bf = ((const bf16x8*)XL)[(nf * 16 + l15) * 16 + (ch ^ l7)];
            acc[0][nf] = __builtin_amdgcn_mfma_f32_16x16x32_bf16(A0, Bf, acc[0][nf], 0, 0, 0);
            acc[1][nf] = __builtin_amdgcn_mfma_f32_16x16x32_bf16(A1, Bf, acc[1][nf], 0, 0, 0);
        }
    }
    #pragma unroll
    for (int mf = 0; mf < 2; ++mf)
        #pragma unroll
        for (int nf = 0; nf < 4; ++nf)
            #pragma unroll
            for (int i = 0; i < 4; ++i) {
                int row = w * 32 + mf * 16 + kg * 4 + i;
                int col = n0 + nf * 16 + l15;
                out[((size_t)b * 128 + row) * HW + col] = f2bf(acc[mf][nf][i]);
            }
}

// ---------------------------------------------------------------------------
// depthwise 3x3 SAME, x4 vectorized, bf16 in -> bf16 out
// ---------------------------------------------------------------------------
__global__ __launch_bounds__(256)
void dwconv_k(const unsigned short* __restrict__ V, const float* __restrict__ Wdw,
              unsigned short* __restrict__ vcb)
{
    int tid = blockIdx.x * 256 + threadIdx.x;
    int e4 = tid & 4095;
    int bc = tid >> 12;
    int c = bc & 127;
    int y = e4 >> 5;
    int x0 = (e4 & 31) << 2;
    const unsigned short* vin = V + (size_t)bc * HW;
    float wf[9];
    #pragma unroll
    for (int i = 0; i < 9; ++i) wf[i] = Wdw[c * 9 + i];
    float a0 = 0.f, a1 = 0.f, a2 = 0.f, a3 = 0.f;
    #pragma unroll
    for (int dy = 0; dy < 3; ++dy) {
        int yy = y + dy - 1;
        if (yy < 0 || yy > 127) continue;
        const unsigned short* r = vin + yy * 128;
        uint2 mu = *(const uint2*)(r + x0);
        float m0 = bf2f((unsigned short)(mu.x & 0xFFFF));
        float m1 = bf2f((unsigned short)(mu.x >> 16));
        float m2 = bf2f((unsigned short)(mu.y & 0xFFFF));
        float m3 = bf2f((unsigned short)(mu.y >> 16));
        float left  = (x0 > 0)   ? bf2f(r[x0 - 1]) : 0.f;
        float right = (x0 < 124) ? bf2f(r[x0 + 4]) : 0.f;
        float w0 = wf[dy * 3], w1 = wf[dy * 3 + 1], w2 = wf[dy * 3 + 2];
        a0 += w0 * left + w1 * m0 + w2 * m1;
        a1 += w0 * m0   + w1 * m1 + w2 * m2;
        a2 += w0 * m1   + w1 * m2 + w2 * m3;
        a3 += w0 * m2   + w1 * m3 + w2 * right;
    }
    uint2 r2;
    r2.x = f2bf_pk(a0, a1);
    r2.y = f2bf_pk(a2, a3);
    *(uint2*)(vcb + (size_t)bc * HW + y * 128 + x0) = r2;
}

// ---------------------------------------------------------------------------
// MFMA Gram partials: 32 slices of 512 px. blk = b*32+ks. grid 256.
// ---------------------------------------------------------------------------
__global__ __launch_bounds__(256)
void gram_mfma_k(const float* __restrict__ x, float* __restrict__ Gp)
{
    __shared__ short XL[128 * 128];
    int t = threadIdx.x;
    int blk = blockIdx.x;
    int b = blk >> 5, ks = blk & 31;
    const float* xb = x + (size_t)b * 128 * HW + ks * 512;
    int l = t & 63, w = t >> 6, kg = l >> 4, l15 = l & 15, l7 = l15 & 7;

    f32x4 acc[2][8];
    #pragma unroll
    for (int mf = 0; mf < 2; ++mf)
        #pragma unroll
        for (int nf = 0; nf < 8; ++nf) acc[mf][nf] = (f32x4){0.f, 0.f, 0.f, 0.f};

    for (int kc = 0; kc < 4; ++kc) {
        __syncthreads();
        #pragma unroll
        for (int it = 0; it < 8; ++it) {
            int g = it * 256 + t;
            int row = g >> 4, oct = g & 15;
            const float* p = xb + (size_t)row * HW + kc * 128 + oct * 8;
            int4 pk;
            pk.x = f2bf_pk(p[0], p[1]); pk.y = f2bf_pk(p[2], p[3]);
            pk.z = f2bf_pk(p[4], p[5]); pk.w = f2bf_pk(p[6], p[7]);
            ((int4*)XL)[row * 16 + (oct ^ (row & 7))] = pk;
        }
        __syncthreads();
        #pragma unroll
        for (int s = 0; s < 4; ++s) {
            int oct = s * 4 + kg;
            bf16x8 A0 = ((const bf16x8*)XL)[(w * 32 + l15) * 16 + (oct ^ l7)];
            bf16x8 A1 = ((const bf16x8*)XL)[(w * 32 + 16 + l15) * 16 + (oct ^ l7)];
            #pragma unroll
            for (int nf = 0; nf < 8; ++nf) {
                bf16x8 Bf = ((const bf16x8*)XL)[(nf * 16 + l15) * 16 + (oct ^ l7)];
                acc[0][nf] = __builtin_amdgcn_mfma_f32_16x16x32_bf16(A0, Bf, acc[0][nf], 0, 0, 0);
                acc[1][nf] = __builtin_amdgcn_mfma_f32_16x16x32_bf16(A1, Bf, acc[1][nf], 0, 0, 0);
            }
        }
    }
    float* gp = Gp + (size_t)blk * 16384;
    #pragma unroll
    for (int mf = 0; mf < 2; ++mf)
        #pragma unroll
        for (int nf = 0; nf < 8; ++nf)
            #pragma unroll
            for (int i = 0; i < 4; ++i) {
                int row = w * 32 + mf * 16 + kg * 4 + i;
                int col = nf * 16 + l15;
                gp[row * 128 + col] = acc[mf][nf][i];
            }
}

__global__ void gram_reduce_k(const float* __restrict__ Gp, float* __restrict__ G)
{
    int idx = blockIdx.x * 256 + threadIdx.x;   // 8*16384
    int b = idx >> 14;
    int ij = idx & 16383;
    const float* gp = Gp + (size_t)(b * 32) * 16384 + ij;
    float s = 0.f;
    #pragma unroll
    for (int ks = 0; ks < 32; ++ks) s += gp[(size_t)ks * 16384];
    G[idx] = s;
}

// ---------------------------------------------------------------------------
// S_h = softmax( (Wq_h G Wk_h^T) * scale[h] )
// ---------------------------------------------------------------------------
__global__ __launch_bounds__(256)
void attn_s2_k(const float* __restrict__ G, const float* __restrict__ Wqkv,
               const float* __restrict__ scale, float* __restrict__ S)
{
    __shared__ float Wq[16][129];
    __shared__ float Wk[16][129];
    __shared__ float Ts[16][129];
    int bh = blockIdx.x;
    int b = bh >> 3, h = bh & 7;
    int t = threadIdx.x;
    #pragma unroll
    for (int i = 0; i < 8; ++i) {
        int idx = t + i * 256;
        int r = idx >> 7, ci = idx & 127;
        Wq[r][ci] = Wqkv[(size_t)(h * 16 + r) * 128 + ci];
        Wk[r][ci] = Wqkv[(size_t)(128 + h * 16 + r) * 128 + ci];
    }
    __syncthreads();
    const float* Gb = G + (size_t)b * 16384;
    #pragma unroll
    for (int i = 0; i < 8; ++i) {
        int idx = t + i * 256;
        int c = idx >> 7, col = idx & 127;
        float s = 0.f;
        #pragma unroll 8
        for (int ci = 0; ci < 128; ++ci)
            s += Wq[c][ci] * Gb[ci * 128 + col];
        Ts[c][col] = s;
    }
    __syncthreads();
    int c = t >> 4, d = t & 15;
    float s = 0.f;
    #pragma unroll 8
    for (int col = 0; col < 128; ++col)
        s += Ts[c][col] * Wk[d][col];
    s *= scale[h];
    float m = s;
    #pragma unroll
    for (int w = 1; w < 16; w <<= 1)
        m = fmaxf(m, __shfl_xor(m, w, 64));
    float e = expf(s - m);
    float sum = e;
    #pragma unroll
    for (int w = 1; w < 16; w <<= 1)
        sum += __shfl_xor(sum, w, 64);
    S[(size_t)bh * 256 + t] = e / sum;
}

// ---------------------------------------------------------------------------
// proj_s with fused PV: out_s = W_proj_s @ (PV(V) + vconv), bf16 in/out.
// ---------------------------------------------------------------------------
__global__ __launch_bounds__(256)
void proj_s_pv_k(const unsigned short* __restrict__ V,
                 const unsigned short* __restrict__ vcb,
                 const float* __restrict__ S, const int4* __restrict__ wbf,
                 unsigned short* __restrict__ out_s)
{
    __shared__ short WL[128 * 128];   // 32 KB
    __shared__ short XL[64 * 128];    // 16 KB
    __shared__ float SL[2048];        // 8 KB
    int t = threadIdx.x;
    int gb = blockIdx.x;
    int b = gb >> 8;
    int n0 = (gb & 255) << 6;

    #pragma unroll
    for (int it = 0; it < 8; ++it)
        ((int4*)WL)[it * 256 + t] = wbf[it * 256 + t];
    #pragma unroll
    for (int i = 0; i < 8; ++i)
        SL[i * 256 + t] = S[(size_t)b * 2048 + i * 256 + t];
    __syncthreads();

    int col = t & 63, w = t >> 6;
    #pragma unroll
    for (int hh = 0; hh < 2; ++hh) {
        int h = w * 2 + hh;
        float v[16];
        #pragma unroll
        for (int d = 0; d < 16; ++d)
            v[d] = bf2f(V[((size_t)(b * 128 + h * 16 + d)) * HW + n0 + col]);
        float o[16];
        #pragma unroll
        for (int c = 0; c < 16; ++c) {
            const float* sl = SL + h * 256 + c * 16;
            float s = 0.f;
            #pragma unroll
            for (int d = 0; d < 16; ++d) s += sl[d] * v[d];
            o[c] = s + bf2f(vcb[((size_t)(b * 128 + h * 16 + c)) * HW + n0 + col]);
        }
        #pragma unroll
        for (int oc = 0; oc < 2; ++oc) {
            int octet = h * 2 + oc;
            int4 p;
            p.x = f2bf_pk(o[oc * 8 + 0], o[oc * 8 + 1]);
            p.y = f2bf_pk(o[oc * 8 + 2], o[oc * 8 + 3]);
            p.z = f2bf_pk(o[oc * 8 + 4], o[oc * 8 + 5]);
            p.w = f2bf_pk(o[oc * 8 + 6], o[oc * 8 + 7]);
            ((int4*)XL)[col * 16 + (octet ^ (col & 7))] = p;
        }
    }
    __syncthreads();

    int l = t & 63, kg = l >> 4, l15 = l & 15, l7 = l15 & 7;
    f32x4 acc[2][4];
    #pragma unroll
    for (int mf = 0; mf < 2; ++mf)
        #pragma unroll
        for (int nf = 0; nf < 4; ++nf) acc[mf][nf] = (f32x4){0.f, 0.f, 0.f, 0.f};
    #pragma unroll
    for (int ks = 0; ks < 4; ++ks) {
        int ch = ks * 4 + kg;
        bf16x8 A0 = ((const bf16x8*)WL)[(w * 32 + l15) * 16 + (ch ^ l7)];
        bf16x8 A1 = ((const bf16x8*)WL)[(w * 32 + 16 + l15) * 16 + (ch ^ l7)];
        #pragma unroll
        for (int nf = 0; nf < 4; ++nf) {
            bf16x8 Bf = ((const bf16x8*)XL)[(nf * 16 + l15) * 16 + (ch ^ l7)];
            acc[0][nf] = __builtin_amdgcn_mfma_f32_16x16x32_bf16(A0, Bf, acc[0][nf], 0, 0, 0);
            acc[1][nf] = __builtin_amdgcn_mfma_f32_16x16x32_bf16(A1, Bf, acc[1][nf], 0, 0, 0);
        }
    }
    #pragma unroll
    for (int mf = 0; mf < 2; ++mf)
        #pragma unroll
        for (int nf = 0; nf < 4; ++nf)
            #pragma unroll
            for (int i = 0; i < 4; ++i) {
                int row = w * 32 + mf * 16 + kg * 4 + i;
                int colg = n0 + nf * 16 + l15;
                out_s[((size_t)b * 128 + row) * HW + colg] = f2bf(acc[mf][nf][i]);
            }
}

// ---------------------------------------------------------------------------
// fused ff1 (GELU) + ff2: swb = W_ff2 @ gelu(W_ff1 @ x). bf16 out.
// ---------------------------------------------------------------------------
__global__ __launch_bounds__(256)
void ff_fused_k(const float* __restrict__ x, const int4* __restrict__ w1bf,
                const int4* __restrict__ w2bf, unsigned short* __restrict__ outp)
{
    __shared__ short WL[128 * 128];   // 32 KB (W1 then W2)
    __shared__ short XL[64 * 128];    // 16 KB (x^T then gelu(mid)^T)
    int t = threadIdx.x;
    int gb = blockIdx.x;
    int b = gb >> 8;
    int n0 = (gb & 255) << 6;

    #pragma unroll
    for (int it = 0; it < 8; ++it)
        ((int4*)WL)[it * 256 + t] = w1bf[it * 256 + t];

    const float* inb = x + (size_t)b * 128 * HW + n0;
    int nl = t & 63;
    #pragma unroll
    for (int it = 0; it < 4; ++it) {
        int c8 = (t >> 6) + it * 4;
        float v[8];
        #pragma unroll
        for (int j = 0; j < 8; ++j) v[j] = inb[(size_t)(c8 * 8 + j) * HW + nl];
        int4 p;
        p.x = f2bf_pk(v[0], v[1]); p.y = f2bf_pk(v[2], v[3]);
        p.z = f2bf_pk(v[4], v[5]); p.w = f2bf_pk(v[6], v[7]);
        ((int4*)XL)[nl * 16 + (c8 ^ (nl & 7))] = p;
    }
    __syncthreads();

    int l = t & 63, w = t >> 6, kg = l >> 4, l15 = l & 15, l7 = l15 & 7;
    f32x4 acc[2][4];
    #pragma unroll
    for (int mf = 0; mf < 2; ++mf)
        #pragma unroll
        for (int nf = 0; nf < 4; ++nf) acc[mf][nf] = (f32x4){0.f, 0.f, 0.f, 0.f};
    #pragma unroll
    for (int ks = 0; ks < 4; ++ks) {
        int ch = ks * 4 + kg;
        bf16x8 A0 = ((const bf16x8*)WL)[(w * 32 + l15) * 16 + (ch ^ l7)];
        bf16x8 A1 = ((const bf16x8*)WL)[(w * 32 + 16 + l15) * 16 + (ch ^ l7)];
        #pragma unroll
        for (int nf = 0; nf < 4; ++nf) {
            bf16x8 Bf = ((const bf16x8*)XL)[(nf * 16 + l15) * 16 + (ch ^ l7)];
            acc[0][nf] = __builtin_amdgcn_mfma_f32_16x16x32_bf16(A0, Bf, acc[0][nf], 0, 0, 0);
            acc[1][nf] = __builtin_amdgcn_mfma_f32_16x16x32_bf16(A1, Bf, acc[1][nf], 0, 0, 0);
        }
    }
    __syncthreads();   // all GEMM1 LDS reads done

    #pragma unroll
    for (int it = 0; it < 8; ++it)
        ((int4*)WL)[it * 256 + t] = w2bf[it * 256 + t];
    #pragma unroll
    for (int mf = 0; mf < 2; ++mf)
        #pragma unroll
        for (int nf = 0; nf < 4; ++nf) {
            float g4[4];
            #pragma unroll
            for (int i = 0; i < 4; ++i) {
                float v = acc[mf][nf][i];
                g4[i] = 0.5f * v * (1.0f + erff(v * 0.70710678118654752f));
            }
            int col = nf * 16 + l15;
            int r0 = w * 32 + mf * 16 + kg * 4;
            int octet = r0 >> 3;
            uint2 pk2;
            pk2.x = f2bf_pk(g4[0], g4[1]);
            pk2.y = f2bf_pk(g4[2], g4[3]);
            ((uint2*)XL)[(col * 16 + (octet ^ (col & 7))) * 2 + (kg & 1)] = pk2;
        }
    __syncthreads();

    f32x4 acc2[2][4];
    #pragma unroll
    for (int mf = 0; mf < 2; ++mf)
        #pragma unroll
        for (int nf = 0; nf < 4; ++nf) acc2[mf][nf] = (f32x4){0.f, 0.f, 0.f, 0.f};
    #pragma unroll
    for (int ks = 0; ks < 4; ++ks) {
        int ch = ks * 4 + kg;
        bf16x8 A0 = ((const bf16x8*)WL)[(w * 32 + l15) * 16 + (ch ^ l7)];
        bf16x8 A1 = ((const bf16x8*)WL)[(w * 32 + 16 + l15) * 16 + (ch ^ l7)];
        #pragma unroll
        for (int nf = 0; nf < 4; ++nf) {
            bf16x8 Bf = ((const bf16x8*)XL)[(nf * 16 + l15) * 16 + (ch ^ l7)];
            acc2[0][nf] = __builtin_amdgcn_mfma_f32_16x16x32_bf16(A0, Bf, acc2[0][nf], 0, 0, 0);
            acc2[1][nf] = __builtin_amdgcn_mfma_f32_16x16x32_bf16(A1, Bf, acc2[1][nf], 0, 0, 0);
        }
    }
    #pragma unroll
    for (int mf = 0; mf < 2; ++mf)
        #pragma unroll
        for (int nf = 0; nf < 4; ++nf)
            #pragma unroll
            for (int i = 0; i < 4; ++i) {
                int row = w * 32 + mf * 16 + kg * 4 + i;
                int col = n0 + nf * 16 + l15;
                outp[((size_t)b * 128 + row) * HW + col] = f2bf(acc2[mf][nf][i]);
            }
}

// ---------------------------------------------------------------------------
// fused gates + final (round-9 shape: block = (b, nt, half), 4096 blocks,
// stage X once, single barrier) with pre-swizzled bf16 weights.
// out = x + out_s*sigmoid(Wgfs@out_f+bgfs) + out_f*sigmoid(Wgsf@out_s+bgsf)
// ---------------------------------------------------------------------------
__global__ __launch_bounds__(256)
void fuse2_k(const float* __restrict__ x, const unsigned short* __restrict__ outs,
             const unsigned short* __restrict__ outf,
             const int4* __restrict__ wgsf_bf, const float* __restrict__ bgsf,
             const int4* __restrict__ wgfs_bf, const float* __restrict__ bgfs,
             float* __restrict__ out)
{
    __shared__ short WS[64 * 128];  // 16 KB (this half of W_gsf)
    __shared__ short WF[64 * 128];  // 16 KB
    __shared__ short XS[64 * 128];  // 16 KB out_s^T tile (all 128 ch)
    __shared__ short XF[64 * 128];  // 16 KB out_f^T tile
    int t = threadIdx.x;
    int gb = blockIdx.x;
    int half = gb & 1;
    int nt = (gb >> 1) & 255;
    int b = gb >> 9;
    int n0 = nt << 6;

    // W halves: pre-swizzled chunks for rows [half*64, half*64+64)
    #pragma unroll
    for (int it = 0; it < 4; ++it) {
        ((int4*)WS)[it * 256 + t] = wgsf_bf[half * 1024 + it * 256 + t];
        ((int4*)WF)[it * 256 + t] = wgfs_bf[half * 1024 + it * 256 + t];
    }
    const unsigned short* sb = outs + (size_t)b * 128 * HW + n0;
    const unsigned short* fb = outf + (size_t)b * 128 * HW + n0;
    int nl = t & 63;
    #pragma unroll
    for (int it = 0; it < 4; ++it) {
        int c8 = (t >> 6) + it * 4;
        unsigned us[8], uf[8];
        #pragma unroll
        for (int j = 0; j < 8; ++j) {
            size_t a = (size_t)(c8 * 8 + j) * HW + nl;
            us[j] = sb[a];
            uf[j] = fb[a];
        }
        int4 ps, pf;
        ps.x = (int)(us[0] | (us[1] << 16)); ps.y = (int)(us[2] | (us[3] << 16));
        ps.z = (int)(us[4] | (us[5] << 16)); ps.w = (int)(us[6] | (us[7] << 16));
        pf.x = (int)(uf[0] | (uf[1] << 16)); pf.y = (int)(uf[2] | (uf[3] << 16));
        pf.z = (int)(uf[4] | (uf[5] << 16)); pf.w = (int)(uf[6] | (uf[7] << 16));
        ((int4*)XS)[nl * 16 + (c8 ^ (nl & 7))] = ps;
        ((int4*)XF)[nl * 16 + (c8 ^ (nl & 7))] = pf;
    }
    __syncthreads();

    int l = t & 63, w = t >> 6, kg = l >> 4, l15 = l & 15, l7 = l15 & 7;
    f32x4 aS[4], aF[4];
    #pragma unroll
    for (int nf = 0; nf < 4; ++nf) {
        aS[nf] = (f32x4){0.f, 0.f, 0.f, 0.f};
        aF[nf] = (f32x4){0.f, 0.f, 0.f, 0.f};
    }
    #pragma unroll
    for (int ks = 0; ks < 4; ++ks) {
        int ch = ks * 4 + kg;
        bf16x8 As = ((const bf16x8*)WS)[(w * 16 + l15) * 16 + (ch ^ l7)];
        bf16x8 Af = ((const bf16x8*)WF)[(w * 16 + l15) * 16 + (ch ^ l7)];
        #pragma unroll
        for (int nf = 0; nf < 4; ++nf) {
            bf16x8 Bs = ((const bf16x8*)XS)[(nf * 16 + l15) * 16 + (ch ^ l7)];
            bf16x8 Bf = ((const bf16x8*)XF)[(nf * 16 + l15) * 16 + (ch ^ l7)];
            aS[nf] = __builtin_amdgcn_mfma_f32_16x16x32_bf16(As, Bs, aS[nf], 0, 0, 0);
            aF[nf] = __builtin_amdgcn_mfma_f32_16x16x32_bf16(Af, Bf, aF[nf], 0, 0, 0);
        }
    }
    #pragma unroll
    for (int nf = 0; nf < 4; ++nf)
        #pragma unroll
        for (int i = 0; i < 4; ++i) {
            int row = half * 64 + w * 16 + kg * 4 + i;
            int cc = nf * 16 + l15;
            float gf = sigmoidf_(aS[nf][i] + bgsf[row]);   // gates out_f
            float gs = sigmoidf_(aF[nf][i] + bgfs[row]);   // gates out_s
            size_t gi = ((size_t)(b * 128) + row) * HW + n0 + cc;
            float os = bf2f(outs[gi]);
            float of = bf2f(outf[gi]);
            out[gi] = x[gi] + os * gs + of * gf;
        }
}

// ---------------------------------------------------------------------------
// FFT: radix-2 128-pt, LDS twiddles
// ---------------------------------------------------------------------------
__device__ __forceinline__ void fft_build_tw(float2* tw, int t)
{
    if (t < 64) {
        float ang = 0.049087385212340519f * (float)t;
        float sn, cs; sincosf(ang, &sn, &cs);
        tw[t] = make_float2(cs, sn);
    }
}

__device__ __forceinline__ void fft_stage_dif(float2 (*buf)[128], const float2* tw,
                                              int t, int s)
{
    int mh = 64 >> s;
    #pragma unroll
    for (int i = 0; i < 4; ++i) {
        int idx = t + i * 256;
        int rl = idx >> 6;
        int bf = idx & 63;
        int blk = bf >> (6 - s);
        int jj = bf & (mh - 1);
        int base = (blk << (7 - s)) + jj;
        float2 a = buf[rl][base];
        float2 b = buf[rl][base + mh];
        float2 w = tw[jj << s];
        float cs = w.x, sn = -w.y;
        float dx = a.x - b.x, dy = a.y - b.y;
        buf[rl][base] = make_float2(a.x + b.x, a.y + b.y);
        buf[rl][base + mh] = make_float2(dx * cs - dy * sn, dx * sn + dy * cs);
    }
}

__device__ __forceinline__ void fft_stage_dit(float2 (*buf)[128], const float2* tw,
                                              int t, int s)
{
    int mh = 64 >> s;
    #pragma unroll
    for (int i = 0; i < 4; ++i) {
        int idx = t + i * 256;
        int rl = idx >> 6;
        int bf = idx & 63;
        int blk = bf >> (6 - s);
        int jj = bf & (mh - 1);
        int base = (blk << (7 - s)) + jj;
        float2 a = buf[rl][base];
        float2 b = buf[rl][base + mh];
        float2 w = tw[jj << s];
        float cs = w.x, sn = w.y;
        float tx = b.x * cs - b.y * sn, ty = b.x * sn + b.y * cs;
        buf[rl][base] = make_float2(a.x + tx, a.y + ty);
        buf[rl][base + mh] = make_float2(a.x - tx, a.y - ty);
    }
}

__device__ __forceinline__ void fft16_fwd(float2 (*buf)[128], const float2* tw, int t)
{
    for (int s = 0; s < 7; ++s) { __syncthreads(); fft_stage_dif(buf, tw, t, s); }
    __syncthreads();
}
__device__ __forceinline__ void fft16_inv(float2 (*buf)[128], const float2* tw, int t)
{
    for (int s = 6; s >= 0; --s) { __syncthreads(); fft_stage_dit(buf, tw, t, s); }
    __syncthreads();
}

__global__ __launch_bounds__(256)
void fft_p1_k(const float* __restrict__ x, const unsigned short* __restrict__ sw,
              float2* __restrict__ A)
{
    __shared__ float2 buf[16][128];
    __shared__ float2 tw[64];
    int t = threadIdx.x;
    fft_build_tw(tw, t);
    int ch = blockIdx.x >> 3;
    int rg = blockIdx.x & 7;
    size_t base = (size_t)ch * HW + rg * 2048;
    #pragma unroll
    for (int i = 0; i < 8; ++i) {
        int idx = t + i * 256;
        int rl = idx >> 7, cc = idx & 127;
        buf[rl][cc] = make_float2(x[base + rl * 128 + cc],
                                  bf2f(sw[base + rl * 128 + cc]));
    }
    fft16_fwd(buf, tw, t);
    size_t abase = (size_t)ch * HW + rg * 16;
    #pragma unroll
    for (int i = 0; i < 8; ++i) {
        int idx = t + i * 256;
        int rl = idx & 15, k1 = idx >> 4;
        A[abase + (size_t)k1 * 128 + rl] = buf[rl][k1];
    }
}

__global__ __launch_bounds__(256)
void fft_p234_k(float2* __restrict__ A)
{
    __shared__ float2 buf[16][128];
    __shared__ float2 tw[64];
    int t = threadIdx.x;
    fft_build_tw(tw, t);
    int ch = blockIdx.x >> 3;
    int rg = blockIdx.x & 7;
    size_t cb = (size_t)ch * HW;

    #pragma unroll
    for (int i = 0; i < 8; ++i) {
        int idx = t + i * 256;
        int l = idx >> 7, cc = idx & 127;
        int k1l;
        if (rg == 0) k1l = (l < 2) ? l * 64 : (l < 9 ? l - 1 : 128 - (l - 8));
        else         k1l = (l < 8) ? 8 * rg + l : 128 - (8 * rg + l - 8);
        buf[l][cc] = A[cb + (size_t)brev7(k1l) * 128 + cc];
    }
    fft16_fwd(buf, tw, t);

    int nItems = (rg == 0) ? 1026 : 1024;
    for (int item = t; item < nItems; item += 256) {
        int lA, lB, k2;
        if (rg == 0) {
            if (item < 896) { int s = item >> 7; k2 = item & 127; lA = 2 + s; lB = 9 + s; }
            else            { int r = item - 896; lA = lB = r / 65; k2 = r % 65; }
        } else {
            int s = item >> 7; k2 = item & 127; lA = s; lB = 8 + s;
        }
        int i2 = brev7(k2), j2 = brev7((128 - k2) & 127);
        float2 z1 = buf[lA][i2];
        float2 z2 = buf[lB][j2];
        float2 X = make_float2(0.5f * (z1.x + z2.x), 0.5f * (z1.y - z2.y));
        float Dx = z1.x - z2.x, Dy = z1.y + z2.y;
        float2 Wf = make_float2(0.5f * Dy, -0.5f * Dx);
        float2 Y = make_float2(X.x * Wf.x - X.y * Wf.y, X.x * Wf.y + X.y * Wf.x);
        buf[lA][i2] = Y;
        buf[lB][j2] = make_float2(Y.x, -Y.y);
    }
    fft16_inv(buf, tw, t);

    #pragma unroll
    for (int i = 0; i < 8; ++i) {
        int idx = t + i * 256;
        int l = idx >> 7, cc = idx & 127;
        int k1l;
        if (rg == 0) k1l = (l < 2) ? l * 64 : (l < 9 ? l - 1 : 128 - (l - 8));
        else         k1l = (l < 8) ? 8 * rg + l : 128 - (8 * rg + l - 8);
        A[cb + (size_t)brev7(k1l) * 128 + cc] = buf[l][cc];
    }
}

__global__ __launch_bounds__(256)
void fft_p5_k(const float2* __restrict__ A, float* __restrict__ outp)
{
    __shared__ float2 buf[16][128];
    __shared__ float2 tw[64];
    int t = threadIdx.x;
    fft_build_tw(tw, t);
    int ch = blockIdx.x >> 3;
    int rg = blockIdx.x & 7;
    size_t abase = (size_t)ch * HW + rg * 16;
    #pragma unroll
    for (int i = 0; i < 8; ++i) {
        int idx = t + i * 256;
        int rl = idx & 15, i1 = idx >> 4;
        buf[rl][i1] = A[abase + (size_t)i1 * 128 + rl];
    }
    fft16_inv(buf, tw, t);
    const float scale = 1.f / 2097152.f;
    size_t obase = (size_t)ch * HW + rg * 2048;
    #pragma unroll
    for (int i = 0; i < 8; ++i) {
        int idx = t + i * 256;
        int rl = idx >> 7, cc = idx & 127;
        outp[obase + rl * 128 + cc] = buf[rl][cc].x * scale;
    }
}

// ---------------------------------------------------------------------------
// Workspace plan (128 MiB ws + d_out scratch):
//  ws[0,32):  V bf16 (phase A) -> out_f bf16 (phase B)
//  ws[32,64): out_s bf16
//  ws[64,96): swb bf16
//  ws[96,96.25): Wbf 7x32KB pre-swizzled bf16 weights (persistent)
//  d_out: vcb bf16 [0,32) / Gp [32,48) / G,S [48,48.6) (phase A);
//         A [0,32) / pre [32,48) (phase B); final output (fuse2).
// ---------------------------------------------------------------------------
extern "C" void kernel_launch(void* const* d_in, const int* in_sizes, int n_in,
                              void* d_out, int out_size, void* d_ws, size_t ws_size,
                              hipStream_t stream)
{
    const float* x        = (const float*)d_in[0];
    const float* W_qkv    = (const float*)d_in[1];
    const float* W_dw     = (const float*)d_in[2];
    const float* W_proj_s = (const float*)d_in[3];
    const float* scale_s  = (const float*)d_in[4];
    const float* W_ff1    = (const float*)d_in[5];
    const float* W_ff2    = (const float*)d_in[6];
    const float* W_proj_f = (const float*)d_in[7];
    const float* W_gsf    = (const float*)d_in[8];
    const float* b_gsf    = (const float*)d_in[9];
    const float* W_gfs    = (const float*)d_in[10];
    const float* b_gfs    = (const float*)d_in[11];
    float* out = (float*)d_out;

    char* ws = (char*)d_ws;
    const size_t MB32 = 33554432ull;
    const size_t MB64 = 67108864ull;
    const size_t MB96 = 100663296ull;
    unsigned short* V     = (unsigned short*)(ws);          // 32 MiB phase A
    unsigned short* out_s = (unsigned short*)(ws + MB32);   // 32 MiB
    unsigned short* swb   = (unsigned short*)(ws + MB64);   // 32 MiB bf16
    unsigned short* out_fp= (unsigned short*)(ws);          // 32 MiB (V dead)
    int4* Wbf4            = (int4*)(ws + MB96);             // 224 KiB
    unsigned short* vcb   = (unsigned short*)out;           // 32 MiB d_out lo
    float* Gp  = out + 8388608;                             // 16 MiB d_out[32,48)
    float* G   = out + 8388608 + 4194304;                   // 512 KiB
    float* S   = G + 131072;                                // 64 KiB
    float2* A  = (float2*)out;                              // 32 MiB phase B
    float* pre = out + 8388608;                             // 16 MiB phase B

    // --- weight pre-conversion (bf16, pre-swizzled) ---
    // slices: 0=W_v 1=W_proj_s 2=W_ff1 3=W_ff2 4=W_proj_f 5=W_gsf 6=W_gfs
    wprep_k<<<56, 256, 0, stream>>>(W_qkv + 256 * 128, W_proj_s, W_ff1, W_ff2,
                                    W_proj_f, W_gsf, W_gfs, Wbf4);

    // --- spatial attention branch ---
    conv_mfma_k<<<2048, 256, 0, stream>>>(x, Wbf4 + 0 * 2048, V);
    dwconv_k<<<16384, 256, 0, stream>>>(V, W_dw, vcb);
    gram_mfma_k<<<256, 256, 0, stream>>>(x, Gp);
    gram_reduce_k<<<512, 256, 0, stream>>>(Gp, G);
    attn_s2_k<<<64, 256, 0, stream>>>(G, W_qkv, scale_s, S);
    proj_s_pv_k<<<2048, 256, 0, stream>>>(V, vcb, S, Wbf4 + 1 * 2048, out_s);

    // --- frequency branch ---
    ff_fused_k<<<2048, 256, 0, stream>>>(x, Wbf4 + 2 * 2048, Wbf4 + 3 * 2048, swb);
    for (int chunk = 0; chunk < 4; ++chunk) {
        const float* xc  = x   + (size_t)chunk * 4194304;
        const unsigned short* swc = swb + (size_t)chunk * 4194304;
        unsigned short* ofc = out_fp + (size_t)chunk * 4194304;
        fft_p1_k<<<2048, 256, 0, stream>>>(xc, swc, A);
        fft_p234_k<<<2048, 256, 0, stream>>>(A);
        fft_p5_k<<<2048, 256, 0, stream>>>(A, pre);
        conv_mfma_k<<<512, 256, 0, stream>>>(pre, Wbf4 + 4 * 2048, ofc);
    }

    // --- fused gates + final output ---
    fuse2_k<<<4096, 256, 0, stream>>>(x, out_s, out_fp,
                                      Wbf4 + 5 * 2048, b_gsf,
                                      Wbf4 + 6 * 2048, b_gfs, out);
}

// Round 12
// 467.204 us; speedup vs baseline: 1.2424x; 1.1561x over previous
//
#include <hip/hip_runtime.h>
#include <math.h>

#define HW 16384

typedef __attribute__((ext_vector_type(8))) short bf16x8;
typedef __attribute__((ext_vector_type(4))) float f32x4;

__device__ __forceinline__ unsigned f2bf_pk(float a, float b)
{
    unsigned ua = __float_as_uint(a), ub = __float_as_uint(b);
    ua = (ua + 0x7FFFu + ((ua >> 16) & 1u)) >> 16;   // RTN-even
    ub = (ub + 0x7FFFu + ((ub >> 16) & 1u)) >> 16;
    return (ua & 0xFFFFu) | (ub << 16);
}
__device__ __forceinline__ unsigned short f2bf(float a)
{
    unsigned ua = __float_as_uint(a);
    ua = (ua + 0x7FFFu + ((ua >> 16) & 1u)) >> 16;
    return (unsigned short)ua;
}
__device__ __forceinline__ float bf2f(unsigned short u)
{
    return __uint_as_float(((unsigned)u) << 16);
}
__device__ __forceinline__ int brev7(int v) { return (int)(__brev((unsigned)v) >> 25); }
__device__ __forceinline__ float sigmoidf_(float v) { return 1.f / (1.f + expf(-v)); }

// ---------------------------------------------------------------------------
// wprep: convert 7 weight matrices (128x128 fp32) to bf16 in pre-swizzled
// LDS chunk order: slot s holds row o=s>>4, col-octet c16 = (s&15) ^ (o&7).
// ---------------------------------------------------------------------------
__global__ __launch_bounds__(256)
void wprep_k(const float* __restrict__ w0, const float* __restrict__ w1,
             const float* __restrict__ w2, const float* __restrict__ w3,
             const float* __restrict__ w4, const float* __restrict__ w5,
             const float* __restrict__ w6, int4* __restrict__ Wbf4)
{
    int m = blockIdx.x >> 3;
    int slot = (blockIdx.x & 7) * 256 + threadIdx.x;   // 0..2047
    const float* src;
    switch (m) {
        case 0: src = w0; break;
        case 1: src = w1; break;
        case 2: src = w2; break;
        case 3: src = w3; break;
        case 4: src = w4; break;
        case 5: src = w5; break;
        default: src = w6; break;
    }
    int o = slot >> 4;
    int c16 = (slot & 15) ^ (o & 7);
    const float* p = src + o * 128 + c16 * 8;
    int4 pk;
    pk.x = f2bf_pk(p[0], p[1]); pk.y = f2bf_pk(p[2], p[3]);
    pk.z = f2bf_pk(p[4], p[5]); pk.w = f2bf_pk(p[6], p[7]);
    Wbf4[m * 2048 + slot] = pk;
}

// ---------------------------------------------------------------------------
// MFMA conv1x1, fp32 in -> bf16 out, pre-swizzled bf16 weights.
// Tile O=128 x N=64, K=128.
// ---------------------------------------------------------------------------
__global__ __launch_bounds__(256)
void conv_mfma_k(const float* __restrict__ in, const int4* __restrict__ wbf,
                 unsigned short* __restrict__ out)
{
    __shared__ short WL[128 * 128];   // 32 KB
    __shared__ short XL[64 * 128];    // 16 KB
    int t = threadIdx.x;
    int gb = blockIdx.x;
    int b = gb >> 8;
    int n0 = (gb & 255) << 6;

    #pragma unroll
    for (int it = 0; it < 8; ++it)
        ((int4*)WL)[it * 256 + t] = wbf[it * 256 + t];

    const float* inb = in + (size_t)b * 128 * HW + n0;
    int nl = t & 63;
    #pragma unroll
    for (int it = 0; it < 4; ++it) {
        int c8 = (t >> 6) + it * 4;
        float v[8];
        #pragma unroll
        for (int j = 0; j < 8; ++j) v[j] = inb[(size_t)(c8 * 8 + j) * HW + nl];
        int4 p;
        p.x = f2bf_pk(v[0], v[1]); p.y = f2bf_pk(v[2], v[3]);
        p.z = f2bf_pk(v[4], v[5]); p.w = f2bf_pk(v[6], v[7]);
        ((int4*)XL)[nl * 16 + (c8 ^ (nl & 7))] = p;
    }
    __syncthreads();

    int l = t & 63, w = t >> 6, kg = l >> 4, l15 = l & 15, l7 = l15 & 7;
    f32x4 acc[2][4];
    #pragma unroll
    for (int mf = 0; mf < 2; ++mf)
        #pragma unroll
        for (int nf = 0; nf < 4; ++nf) acc[mf][nf] = (f32x4){0.f, 0.f, 0.f, 0.f};
    #pragma unroll
    for (int ks = 0; ks < 4; ++ks) {
        int ch = ks * 4 + kg;
        bf16x8 A0 = ((const bf16x8*)WL)[(w * 32 + l15) * 16 + (ch ^ l7)];
        bf16x8 A1 = ((const bf16x8*)WL)[(w * 32 + 16 + l15) * 16 + (ch ^ l7)];
        #pragma unroll
        for (int nf = 0; nf < 4; ++nf) {
            bf16x8 Bf = ((const bf16x8*)XL)[(nf * 16 + l15) * 16 + (ch ^ l7)];
            acc[0][nf] = __builtin_amdgcn_mfma_f32_16x16x32_bf16(A0, Bf, acc[0][nf], 0, 0, 0);
            acc[1][nf] = __builtin_amdgcn_mfma_f32_16x16x32_bf16(A1, Bf, acc[1][nf], 0, 0, 0);
        }
    }
    #pragma unroll
    for (int mf = 0; mf < 2; ++mf)
        #pragma unroll
        for (int nf = 0; nf < 4; ++nf)
            #pragma unroll
            for (int i = 0; i < 4; ++i) {
                int row = w * 32 + mf * 16 + kg * 4 + i;
                int col = n0 + nf * 16 + l15;
                out[((size_t)b * 128 + row) * HW + col] = f2bf(acc[mf][nf][i]);
            }
}

// ---------------------------------------------------------------------------
// MFMA conv1x1, bf16 in -> bf16 out (bit-repack staging, no cvt VALU)
// ---------------------------------------------------------------------------
__global__ __launch_bounds__(256)
void conv_mfma_bf_k(const unsigned short* __restrict__ in,
                    const int4* __restrict__ wbf,
                    unsigned short* __restrict__ out)
{
    __shared__ short WL[128 * 128];   // 32 KB
    __shared__ short XL[64 * 128];    // 16 KB
    int t = threadIdx.x;
    int gb = blockIdx.x;
    int b = gb >> 8;
    int n0 = (gb & 255) << 6;

    #pragma unroll
    for (int it = 0; it < 8; ++it)
        ((int4*)WL)[it * 256 + t] = wbf[it * 256 + t];

    const unsigned short* inb = in + (size_t)b * 128 * HW + n0;
    int nl = t & 63;
    #pragma unroll
    for (int it = 0; it < 4; ++it) {
        int c8 = (t >> 6) + it * 4;
        unsigned u[8];
        #pragma unroll
        for (int j = 0; j < 8; ++j) u[j] = inb[(size_t)(c8 * 8 + j) * HW + nl];
        int4 p;
        p.x = (int)(u[0] | (u[1] << 16)); p.y = (int)(u[2] | (u[3] << 16));
        p.z = (int)(u[4] | (u[5] << 16)); p.w = (int)(u[6] | (u[7] << 16));
        ((int4*)XL)[nl * 16 + (c8 ^ (nl & 7))] = p;
    }
    __syncthreads();

    int l = t & 63, w = t >> 6, kg = l >> 4, l15 = l & 15, l7 = l15 & 7;
    f32x4 acc[2][4];
    #pragma unroll
    for (int mf = 0; mf < 2; ++mf)
        #pragma unroll
        for (int nf = 0; nf < 4; ++nf) acc[mf][nf] = (f32x4){0.f, 0.f, 0.f, 0.f};
    #pragma unroll
    for (int ks = 0; ks < 4; ++ks) {
        int ch = ks * 4 + kg;
        bf16x8 A0 = ((const bf16x8*)WL)[(w * 32 + l15) * 16 + (ch ^ l7)];
        bf16x8 A1 = ((const bf16x8*)WL)[(w * 32 + 16 + l15) * 16 + (ch ^ l7)];
        #pragma unroll
        for (int nf = 0; nf < 4; ++nf) {
            bf16x8 Bf = ((const bf16x8*)XL)[(nf * 16 + l15) * 16 + (ch ^ l7)];
            acc[0][nf] = __builtin_amdgcn_mfma_f32_16x16x32_bf16(A0, Bf, acc[0][nf], 0, 0, 0);
            acc[1][nf] = __builtin_amdgcn_mfma_f32_16x16x32_bf16(A1, Bf, acc[1][nf], 0, 0, 0);
        }
    }
    #pragma unroll
    for (int mf = 0; mf < 2; ++mf)
        #pragma unroll
        for (int nf = 0; nf < 4; ++nf)
            #pragma unroll
            for (int i = 0; i < 4; ++i) {
                int row = w * 32 + mf * 16 + kg * 4 + i;
                int col = n0 + nf * 16 + l15;
                out[((size_t)b * 128 + row) * HW + col] = f2bf(acc[mf][nf][i]);
            }
}

// ---------------------------------------------------------------------------
// depthwise 3x3 SAME, x4 vectorized, bf16 in -> bf16 out
// ---------------------------------------------------------------------------
__global__ __launch_bounds__(256)
void dwconv_k(const unsigned short* __restrict__ V, const float* __restrict__ Wdw,
              unsigned short* __restrict__ vcb)
{
    int tid = blockIdx.x * 256 + threadIdx.x;
    int e4 = tid & 4095;
    int bc = tid >> 12;
    int c = bc & 127;
    int y = e4 >> 5;
    int x0 = (e4 & 31) << 2;
    const unsigned short* vin = V + (size_t)bc * HW;
    float wf[9];
    #pragma unroll
    for (int i = 0; i < 9; ++i) wf[i] = Wdw[c * 9 + i];
    float a0 = 0.f, a1 = 0.f, a2 = 0.f, a3 = 0.f;
    #pragma unroll
    for (int dy = 0; dy < 3; ++dy) {
        int yy = y + dy - 1;
        if (yy < 0 || yy > 127) continue;
        const unsigned short* r = vin + yy * 128;
        uint2 mu = *(const uint2*)(r + x0);
        float m0 = bf2f((unsigned short)(mu.x & 0xFFFF));
        float m1 = bf2f((unsigned short)(mu.x >> 16));
        float m2 = bf2f((unsigned short)(mu.y & 0xFFFF));
        float m3 = bf2f((unsigned short)(mu.y >> 16));
        float left  = (x0 > 0)   ? bf2f(r[x0 - 1]) : 0.f;
        float right = (x0 < 124) ? bf2f(r[x0 + 4]) : 0.f;
        float w0 = wf[dy * 3], w1 = wf[dy * 3 + 1], w2 = wf[dy * 3 + 2];
        a0 += w0 * left + w1 * m0 + w2 * m1;
        a1 += w0 * m0   + w1 * m1 + w2 * m2;
        a2 += w0 * m1   + w1 * m2 + w2 * m3;
        a3 += w0 * m2   + w1 * m3 + w2 * right;
    }
    uint2 r2;
    r2.x = f2bf_pk(a0, a1);
    r2.y = f2bf_pk(a2, a3);
    *(uint2*)(vcb + (size_t)bc * HW + y * 128 + x0) = r2;
}

// ---------------------------------------------------------------------------
// MFMA Gram partials: 32 slices of 512 px. blk = b*32+ks. grid 256.
// ---------------------------------------------------------------------------
__global__ __launch_bounds__(256)
void gram_mfma_k(const float* __restrict__ x, float* __restrict__ Gp)
{
    __shared__ short XL[128 * 128];
    int t = threadIdx.x;
    int blk = blockIdx.x;
    int b = blk >> 5, ks = blk & 31;
    const float* xb = x + (size_t)b * 128 * HW + ks * 512;
    int l = t & 63, w = t >> 6, kg = l >> 4, l15 = l & 15, l7 = l15 & 7;

    f32x4 acc[2][8];
    #pragma unroll
    for (int mf = 0; mf < 2; ++mf)
        #pragma unroll
        for (int nf = 0; nf < 8; ++nf) acc[mf][nf] = (f32x4){0.f, 0.f, 0.f, 0.f};

    for (int kc = 0; kc < 4; ++kc) {
        __syncthreads();
        #pragma unroll
        for (int it = 0; it < 8; ++it) {
            int g = it * 256 + t;
            int row = g >> 4, oct = g & 15;
            const float* p = xb + (size_t)row * HW + kc * 128 + oct * 8;
            int4 pk;
            pk.x = f2bf_pk(p[0], p[1]); pk.y = f2bf_pk(p[2], p[3]);
            pk.z = f2bf_pk(p[4], p[5]); pk.w = f2bf_pk(p[6], p[7]);
            ((int4*)XL)[row * 16 + (oct ^ (row & 7))] = pk;
        }
        __syncthreads();
        #pragma unroll
        for (int s = 0; s < 4; ++s) {
            int oct = s * 4 + kg;
            bf16x8 A0 = ((const bf16x8*)XL)[(w * 32 + l15) * 16 + (oct ^ l7)];
            bf16x8 A1 = ((const bf16x8*)XL)[(w * 32 + 16 + l15) * 16 + (oct ^ l7)];
            #pragma unroll
            for (int nf = 0; nf < 8; ++nf) {
                bf16x8 Bf = ((const bf16x8*)XL)[(nf * 16 + l15) * 16 + (oct ^ l7)];
                acc[0][nf] = __builtin_amdgcn_mfma_f32_16x16x32_bf16(A0, Bf, acc[0][nf], 0, 0, 0);
                acc[1][nf] = __builtin_amdgcn_mfma_f32_16x16x32_bf16(A1, Bf, acc[1][nf], 0, 0, 0);
            }
        }
    }
    float* gp = Gp + (size_t)blk * 16384;
    #pragma unroll
    for (int mf = 0; mf < 2; ++mf)
        #pragma unroll
        for (int nf = 0; nf < 8; ++nf)
            #pragma unroll
            for (int i = 0; i < 4; ++i) {
                int row = w * 32 + mf * 16 + kg * 4 + i;
                int col = nf * 16 + l15;
                gp[row * 128 + col] = acc[mf][nf][i];
            }
}

__global__ void gram_reduce_k(const float* __restrict__ Gp, float* __restrict__ G)
{
    int idx = blockIdx.x * 256 + threadIdx.x;   // 8*16384
    int b = idx >> 14;
    int ij = idx & 16383;
    const float* gp = Gp + (size_t)(b * 32) * 16384 + ij;
    float s = 0.f;
    #pragma unroll
    for (int ks = 0; ks < 32; ++ks) s += gp[(size_t)ks * 16384];
    G[idx] = s;
}

// ---------------------------------------------------------------------------
// S_h = softmax( (Wq_h G Wk_h^T) * scale[h] )
// ---------------------------------------------------------------------------
__global__ __launch_bounds__(256)
void attn_s2_k(const float* __restrict__ G, const float* __restrict__ Wqkv,
               const float* __restrict__ scale, float* __restrict__ S)
{
    __shared__ float Wq[16][129];
    __shared__ float Wk[16][129];
    __shared__ float Ts[16][129];
    int bh = blockIdx.x;
    int b = bh >> 3, h = bh & 7;
    int t = threadIdx.x;
    #pragma unroll
    for (int i = 0; i < 8; ++i) {
        int idx = t + i * 256;
        int r = idx >> 7, ci = idx & 127;
        Wq[r][ci] = Wqkv[(size_t)(h * 16 + r) * 128 + ci];
        Wk[r][ci] = Wqkv[(size_t)(128 + h * 16 + r) * 128 + ci];
    }
    __syncthreads();
    const float* Gb = G + (size_t)b * 16384;
    #pragma unroll
    for (int i = 0; i < 8; ++i) {
        int idx = t + i * 256;
        int c = idx >> 7, col = idx & 127;
        float s = 0.f;
        #pragma unroll 8
        for (int ci = 0; ci < 128; ++ci)
            s += Wq[c][ci] * Gb[ci * 128 + col];
        Ts[c][col] = s;
    }
    __syncthreads();
    int c = t >> 4, d = t & 15;
    float s = 0.f;
    #pragma unroll 8
    for (int col = 0; col < 128; ++col)
        s += Ts[c][col] * Wk[d][col];
    s *= scale[h];
    float m = s;
    #pragma unroll
    for (int w = 1; w < 16; w <<= 1)
        m = fmaxf(m, __shfl_xor(m, w, 64));
    float e = expf(s - m);
    float sum = e;
    #pragma unroll
    for (int w = 1; w < 16; w <<= 1)
        sum += __shfl_xor(sum, w, 64);
    S[(size_t)bh * 256 + t] = e / sum;
}

// ---------------------------------------------------------------------------
// proj_s with fused PV: out_s = W_proj_s @ (PV(V) + vconv), bf16 in/out.
// ---------------------------------------------------------------------------
__global__ __launch_bounds__(256)
void proj_s_pv_k(const unsigned short* __restrict__ V,
                 const unsigned short* __restrict__ vcb,
                 const float* __restrict__ S, const int4* __restrict__ wbf,
                 unsigned short* __restrict__ out_s)
{
    __shared__ short WL[128 * 128];   // 32 KB
    __shared__ short XL[64 * 128];    // 16 KB
    __shared__ float SL[2048];        // 8 KB
    int t = threadIdx.x;
    int gb = blockIdx.x;
    int b = gb >> 8;
    int n0 = (gb & 255) << 6;

    #pragma unroll
    for (int it = 0; it < 8; ++it)
        ((int4*)WL)[it * 256 + t] = wbf[it * 256 + t];
    #pragma unroll
    for (int i = 0; i < 8; ++i)
        SL[i * 256 + t] = S[(size_t)b * 2048 + i * 256 + t];
    __syncthreads();

    int col = t & 63, w = t >> 6;
    #pragma unroll
    for (int hh = 0; hh < 2; ++hh) {
        int h = w * 2 + hh;
        float v[16];
        #pragma unroll
        for (int d = 0; d < 16; ++d)
            v[d] = bf2f(V[((size_t)(b * 128 + h * 16 + d)) * HW + n0 + col]);
        float o[16];
        #pragma unroll
        for (int c = 0; c < 16; ++c) {
            const float* sl = SL + h * 256 + c * 16;
            float s = 0.f;
            #pragma unroll
            for (int d = 0; d < 16; ++d) s += sl[d] * v[d];
            o[c] = s + bf2f(vcb[((size_t)(b * 128 + h * 16 + c)) * HW + n0 + col]);
        }
        #pragma unroll
        for (int oc = 0; oc < 2; ++oc) {
            int octet = h * 2 + oc;
            int4 p;
            p.x = f2bf_pk(o[oc * 8 + 0], o[oc * 8 + 1]);
            p.y = f2bf_pk(o[oc * 8 + 2], o[oc * 8 + 3]);
            p.z = f2bf_pk(o[oc * 8 + 4], o[oc * 8 + 5]);
            p.w = f2bf_pk(o[oc * 8 + 6], o[oc * 8 + 7]);
            ((int4*)XL)[col * 16 + (octet ^ (col & 7))] = p;
        }
    }
    __syncthreads();

    int l = t & 63, kg = l >> 4, l15 = l & 15, l7 = l15 & 7;
    f32x4 acc[2][4];
    #pragma unroll
    for (int mf = 0; mf < 2; ++mf)
        #pragma unroll
        for (int nf = 0; nf < 4; ++nf) acc[mf][nf] = (f32x4){0.f, 0.f, 0.f, 0.f};
    #pragma unroll
    for (int ks = 0; ks < 4; ++ks) {
        int ch = ks * 4 + kg;
        bf16x8 A0 = ((const bf16x8*)WL)[(w * 32 + l15) * 16 + (ch ^ l7)];
        bf16x8 A1 = ((const bf16x8*)WL)[(w * 32 + 16 + l15) * 16 + (ch ^ l7)];
        #pragma unroll
        for (int nf = 0; nf < 4; ++nf) {
            bf16x8 Bf = ((const bf16x8*)XL)[(nf * 16 + l15) * 16 + (ch ^ l7)];
            acc[0][nf] = __builtin_amdgcn_mfma_f32_16x16x32_bf16(A0, Bf, acc[0][nf], 0, 0, 0);
            acc[1][nf] = __builtin_amdgcn_mfma_f32_16x16x32_bf16(A1, Bf, acc[1][nf], 0, 0, 0);
        }
    }
    #pragma unroll
    for (int mf = 0; mf < 2; ++mf)
        #pragma unroll
        for (int nf = 0; nf < 4; ++nf)
            #pragma unroll
            for (int i = 0; i < 4; ++i) {
                int row = w * 32 + mf * 16 + kg * 4 + i;
                int colg = n0 + nf * 16 + l15;
                out_s[((size_t)b * 128 + row) * HW + colg] = f2bf(acc[mf][nf][i]);
            }
}

// ---------------------------------------------------------------------------
// fused ff1 (GELU) + ff2: swb = W_ff2 @ gelu(W_ff1 @ x). bf16 out.
// ---------------------------------------------------------------------------
__global__ __launch_bounds__(256)
void ff_fused_k(const float* __restrict__ x, const int4* __restrict__ w1bf,
                const int4* __restrict__ w2bf, unsigned short* __restrict__ outp)
{
    __shared__ short WL[128 * 128];   // 32 KB (W1 then W2)
    __shared__ short XL[64 * 128];    // 16 KB (x^T then gelu(mid)^T)
    int t = threadIdx.x;
    int gb = blockIdx.x;
    int b = gb >> 8;
    int n0 = (gb & 255) << 6;

    #pragma unroll
    for (int it = 0; it < 8; ++it)
        ((int4*)WL)[it * 256 + t] = w1bf[it * 256 + t];

    const float* inb = x + (size_t)b * 128 * HW + n0;
    int nl = t & 63;
    #pragma unroll
    for (int it = 0; it < 4; ++it) {
        int c8 = (t >> 6) + it * 4;
        float v[8];
        #pragma unroll
        for (int j = 0; j < 8; ++j) v[j] = inb[(size_t)(c8 * 8 + j) * HW + nl];
        int4 p;
        p.x = f2bf_pk(v[0], v[1]); p.y = f2bf_pk(v[2], v[3]);
        p.z = f2bf_pk(v[4], v[5]); p.w = f2bf_pk(v[6], v[7]);
        ((int4*)XL)[nl * 16 + (c8 ^ (nl & 7))] = p;
    }
    __syncthreads();

    int l = t & 63, w = t >> 6, kg = l >> 4, l15 = l & 15, l7 = l15 & 7;
    f32x4 acc[2][4];
    #pragma unroll
    for (int mf = 0; mf < 2; ++mf)
        #pragma unroll
        for (int nf = 0; nf < 4; ++nf) acc[mf][nf] = (f32x4){0.f, 0.f, 0.f, 0.f};
    #pragma unroll
    for (int ks = 0; ks < 4; ++ks) {
        int ch = ks * 4 + kg;
        bf16x8 A0 = ((const bf16x8*)WL)[(w * 32 + l15) * 16 + (ch ^ l7)];
        bf16x8 A1 = ((const bf16x8*)WL)[(w * 32 + 16 + l15) * 16 + (ch ^ l7)];
        #pragma unroll
        for (int nf = 0; nf < 4; ++nf) {
            bf16x8 Bf = ((const bf16x8*)XL)[(nf * 16 + l15) * 16 + (ch ^ l7)];
            acc[0][nf] = __builtin_amdgcn_mfma_f32_16x16x32_bf16(A0, Bf, acc[0][nf], 0, 0, 0);
            acc[1][nf] = __builtin_amdgcn_mfma_f32_16x16x32_bf16(A1, Bf, acc[1][nf], 0, 0, 0);
        }
    }
    __syncthreads();   // all GEMM1 LDS reads done

    #pragma unroll
    for (int it = 0; it < 8; ++it)
        ((int4*)WL)[it * 256 + t] = w2bf[it * 256 + t];
    #pragma unroll
    for (int mf = 0; mf < 2; ++mf)
        #pragma unroll
        for (int nf = 0; nf < 4; ++nf) {
            float g4[4];
            #pragma unroll
            for (int i = 0; i < 4; ++i) {
                float v = acc[mf][nf][i];
                g4[i] = 0.5f * v * (1.0f + erff(v * 0.70710678118654752f));
            }
            int col = nf * 16 + l15;
            int r0 = w * 32 + mf * 16 + kg * 4;
            int octet = r0 >> 3;
            uint2 pk2;
            pk2.x = f2bf_pk(g4[0], g4[1]);
            pk2.y = f2bf_pk(g4[2], g4[3]);
            ((uint2*)XL)[(col * 16 + (octet ^ (col & 7))) * 2 + (kg & 1)] = pk2;
        }
    __syncthreads();

    f32x4 acc2[2][4];
    #pragma unroll
    for (int mf = 0; mf < 2; ++mf)
        #pragma unroll
        for (int nf = 0; nf < 4; ++nf) acc2[mf][nf] = (f32x4){0.f, 0.f, 0.f, 0.f};
    #pragma unroll
    for (int ks = 0; ks < 4; ++ks) {
        int ch = ks * 4 + kg;
        bf16x8 A0 = ((const bf16x8*)WL)[(w * 32 + l15) * 16 + (ch ^ l7)];
        bf16x8 A1 = ((const bf16x8*)WL)[(w * 32 + 16 + l15) * 16 + (ch ^ l7)];
        #pragma unroll
        for (int nf = 0; nf < 4; ++nf) {
            bf16x8 Bf = ((const bf16x8*)XL)[(nf * 16 + l15) * 16 + (ch ^ l7)];
            acc2[0][nf] = __builtin_amdgcn_mfma_f32_16x16x32_bf16(A0, Bf, acc2[0][nf], 0, 0, 0);
            acc2[1][nf] = __builtin_amdgcn_mfma_f32_16x16x32_bf16(A1, Bf, acc2[1][nf], 0, 0, 0);
        }
    }
    #pragma unroll
    for (int mf = 0; mf < 2; ++mf)
        #pragma unroll
        for (int nf = 0; nf < 4; ++nf)
            #pragma unroll
            for (int i = 0; i < 4; ++i) {
                int row = w * 32 + mf * 16 + kg * 4 + i;
                int col = n0 + nf * 16 + l15;
                outp[((size_t)b * 128 + row) * HW + col] = f2bf(acc2[mf][nf][i]);
            }
}

// ---------------------------------------------------------------------------
// fused gates + final: block = (b, nt, half), 4096 blocks, single barrier,
// pre-swizzled bf16 weights.
// out = x + out_s*sigmoid(Wgfs@out_f+bgfs) + out_f*sigmoid(Wgsf@out_s+bgsf)
// ---------------------------------------------------------------------------
__global__ __launch_bounds__(256)
void fuse2_k(const float* __restrict__ x, const unsigned short* __restrict__ outs,
             const unsigned short* __restrict__ outf,
             const int4* __restrict__ wgsf_bf, const float* __restrict__ bgsf,
             const int4* __restrict__ wgfs_bf, const float* __restrict__ bgfs,
             float* __restrict__ out)
{
    __shared__ short WS[64 * 128];  // 16 KB (this half of W_gsf)
    __shared__ short WF[64 * 128];  // 16 KB
    __shared__ short XS[64 * 128];  // 16 KB out_s^T tile (all 128 ch)
    __shared__ short XF[64 * 128];  // 16 KB out_f^T tile
    int t = threadIdx.x;
    int gb = blockIdx.x;
    int half = gb & 1;
    int nt = (gb >> 1) & 255;
    int b = gb >> 9;
    int n0 = nt << 6;

    #pragma unroll
    for (int it = 0; it < 4; ++it) {
        ((int4*)WS)[it * 256 + t] = wgsf_bf[half * 1024 + it * 256 + t];
        ((int4*)WF)[it * 256 + t] = wgfs_bf[half * 1024 + it * 256 + t];
    }
    const unsigned short* sb = outs + (size_t)b * 128 * HW + n0;
    const unsigned short* fb = outf + (size_t)b * 128 * HW + n0;
    int nl = t & 63;
    #pragma unroll
    for (int it = 0; it < 4; ++it) {
        int c8 = (t >> 6) + it * 4;
        unsigned us[8], uf[8];
        #pragma unroll
        for (int j = 0; j < 8; ++j) {
            size_t a = (size_t)(c8 * 8 + j) * HW + nl;
            us[j] = sb[a];
            uf[j] = fb[a];
        }
        int4 ps, pf;
        ps.x = (int)(us[0] | (us[1] << 16)); ps.y = (int)(us[2] | (us[3] << 16));
        ps.z = (int)(us[4] | (us[5] << 16)); ps.w = (int)(us[6] | (us[7] << 16));
        pf.x = (int)(uf[0] | (uf[1] << 16)); pf.y = (int)(uf[2] | (uf[3] << 16));
        pf.z = (int)(uf[4] | (uf[5] << 16)); pf.w = (int)(uf[6] | (uf[7] << 16));
        ((int4*)XS)[nl * 16 + (c8 ^ (nl & 7))] = ps;
        ((int4*)XF)[nl * 16 + (c8 ^ (nl & 7))] = pf;
    }
    __syncthreads();

    int l = t & 63, w = t >> 6, kg = l >> 4, l15 = l & 15, l7 = l15 & 7;
    f32x4 aS[4], aF[4];
    #pragma unroll
    for (int nf = 0; nf < 4; ++nf) {
        aS[nf] = (f32x4){0.f, 0.f, 0.f, 0.f};
        aF[nf] = (f32x4){0.f, 0.f, 0.f, 0.f};
    }
    #pragma unroll
    for (int ks = 0; ks < 4; ++ks) {
        int ch = ks * 4 + kg;
        bf16x8 As = ((const bf16x8*)WS)[(w * 16 + l15) * 16 + (ch ^ l7)];
        bf16x8 Af = ((const bf16x8*)WF)[(w * 16 + l15) * 16 + (ch ^ l7)];
        #pragma unroll
        for (int nf = 0; nf < 4; ++nf) {
            bf16x8 Bs = ((const bf16x8*)XS)[(nf * 16 + l15) * 16 + (ch ^ l7)];
            bf16x8 Bf = ((const bf16x8*)XF)[(nf * 16 + l15) * 16 + (ch ^ l7)];
            aS[nf] = __builtin_amdgcn_mfma_f32_16x16x32_bf16(As, Bs, aS[nf], 0, 0, 0);
            aF[nf] = __builtin_amdgcn_mfma_f32_16x16x32_bf16(Af, Bf, aF[nf], 0, 0, 0);
        }
    }
    #pragma unroll
    for (int nf = 0; nf < 4; ++nf)
        #pragma unroll
        for (int i = 0; i < 4; ++i) {
            int row = half * 64 + w * 16 + kg * 4 + i;
            int cc = nf * 16 + l15;
            float gf = sigmoidf_(aS[nf][i] + bgsf[row]);   // gates out_f
            float gs = sigmoidf_(aF[nf][i] + bgfs[row]);   // gates out_s
            size_t gi = ((size_t)(b * 128) + row) * HW + n0 + cc;
            float os = bf2f(outs[gi]);
            float of = bf2f(outf[gi]);
            out[gi] = x[gi] + os * gs + of * gf;
        }
}

// ---------------------------------------------------------------------------
// FFT: radix-2 128-pt, LDS twiddles. A is complex bf16 (packed uint).
// ---------------------------------------------------------------------------
__device__ __forceinline__ void fft_build_tw(float2* tw, int t)
{
    if (t < 64) {
        float ang = 0.049087385212340519f * (float)t;
        float sn, cs; sincosf(ang, &sn, &cs);
        tw[t] = make_float2(cs, sn);
    }
}

__device__ __forceinline__ void fft_stage_dif(float2 (*buf)[128], const float2* tw,
                                              int t, int s)
{
    int mh = 64 >> s;
    #pragma unroll
    for (int i = 0; i < 4; ++i) {
        int idx = t + i * 256;
        int rl = idx >> 6;
        int bf = idx & 63;
        int blk = bf >> (6 - s);
        int jj = bf & (mh - 1);
        int base = (blk << (7 - s)) + jj;
        float2 a = buf[rl][base];
        float2 b = buf[rl][base + mh];
        float2 w = tw[jj << s];
        float cs = w.x, sn = -w.y;
        float dx = a.x - b.x, dy = a.y - b.y;
        buf[rl][base] = make_float2(a.x + b.x, a.y + b.y);
        buf[rl][base + mh] = make_float2(dx * cs - dy * sn, dx * sn + dy * cs);
    }
}

__device__ __forceinline__ void fft_stage_dit(float2 (*buf)[128], const float2* tw,
                                              int t, int s)
{
    int mh = 64 >> s;
    #pragma unroll
    for (int i = 0; i < 4; ++i) {
        int idx = t + i * 256;
        int rl = idx >> 6;
        int bf = idx & 63;
        int blk = bf >> (6 - s);
        int jj = bf & (mh - 1);
        int base = (blk << (7 - s)) + jj;
        float2 a = buf[rl][base];
        float2 b = buf[rl][base + mh];
        float2 w = tw[jj << s];
        float cs = w.x, sn = w.y;
        float tx = b.x * cs - b.y * sn, ty = b.x * sn + b.y * cs;
        buf[rl][base] = make_float2(a.x + tx, a.y + ty);
        buf[rl][base + mh] = make_float2(a.x - tx, a.y - ty);
    }
}

__device__ __forceinline__ void fft16_fwd(float2 (*buf)[128], const float2* tw, int t)
{
    for (int s = 0; s < 7; ++s) { __syncthreads(); fft_stage_dif(buf, tw, t, s); }
    __syncthreads();
}
__device__ __forceinline__ void fft16_inv(float2 (*buf)[128], const float2* tw, int t)
{
    for (int s = 6; s >= 0; --s) { __syncthreads(); fft_stage_dit(buf, tw, t, s); }
    __syncthreads();
}

// P1: z = x + i*sw, row FFT over w, write transposed A[ch][i1][r] (bf16 pair)
__global__ __launch_bounds__(256)
void fft_p1_k(const float* __restrict__ x, const unsigned short* __restrict__ sw,
              unsigned* __restrict__ A)
{
    __shared__ float2 buf[16][128];
    __shared__ float2 tw[64];
    int t = threadIdx.x;
    fft_build_tw(tw, t);
    int ch = blockIdx.x >> 3;
    int rg = blockIdx.x & 7;
    size_t base = (size_t)ch * HW + rg * 2048;
    #pragma unroll
    for (int i = 0; i < 8; ++i) {
        int idx = t + i * 256;
        int rl = idx >> 7, cc = idx & 127;
        buf[rl][cc] = make_float2(x[base + rl * 128 + cc],
                                  bf2f(sw[base + rl * 128 + cc]));
    }
    fft16_fwd(buf, tw, t);
    size_t abase = (size_t)ch * HW + rg * 16;
    #pragma unroll
    for (int i = 0; i < 8; ++i) {
        int idx = t + i * 256;
        int rl = idx & 15, k1 = idx >> 4;
        A[abase + (size_t)k1 * 128 + rl] = f2bf_pk(buf[rl][k1].x, buf[rl][k1].y);
    }
}

// P2+P3+P4 fused, in-place on bf16 A
__global__ __launch_bounds__(256)
void fft_p234_k(unsigned* __restrict__ A)
{
    __shared__ float2 buf[16][128];
    __shared__ float2 tw[64];
    int t = threadIdx.x;
    fft_build_tw(tw, t);
    int ch = blockIdx.x >> 3;
    int rg = blockIdx.x & 7;
    size_t cb = (size_t)ch * HW;

    #pragma unroll
    for (int i = 0; i < 8; ++i) {
        int idx = t + i * 256;
        int l = idx >> 7, cc = idx & 127;
        int k1l;
        if (rg == 0) k1l = (l < 2) ? l * 64 : (l < 9 ? l - 1 : 128 - (l - 8));
        else         k1l = (l < 8) ? 8 * rg + l : 128 - (8 * rg + l - 8);
        unsigned z = A[cb + (size_t)brev7(k1l) * 128 + cc];
        buf[l][cc] = make_float2(bf2f((unsigned short)(z & 0xFFFF)),
                                 bf2f((unsigned short)(z >> 16)));
    }
    fft16_fwd(buf, tw, t);

    int nItems = (rg == 0) ? 1026 : 1024;
    for (int item = t; item < nItems; item += 256) {
        int lA, lB, k2;
        if (rg == 0) {
            if (item < 896) { int s = item >> 7; k2 = item & 127; lA = 2 + s; lB = 9 + s; }
            else            { int r = item - 896; lA = lB = r / 65; k2 = r % 65; }
        } else {
            int s = item >> 7; k2 = item & 127; lA = s; lB = 8 + s;
        }
        int i2 = brev7(k2), j2 = brev7((128 - k2) & 127);
        float2 z1 = buf[lA][i2];
        float2 z2 = buf[lB][j2];
        float2 X = make_float2(0.5f * (z1.x + z2.x), 0.5f * (z1.y - z2.y));
        float Dx = z1.x - z2.x, Dy = z1.y + z2.y;
        float2 Wf = make_float2(0.5f * Dy, -0.5f * Dx);
        float2 Y = make_float2(X.x * Wf.x - X.y * Wf.y, X.x * Wf.y + X.y * Wf.x);
        buf[lA][i2] = Y;
        buf[lB][j2] = make_float2(Y.x, -Y.y);
    }
    fft16_inv(buf, tw, t);

    #pragma unroll
    for (int i = 0; i < 8; ++i) {
        int idx = t + i * 256;
        int l = idx >> 7, cc = idx & 127;
        int k1l;
        if (rg == 0) k1l = (l < 2) ? l * 64 : (l < 9 ? l - 1 : 128 - (l - 8));
        else         k1l = (l < 8) ? 8 * rg + l : 128 - (8 * rg + l - 8);
        A[cb + (size_t)brev7(k1l) * 128 + cc] = f2bf_pk(buf[l][cc].x, buf[l][cc].y);
    }
}

// P5: inverse FFT over i1 (transposed read), write real out * scale (bf16)
__global__ __launch_bounds__(256)
void fft_p5_k(const unsigned* __restrict__ A, unsigned short* __restrict__ outp)
{
    __shared__ float2 buf[16][128];
    __shared__ float2 tw[64];
    int t = threadIdx.x;
    fft_build_tw(tw, t);
    int ch = blockIdx.x >> 3;
    int rg = blockIdx.x & 7;
    size_t abase = (size_t)ch * HW + rg * 16;
    #pragma unroll
    for (int i = 0; i < 8; ++i) {
        int idx = t + i * 256;
        int rl = idx & 15, i1 = idx >> 4;
        unsigned z = A[abase + (size_t)i1 * 128 + rl];
        buf[rl][i1] = make_float2(bf2f((unsigned short)(z & 0xFFFF)),
                                  bf2f((unsigned short)(z >> 16)));
    }
    fft16_inv(buf, tw, t);
    const float scale = 1.f / 2097152.f;
    size_t obase = (size_t)ch * HW + rg * 2048;
    #pragma unroll
    for (int i = 0; i < 8; ++i) {
        int idx = t + i * 256;
        int rl = idx >> 7, cc = idx & 127;
        outp[obase + rl * 128 + cc] = f2bf(buf[rl][cc].x * scale);
    }
}

// ---------------------------------------------------------------------------
// Workspace plan (128 MiB ws + d_out scratch):
//  ws[0,32):  V bf16 (phase A) -> out_f bf16 (phase B)
//  ws[32,64): out_s bf16
//  ws[64,96): swb bf16 (phase B early) -> pre bf16 (after p1 consumes swb)
//  ws[96,96.25): Wbf 7x32KB pre-swizzled bf16 weights (persistent)
//  d_out: vcb bf16 [0,32) / Gp [32,48) / G,S (phase A);
//         A complex-bf16 [0,64) (phase B); final output (fuse2).
// ---------------------------------------------------------------------------
extern "C" void kernel_launch(void* const* d_in, const int* in_sizes, int n_in,
                              void* d_out, int out_size, void* d_ws, size_t ws_size,
                              hipStream_t stream)
{
    const float* x        = (const float*)d_in[0];
    const float* W_qkv    = (const float*)d_in[1];
    const float* W_dw     = (const float*)d_in[2];
    const float* W_proj_s = (const float*)d_in[3];
    const float* scale_s  = (const float*)d_in[4];
    const float* W_ff1    = (const float*)d_in[5];
    const float* W_ff2    = (const float*)d_in[6];
    const float* W_proj_f = (const float*)d_in[7];
    const float* W_gsf    = (const float*)d_in[8];
    const float* b_gsf    = (const float*)d_in[9];
    const float* W_gfs    = (const float*)d_in[10];
    const float* b_gfs    = (const float*)d_in[11];
    float* out = (float*)d_out;

    char* ws = (char*)d_ws;
    const size_t MB32 = 33554432ull;
    const size_t MB64 = 67108864ull;
    const size_t MB96 = 100663296ull;
    unsigned short* V     = (unsigned short*)(ws);          // 32 MiB phase A
    unsigned short* out_s = (unsigned short*)(ws + MB32);   // 32 MiB
    unsigned short* swb   = (unsigned short*)(ws + MB64);   // 32 MiB bf16
    unsigned short* pre   = (unsigned short*)(ws + MB64);   // 32 MiB (swb dead)
    unsigned short* out_fp= (unsigned short*)(ws);          // 32 MiB (V dead)
    int4* Wbf4            = (int4*)(ws + MB96);             // 224 KiB
    unsigned short* vcb   = (unsigned short*)out;           // 32 MiB d_out lo
    float* Gp  = out + 8388608;                             // 16 MiB d_out[32,48)
    float* G   = out + 8388608 + 4194304;                   // 512 KiB
    float* S   = G + 131072;                                // 64 KiB
    unsigned* A = (unsigned*)out;                           // 64 MiB phase B

    // --- weight pre-conversion (bf16, pre-swizzled) ---
    // slices: 0=W_v 1=W_proj_s 2=W_ff1 3=W_ff2 4=W_proj_f 5=W_gsf 6=W_gfs
    wprep_k<<<56, 256, 0, stream>>>(W_qkv + 256 * 128, W_proj_s, W_ff1, W_ff2,
                                    W_proj_f, W_gsf, W_gfs, Wbf4);

    // --- spatial attention branch ---
    conv_mfma_k<<<2048, 256, 0, stream>>>(x, Wbf4 + 0 * 2048, V);
    dwconv_k<<<16384, 256, 0, stream>>>(V, W_dw, vcb);
    gram_mfma_k<<<256, 256, 0, stream>>>(x, Gp);
    gram_reduce_k<<<512, 256, 0, stream>>>(Gp, G);
    attn_s2_k<<<64, 256, 0, stream>>>(G, W_qkv, scale_s, S);
    proj_s_pv_k<<<2048, 256, 0, stream>>>(V, vcb, S, Wbf4 + 1 * 2048, out_s);

    // --- frequency branch (single pass, A = complex bf16 in d_out) ---
    ff_fused_k<<<2048, 256, 0, stream>>>(x, Wbf4 + 2 * 2048, Wbf4 + 3 * 2048, swb);
    fft_p1_k<<<8192, 256, 0, stream>>>(x, swb, A);
    fft_p234_k<<<8192, 256, 0, stream>>>(A);
    fft_p5_k<<<8192, 256, 0, stream>>>(A, pre);
    conv_mfma_bf_k<<<2048, 256, 0, stream>>>(pre, Wbf4 + 4 * 2048, out_fp);

    // --- fused gates + final output ---
    fuse2_k<<<4096, 256, 0, stream>>>(x, out_s, out_fp,
                                      Wbf4 + 5 * 2048, b_gsf,
                                      Wbf4 + 6 * 2048, b_gfs, out);
}

// Round 13
// 419.311 us; speedup vs baseline: 1.3843x; 1.1142x over previous
//
#include <hip/hip_runtime.h>
#include <math.h>

#define HW 16384

typedef __attribute__((ext_vector_type(8))) short bf16x8;
typedef __attribute__((ext_vector_type(4))) float f32x4;

__device__ __forceinline__ unsigned f2bf_pk(float a, float b)
{
    unsigned ua = __float_as_uint(a), ub = __float_as_uint(b);
    ua = (ua + 0x7FFFu + ((ua >> 16) & 1u)) >> 16;   // RTN-even
    ub = (ub + 0x7FFFu + ((ub >> 16) & 1u)) >> 16;
    return (ua & 0xFFFFu) | (ub << 16);
}
__device__ __forceinline__ unsigned short f2bf(float a)
{
    unsigned ua = __float_as_uint(a);
    ua = (ua + 0x7FFFu + ((ua >> 16) & 1u)) >> 16;
    return (unsigned short)ua;
}
__device__ __forceinline__ float bf2f(unsigned short u)
{
    return __uint_as_float(((unsigned)u) << 16);
}
__device__ __forceinline__ int brev7(int v) { return (int)(__brev((unsigned)v) >> 25); }
__device__ __forceinline__ float sigmoidf_(float v) { return 1.f / (1.f + expf(-v)); }

// LDS bank-conflict swizzle for float2 buf[16][128]:
//  - XOR row low bits -> column reads hit distinct bank pairs
//  - fold j bits 5-6 into bits 1-2 -> bit-reversed access spreads
// Bijective per row; applied to EVERY buf access (write & read).
__device__ __forceinline__ int SWZ(int r, int j)
{
    return j ^ (r & 15) ^ (((j >> 5) & 3) << 1);
}

// ---------------------------------------------------------------------------
// wprep: convert 7 weight matrices (128x128 fp32) to bf16 in pre-swizzled
// LDS chunk order: slot s holds row o=s>>4, col-octet c16 = (s&15) ^ (o&7).
// ---------------------------------------------------------------------------
__global__ __launch_bounds__(256)
void wprep_k(const float* __restrict__ w0, const float* __restrict__ w1,
             const float* __restrict__ w2, const float* __restrict__ w3,
             const float* __restrict__ w4, const float* __restrict__ w5,
             const float* __restrict__ w6, int4* __restrict__ Wbf4)
{
    int m = blockIdx.x >> 3;
    int slot = (blockIdx.x & 7) * 256 + threadIdx.x;   // 0..2047
    const float* src;
    switch (m) {
        case 0: src = w0; break;
        case 1: src = w1; break;
        case 2: src = w2; break;
        case 3: src = w3; break;
        case 4: src = w4; break;
        case 5: src = w5; break;
        default: src = w6; break;
    }
    int o = slot >> 4;
    int c16 = (slot & 15) ^ (o & 7);
    const float* p = src + o * 128 + c16 * 8;
    int4 pk;
    pk.x = f2bf_pk(p[0], p[1]); pk.y = f2bf_pk(p[2], p[3]);
    pk.z = f2bf_pk(p[4], p[5]); pk.w = f2bf_pk(p[6], p[7]);
    Wbf4[m * 2048 + slot] = pk;
}

// ---------------------------------------------------------------------------
// MFMA conv1x1, fp32 in -> bf16 out, pre-swizzled bf16 weights.
// ---------------------------------------------------------------------------
__global__ __launch_bounds__(256)
void conv_mfma_k(const float* __restrict__ in, const int4* __restrict__ wbf,
                 unsigned short* __restrict__ out)
{
    __shared__ short WL[128 * 128];   // 32 KB
    __shared__ short XL[64 * 128];    // 16 KB
    int t = threadIdx.x;
    int gb = blockIdx.x;
    int b = gb >> 8;
    int n0 = (gb & 255) << 6;

    #pragma unroll
    for (int it = 0; it < 8; ++it)
        ((int4*)WL)[it * 256 + t] = wbf[it * 256 + t];

    const float* inb = in + (size_t)b * 128 * HW + n0;
    int nl = t & 63;
    #pragma unroll
    for (int it = 0; it < 4; ++it) {
        int c8 = (t >> 6) + it * 4;
        float v[8];
        #pragma unroll
        for (int j = 0; j < 8; ++j) v[j] = inb[(size_t)(c8 * 8 + j) * HW + nl];
        int4 p;
        p.x = f2bf_pk(v[0], v[1]); p.y = f2bf_pk(v[2], v[3]);
        p.z = f2bf_pk(v[4], v[5]); p.w = f2bf_pk(v[6], v[7]);
        ((int4*)XL)[nl * 16 + (c8 ^ (nl & 7))] = p;
    }
    __syncthreads();

    int l = t & 63, w = t >> 6, kg = l >> 4, l15 = l & 15, l7 = l15 & 7;
    f32x4 acc[2][4];
    #pragma unroll
    for (int mf = 0; mf < 2; ++mf)
        #pragma unroll
        for (int nf = 0; nf < 4; ++nf) acc[mf][nf] = (f32x4){0.f, 0.f, 0.f, 0.f};
    #pragma unroll
    for (int ks = 0; ks < 4; ++ks) {
        int ch = ks * 4 + kg;
        bf16x8 A0 = ((const bf16x8*)WL)[(w * 32 + l15) * 16 + (ch ^ l7)];
        bf16x8 A1 = ((const bf16x8*)WL)[(w * 32 + 16 + l15) * 16 + (ch ^ l7)];
        #pragma unroll
        for (int nf = 0; nf < 4; ++nf) {
            bf16x8 Bf = ((const bf16x8*)XL)[(nf * 16 + l15) * 16 + (ch ^ l7)];
            acc[0][nf] = __builtin_amdgcn_mfma_f32_16x16x32_bf16(A0, Bf, acc[0][nf], 0, 0, 0);
            acc[1][nf] = __builtin_amdgcn_mfma_f32_16x16x32_bf16(A1, Bf, acc[1][nf], 0, 0, 0);
        }
    }
    #pragma unroll
    for (int mf = 0; mf < 2; ++mf)
        #pragma unroll
        for (int nf = 0; nf < 4; ++nf)
            #pragma unroll
            for (int i = 0; i < 4; ++i) {
                int row = w * 32 + mf * 16 + kg * 4 + i;
                int col = n0 + nf * 16 + l15;
                out[((size_t)b * 128 + row) * HW + col] = f2bf(acc[mf][nf][i]);
            }
}

// ---------------------------------------------------------------------------
// MFMA conv1x1, bf16 in -> bf16 out (bit-repack staging, no cvt VALU)
// ---------------------------------------------------------------------------
__global__ __launch_bounds__(256)
void conv_mfma_bf_k(const unsigned short* __restrict__ in,
                    const int4* __restrict__ wbf,
                    unsigned short* __restrict__ out)
{
    __shared__ short WL[128 * 128];   // 32 KB
    __shared__ short XL[64 * 128];    // 16 KB
    int t = threadIdx.x;
    int gb = blockIdx.x;
    int b = gb >> 8;
    int n0 = (gb & 255) << 6;

    #pragma unroll
    for (int it = 0; it < 8; ++it)
        ((int4*)WL)[it * 256 + t] = wbf[it * 256 + t];

    const unsigned short* inb = in + (size_t)b * 128 * HW + n0;
    int nl = t & 63;
    #pragma unroll
    for (int it = 0; it < 4; ++it) {
        int c8 = (t >> 6) + it * 4;
        unsigned u[8];
        #pragma unroll
        for (int j = 0; j < 8; ++j) u[j] = inb[(size_t)(c8 * 8 + j) * HW + nl];
        int4 p;
        p.x = (int)(u[0] | (u[1] << 16)); p.y = (int)(u[2] | (u[3] << 16));
        p.z = (int)(u[4] | (u[5] << 16)); p.w = (int)(u[6] | (u[7] << 16));
        ((int4*)XL)[nl * 16 + (c8 ^ (nl & 7))] = p;
    }
    __syncthreads();

    int l = t & 63, w = t >> 6, kg = l >> 4, l15 = l & 15, l7 = l15 & 7;
    f32x4 acc[2][4];
    #pragma unroll
    for (int mf = 0; mf < 2; ++mf)
        #pragma unroll
        for (int nf = 0; nf < 4; ++nf) acc[mf][nf] = (f32x4){0.f, 0.f, 0.f, 0.f};
    #pragma unroll
    for (int ks = 0; ks < 4; ++ks) {
        int ch = ks * 4 + kg;
        bf16x8 A0 = ((const bf16x8*)WL)[(w * 32 + l15) * 16 + (ch ^ l7)];
        bf16x8 A1 = ((const bf16x8*)WL)[(w * 32 + 16 + l15) * 16 + (ch ^ l7)];
        #pragma unroll
        for (int nf = 0; nf < 4; ++nf) {
            bf16x8 Bf = ((const bf16x8*)XL)[(nf * 16 + l15) * 16 + (ch ^ l7)];
            acc[0][nf] = __builtin_amdgcn_mfma_f32_16x16x32_bf16(A0, Bf, acc[0][nf], 0, 0, 0);
            acc[1][nf] = __builtin_amdgcn_mfma_f32_16x16x32_bf16(A1, Bf, acc[1][nf], 0, 0, 0);
        }
    }
    #pragma unroll
    for (int mf = 0; mf < 2; ++mf)
        #pragma unroll
        for (int nf = 0; nf < 4; ++nf)
            #pragma unroll
            for (int i = 0; i < 4; ++i) {
                int row = w * 32 + mf * 16 + kg * 4 + i;
                int col = n0 + nf * 16 + l15;
                out[((size_t)b * 128 + row) * HW + col] = f2bf(acc[mf][nf][i]);
            }
}

// ---------------------------------------------------------------------------
// depthwise 3x3 SAME, x4 vectorized, bf16 in -> bf16 out
// ---------------------------------------------------------------------------
__global__ __launch_bounds__(256)
void dwconv_k(const unsigned short* __restrict__ V, const float* __restrict__ Wdw,
              unsigned short* __restrict__ vcb)
{
    int tid = blockIdx.x * 256 + threadIdx.x;
    int e4 = tid & 4095;
    int bc = tid >> 12;
    int c = bc & 127;
    int y = e4 >> 5;
    int x0 = (e4 & 31) << 2;
    const unsigned short* vin = V + (size_t)bc * HW;
    float wf[9];
    #pragma unroll
    for (int i = 0; i < 9; ++i) wf[i] = Wdw[c * 9 + i];
    float a0 = 0.f, a1 = 0.f, a2 = 0.f, a3 = 0.f;
    #pragma unroll
    for (int dy = 0; dy < 3; ++dy) {
        int yy = y + dy - 1;
        if (yy < 0 || yy > 127) continue;
        const unsigned short* r = vin + yy * 128;
        uint2 mu = *(const uint2*)(r + x0);
        float m0 = bf2f((unsigned short)(mu.x & 0xFFFF));
        float m1 = bf2f((unsigned short)(mu.x >> 16));
        float m2 = bf2f((unsigned short)(mu.y & 0xFFFF));
        float m3 = bf2f((unsigned short)(mu.y >> 16));
        float left  = (x0 > 0)   ? bf2f(r[x0 - 1]) : 0.f;
        float right = (x0 < 124) ? bf2f(r[x0 + 4]) : 0.f;
        float w0 = wf[dy * 3], w1 = wf[dy * 3 + 1], w2 = wf[dy * 3 + 2];
        a0 += w0 * left + w1 * m0 + w2 * m1;
        a1 += w0 * m0   + w1 * m1 + w2 * m2;
        a2 += w0 * m1   + w1 * m2 + w2 * m3;
        a3 += w0 * m2   + w1 * m3 + w2 * right;
    }
    uint2 r2;
    r2.x = f2bf_pk(a0, a1);
    r2.y = f2bf_pk(a2, a3);
    *(uint2*)(vcb + (size_t)bc * HW + y * 128 + x0) = r2;
}

// ---------------------------------------------------------------------------
// MFMA Gram partials: 32 slices of 512 px. blk = b*32+ks. grid 256.
// ---------------------------------------------------------------------------
__global__ __launch_bounds__(256)
void gram_mfma_k(const float* __restrict__ x, float* __restrict__ Gp)
{
    __shared__ short XL[128 * 128];
    int t = threadIdx.x;
    int blk = blockIdx.x;
    int b = blk >> 5, ks = blk & 31;
    const float* xb = x + (size_t)b * 128 * HW + ks * 512;
    int l = t & 63, w = t >> 6, kg = l >> 4, l15 = l & 15, l7 = l15 & 7;

    f32x4 acc[2][8];
    #pragma unroll
    for (int mf = 0; mf < 2; ++mf)
        #pragma unroll
        for (int nf = 0; nf < 8; ++nf) acc[mf][nf] = (f32x4){0.f, 0.f, 0.f, 0.f};

    for (int kc = 0; kc < 4; ++kc) {
        __syncthreads();
        #pragma unroll
        for (int it = 0; it < 8; ++it) {
            int g = it * 256 + t;
            int row = g >> 4, oct = g & 15;
            const float* p = xb + (size_t)row * HW + kc * 128 + oct * 8;
            int4 pk;
            pk.x = f2bf_pk(p[0], p[1]); pk.y = f2bf_pk(p[2], p[3]);
            pk.z = f2bf_pk(p[4], p[5]); pk.w = f2bf_pk(p[6], p[7]);
            ((int4*)XL)[row * 16 + (oct ^ (row & 7))] = pk;
        }
        __syncthreads();
        #pragma unroll
        for (int s = 0; s < 4; ++s) {
            int oct = s * 4 + kg;
            bf16x8 A0 = ((const bf16x8*)XL)[(w * 32 + l15) * 16 + (oct ^ l7)];
            bf16x8 A1 = ((const bf16x8*)XL)[(w * 32 + 16 + l15) * 16 + (oct ^ l7)];
            #pragma unroll
            for (int nf = 0; nf < 8; ++nf) {
                bf16x8 Bf = ((const bf16x8*)XL)[(nf * 16 + l15) * 16 + (oct ^ l7)];
                acc[0][nf] = __builtin_amdgcn_mfma_f32_16x16x32_bf16(A0, Bf, acc[0][nf], 0, 0, 0);
                acc[1][nf] = __builtin_amdgcn_mfma_f32_16x16x32_bf16(A1, Bf, acc[1][nf], 0, 0, 0);
            }
        }
    }
    float* gp = Gp + (size_t)blk * 16384;
    #pragma unroll
    for (int mf = 0; mf < 2; ++mf)
        #pragma unroll
        for (int nf = 0; nf < 8; ++nf)
            #pragma unroll
            for (int i = 0; i < 4; ++i) {
                int row = w * 32 + mf * 16 + kg * 4 + i;
                int col = nf * 16 + l15;
                gp[row * 128 + col] = acc[mf][nf][i];
            }
}

__global__ void gram_reduce_k(const float* __restrict__ Gp, float* __restrict__ G)
{
    int idx = blockIdx.x * 256 + threadIdx.x;   // 8*16384
    int b = idx >> 14;
    int ij = idx & 16383;
    const float* gp = Gp + (size_t)(b * 32) * 16384 + ij;
    float s = 0.f;
    #pragma unroll
    for (int ks = 0; ks < 32; ++ks) s += gp[(size_t)ks * 16384];
    G[idx] = s;
}

// ---------------------------------------------------------------------------
// S_h = softmax( (Wq_h G Wk_h^T) * scale[h] )
// ---------------------------------------------------------------------------
__global__ __launch_bounds__(256)
void attn_s2_k(const float* __restrict__ G, const float* __restrict__ Wqkv,
               const float* __restrict__ scale, float* __restrict__ S)
{
    __shared__ float Wq[16][129];
    __shared__ float Wk[16][129];
    __shared__ float Ts[16][129];
    int bh = blockIdx.x;
    int b = bh >> 3, h = bh & 7;
    int t = threadIdx.x;
    #pragma unroll
    for (int i = 0; i < 8; ++i) {
        int idx = t + i * 256;
        int r = idx >> 7, ci = idx & 127;
        Wq[r][ci] = Wqkv[(size_t)(h * 16 + r) * 128 + ci];
        Wk[r][ci] = Wqkv[(size_t)(128 + h * 16 + r) * 128 + ci];
    }
    __syncthreads();
    const float* Gb = G + (size_t)b * 16384;
    #pragma unroll
    for (int i = 0; i < 8; ++i) {
        int idx = t + i * 256;
        int c = idx >> 7, col = idx & 127;
        float s = 0.f;
        #pragma unroll 8
        for (int ci = 0; ci < 128; ++ci)
            s += Wq[c][ci] * Gb[ci * 128 + col];
        Ts[c][col] = s;
    }
    __syncthreads();
    int c = t >> 4, d = t & 15;
    float s = 0.f;
    #pragma unroll 8
    for (int col = 0; col < 128; ++col)
        s += Ts[c][col] * Wk[d][col];
    s *= scale[h];
    float m = s;
    #pragma unroll
    for (int w = 1; w < 16; w <<= 1)
        m = fmaxf(m, __shfl_xor(m, w, 64));
    float e = expf(s - m);
    float sum = e;
    #pragma unroll
    for (int w = 1; w < 16; w <<= 1)
        sum += __shfl_xor(sum, w, 64);
    S[(size_t)bh * 256 + t] = e / sum;
}

// ---------------------------------------------------------------------------
// proj_s with fused PV: out_s = W_proj_s @ (PV(V) + vconv), bf16 in/out.
// ---------------------------------------------------------------------------
__global__ __launch_bounds__(256)
void proj_s_pv_k(const unsigned short* __restrict__ V,
                 const unsigned short* __restrict__ vcb,
                 const float* __restrict__ S, const int4* __restrict__ wbf,
                 unsigned short* __restrict__ out_s)
{
    __shared__ short WL[128 * 128];   // 32 KB
    __shared__ short XL[64 * 128];    // 16 KB
    __shared__ float SL[2048];        // 8 KB
    int t = threadIdx.x;
    int gb = blockIdx.x;
    int b = gb >> 8;
    int n0 = (gb & 255) << 6;

    #pragma unroll
    for (int it = 0; it < 8; ++it)
        ((int4*)WL)[it * 256 + t] = wbf[it * 256 + t];
    #pragma unroll
    for (int i = 0; i < 8; ++i)
        SL[i * 256 + t] = S[(size_t)b * 2048 + i * 256 + t];
    __syncthreads();

    int col = t & 63, w = t >> 6;
    #pragma unroll
    for (int hh = 0; hh < 2; ++hh) {
        int h = w * 2 + hh;
        float v[16];
        #pragma unroll
        for (int d = 0; d < 16; ++d)
            v[d] = bf2f(V[((size_t)(b * 128 + h * 16 + d)) * HW + n0 + col]);
        float o[16];
        #pragma unroll
        for (int c = 0; c < 16; ++c) {
            const float* sl = SL + h * 256 + c * 16;
            float s = 0.f;
            #pragma unroll
            for (int d = 0; d < 16; ++d) s += sl[d] * v[d];
            o[c] = s + bf2f(vcb[((size_t)(b * 128 + h * 16 + c)) * HW + n0 + col]);
        }
        #pragma unroll
        for (int oc = 0; oc < 2; ++oc) {
            int octet = h * 2 + oc;
            int4 p;
            p.x = f2bf_pk(o[oc * 8 + 0], o[oc * 8 + 1]);
            p.y = f2bf_pk(o[oc * 8 + 2], o[oc * 8 + 3]);
            p.z = f2bf_pk(o[oc * 8 + 4], o[oc * 8 + 5]);
            p.w = f2bf_pk(o[oc * 8 + 6], o[oc * 8 + 7]);
            ((int4*)XL)[col * 16 + (octet ^ (col & 7))] = p;
        }
    }
    __syncthreads();

    int l = t & 63, kg = l >> 4, l15 = l & 15, l7 = l15 & 7;
    f32x4 acc[2][4];
    #pragma unroll
    for (int mf = 0; mf < 2; ++mf)
        #pragma unroll
        for (int nf = 0; nf < 4; ++nf) acc[mf][nf] = (f32x4){0.f, 0.f, 0.f, 0.f};
    #pragma unroll
    for (int ks = 0; ks < 4; ++ks) {
        int ch = ks * 4 + kg;
        bf16x8 A0 = ((const bf16x8*)WL)[(w * 32 + l15) * 16 + (ch ^ l7)];
        bf16x8 A1 = ((const bf16x8*)WL)[(w * 32 + 16 + l15) * 16 + (ch ^ l7)];
        #pragma unroll
        for (int nf = 0; nf < 4; ++nf) {
            bf16x8 Bf = ((const bf16x8*)XL)[(nf * 16 + l15) * 16 + (ch ^ l7)];
            acc[0][nf] = __builtin_amdgcn_mfma_f32_16x16x32_bf16(A0, Bf, acc[0][nf], 0, 0, 0);
            acc[1][nf] = __builtin_amdgcn_mfma_f32_16x16x32_bf16(A1, Bf, acc[1][nf], 0, 0, 0);
        }
    }
    #pragma unroll
    for (int mf = 0; mf < 2; ++mf)
        #pragma unroll
        for (int nf = 0; nf < 4; ++nf)
            #pragma unroll
            for (int i = 0; i < 4; ++i) {
                int row = w * 32 + mf * 16 + kg * 4 + i;
                int colg = n0 + nf * 16 + l15;
                out_s[((size_t)b * 128 + row) * HW + colg] = f2bf(acc[mf][nf][i]);
            }
}

// ---------------------------------------------------------------------------
// fused ff1 (GELU) + ff2: swb = W_ff2 @ gelu(W_ff1 @ x). bf16 out.
// ---------------------------------------------------------------------------
__global__ __launch_bounds__(256)
void ff_fused_k(const float* __restrict__ x, const int4* __restrict__ w1bf,
                const int4* __restrict__ w2bf, unsigned short* __restrict__ outp)
{
    __shared__ short WL[128 * 128];   // 32 KB (W1 then W2)
    __shared__ short XL[64 * 128];    // 16 KB (x^T then gelu(mid)^T)
    int t = threadIdx.x;
    int gb = blockIdx.x;
    int b = gb >> 8;
    int n0 = (gb & 255) << 6;

    #pragma unroll
    for (int it = 0; it < 8; ++it)
        ((int4*)WL)[it * 256 + t] = w1bf[it * 256 + t];

    const float* inb = x + (size_t)b * 128 * HW + n0;
    int nl = t & 63;
    #pragma unroll
    for (int it = 0; it < 4; ++it) {
        int c8 = (t >> 6) + it * 4;
        float v[8];
        #pragma unroll
        for (int j = 0; j < 8; ++j) v[j] = inb[(size_t)(c8 * 8 + j) * HW + nl];
        int4 p;
        p.x = f2bf_pk(v[0], v[1]); p.y = f2bf_pk(v[2], v[3]);
        p.z = f2bf_pk(v[4], v[5]); p.w = f2bf_pk(v[6], v[7]);
        ((int4*)XL)[nl * 16 + (c8 ^ (nl & 7))] = p;
    }
    __syncthreads();

    int l = t & 63, w = t >> 6, kg = l >> 4, l15 = l & 15, l7 = l15 & 7;
    f32x4 acc[2][4];
    #pragma unroll
    for (int mf = 0; mf < 2; ++mf)
        #pragma unroll
        for (int nf = 0; nf < 4; ++nf) acc[mf][nf] = (f32x4){0.f, 0.f, 0.f, 0.f};
    #pragma unroll
    for (int ks = 0; ks < 4; ++ks) {
        int ch = ks * 4 + kg;
        bf16x8 A0 = ((const bf16x8*)WL)[(w * 32 + l15) * 16 + (ch ^ l7)];
        bf16x8 A1 = ((const bf16x8*)WL)[(w * 32 + 16 + l15) * 16 + (ch ^ l7)];
        #pragma unroll
        for (int nf = 0; nf < 4; ++nf) {
            bf16x8 Bf = ((const bf16x8*)XL)[(nf * 16 + l15) * 16 + (ch ^ l7)];
            acc[0][nf] = __builtin_amdgcn_mfma_f32_16x16x32_bf16(A0, Bf, acc[0][nf], 0, 0, 0);
            acc[1][nf] = __builtin_amdgcn_mfma_f32_16x16x32_bf16(A1, Bf, acc[1][nf], 0, 0, 0);
        }
    }
    __syncthreads();   // all GEMM1 LDS reads done

    #pragma unroll
    for (int it = 0; it < 8; ++it)
        ((int4*)WL)[it * 256 + t] = w2bf[it * 256 + t];
    #pragma unroll
    for (int mf = 0; mf < 2; ++mf)
        #pragma unroll
        for (int nf = 0; nf < 4; ++nf) {
            float g4[4];
            #pragma unroll
            for (int i = 0; i < 4; ++i) {
                float v = acc[mf][nf][i];
                g4[i] = 0.5f * v * (1.0f + erff(v * 0.70710678118654752f));
            }
            int col = nf * 16 + l15;
            int r0 = w * 32 + mf * 16 + kg * 4;
            int octet = r0 >> 3;
            uint2 pk2;
            pk2.x = f2bf_pk(g4[0], g4[1]);
            pk2.y = f2bf_pk(g4[2], g4[3]);
            ((uint2*)XL)[(col * 16 + (octet ^ (col & 7))) * 2 + (kg & 1)] = pk2;
        }
    __syncthreads();

    f32x4 acc2[2][4];
    #pragma unroll
    for (int mf = 0; mf < 2; ++mf)
        #pragma unroll
        for (int nf = 0; nf < 4; ++nf) acc2[mf][nf] = (f32x4){0.f, 0.f, 0.f, 0.f};
    #pragma unroll
    for (int ks = 0; ks < 4; ++ks) {
        int ch = ks * 4 + kg;
        bf16x8 A0 = ((const bf16x8*)WL)[(w * 32 + l15) * 16 + (ch ^ l7)];
        bf16x8 A1 = ((const bf16x8*)WL)[(w * 32 + 16 + l15) * 16 + (ch ^ l7)];
        #pragma unroll
        for (int nf = 0; nf < 4; ++nf) {
            bf16x8 Bf = ((const bf16x8*)XL)[(nf * 16 + l15) * 16 + (ch ^ l7)];
            acc2[0][nf] = __builtin_amdgcn_mfma_f32_16x16x32_bf16(A0, Bf, acc2[0][nf], 0, 0, 0);
            acc2[1][nf] = __builtin_amdgcn_mfma_f32_16x16x32_bf16(A1, Bf, acc2[1][nf], 0, 0, 0);
        }
    }
    #pragma unroll
    for (int mf = 0; mf < 2; ++mf)
        #pragma unroll
        for (int nf = 0; nf < 4; ++nf)
            #pragma unroll
            for (int i = 0; i < 4; ++i) {
                int row = w * 32 + mf * 16 + kg * 4 + i;
                int col = n0 + nf * 16 + l15;
                outp[((size_t)b * 128 + row) * HW + col] = f2bf(acc2[mf][nf][i]);
            }
}

// ---------------------------------------------------------------------------
// fused gates + final: block = (b, nt, half), 4096 blocks, single barrier.
// out = x + out_s*sigmoid(Wgfs@out_f+bgfs) + out_f*sigmoid(Wgsf@out_s+bgsf)
// ---------------------------------------------------------------------------
__global__ __launch_bounds__(256)
void fuse2_k(const float* __restrict__ x, const unsigned short* __restrict__ outs,
             const unsigned short* __restrict__ outf,
             const int4* __restrict__ wgsf_bf, const float* __restrict__ bgsf,
             const int4* __restrict__ wgfs_bf, const float* __restrict__ bgfs,
             float* __restrict__ out)
{
    __shared__ short WS[64 * 128];  // 16 KB (this half of W_gsf)
    __shared__ short WF[64 * 128];  // 16 KB
    __shared__ short XS[64 * 128];  // 16 KB out_s^T tile (all 128 ch)
    __shared__ short XF[64 * 128];  // 16 KB out_f^T tile
    int t = threadIdx.x;
    int gb = blockIdx.x;
    int half = gb & 1;
    int nt = (gb >> 1) & 255;
    int b = gb >> 9;
    int n0 = nt << 6;

    #pragma unroll
    for (int it = 0; it < 4; ++it) {
        ((int4*)WS)[it * 256 + t] = wgsf_bf[half * 1024 + it * 256 + t];
        ((int4*)WF)[it * 256 + t] = wgfs_bf[half * 1024 + it * 256 + t];
    }
    const unsigned short* sb = outs + (size_t)b * 128 * HW + n0;
    const unsigned short* fb = outf + (size_t)b * 128 * HW + n0;
    int nl = t & 63;
    #pragma unroll
    for (int it = 0; it < 4; ++it) {
        int c8 = (t >> 6) + it * 4;
        unsigned us[8], uf[8];
        #pragma unroll
        for (int j = 0; j < 8; ++j) {
            size_t a = (size_t)(c8 * 8 + j) * HW + nl;
            us[j] = sb[a];
            uf[j] = fb[a];
        }
        int4 ps, pf;
        ps.x = (int)(us[0] | (us[1] << 16)); ps.y = (int)(us[2] | (us[3] << 16));
        ps.z = (int)(us[4] | (us[5] << 16)); ps.w = (int)(us[6] | (us[7] << 16));
        pf.x = (int)(uf[0] | (uf[1] << 16)); pf.y = (int)(uf[2] | (uf[3] << 16));
        pf.z = (int)(uf[4] | (uf[5] << 16)); pf.w = (int)(uf[6] | (uf[7] << 16));
        ((int4*)XS)[nl * 16 + (c8 ^ (nl & 7))] = ps;
        ((int4*)XF)[nl * 16 + (c8 ^ (nl & 7))] = pf;
    }
    __syncthreads();

    int l = t & 63, w = t >> 6, kg = l >> 4, l15 = l & 15, l7 = l15 & 7;
    f32x4 aS[4], aF[4];
    #pragma unroll
    for (int nf = 0; nf < 4; ++nf) {
        aS[nf] = (f32x4){0.f, 0.f, 0.f, 0.f};
        aF[nf] = (f32x4){0.f, 0.f, 0.f, 0.f};
    }
    #pragma unroll
    for (int ks = 0; ks < 4; ++ks) {
        int ch = ks * 4 + kg;
        bf16x8 As = ((const bf16x8*)WS)[(w * 16 + l15) * 16 + (ch ^ l7)];
        bf16x8 Af = ((const bf16x8*)WF)[(w * 16 + l15) * 16 + (ch ^ l7)];
        #pragma unroll
        for (int nf = 0; nf < 4; ++nf) {
            bf16x8 Bs = ((const bf16x8*)XS)[(nf * 16 + l15) * 16 + (ch ^ l7)];
            bf16x8 Bf = ((const bf16x8*)XF)[(nf * 16 + l15) * 16 + (ch ^ l7)];
            aS[nf] = __builtin_amdgcn_mfma_f32_16x16x32_bf16(As, Bs, aS[nf], 0, 0, 0);
            aF[nf] = __builtin_amdgcn_mfma_f32_16x16x32_bf16(Af, Bf, aF[nf], 0, 0, 0);
        }
    }
    #pragma unroll
    for (int nf = 0; nf < 4; ++nf)
        #pragma unroll
        for (int i = 0; i < 4; ++i) {
            int row = half * 64 + w * 16 + kg * 4 + i;
            int cc = nf * 16 + l15;
            float gf = sigmoidf_(aS[nf][i] + bgsf[row]);   // gates out_f
            float gs = sigmoidf_(aF[nf][i] + bgfs[row]);   // gates out_s
            size_t gi = ((size_t)(b * 128) + row) * HW + n0 + cc;
            float os = bf2f(outs[gi]);
            float of = bf2f(outf[gi]);
            out[gi] = x[gi] + os * gs + of * gf;
        }
}

// ---------------------------------------------------------------------------
// FFT: radix-2 128-pt, LDS twiddles. A is complex bf16 (packed uint).
// All LDS buf accesses go through SWZ() (write & read identical).
// ---------------------------------------------------------------------------
__device__ __forceinline__ void fft_build_tw(float2* tw, int t)
{
    if (t < 64) {
        float ang = 0.049087385212340519f * (float)t;
        float sn, cs; sincosf(ang, &sn, &cs);
        tw[t] = make_float2(cs, sn);
    }
}

__device__ __forceinline__ void fft_stage_dif(float2 (*buf)[128], const float2* tw,
                                              int t, int s)
{
    int mh = 64 >> s;
    #pragma unroll
    for (int i = 0; i < 4; ++i) {
        int idx = t + i * 256;
        int rl = idx >> 6;
        int bf = idx & 63;
        int blk = bf >> (6 - s);
        int jj = bf & (mh - 1);
        int base = (blk << (7 - s)) + jj;
        int pa = SWZ(rl, base), pb = SWZ(rl, base + mh);
        float2 a = buf[rl][pa];
        float2 b = buf[rl][pb];
        float2 w = tw[jj << s];
        float cs = w.x, sn = -w.y;
        float dx = a.x - b.x, dy = a.y - b.y;
        buf[rl][pa] = make_float2(a.x + b.x, a.y + b.y);
        buf[rl][pb] = make_float2(dx * cs - dy * sn, dx * sn + dy * cs);
    }
}

__device__ __forceinline__ void fft_stage_dit(float2 (*buf)[128], const float2* tw,
                                              int t, int s)
{
    int mh = 64 >> s;
    #pragma unroll
    for (int i = 0; i < 4; ++i) {
        int idx = t + i * 256;
        int rl = idx >> 6;
        int bf = idx & 63;
        int blk = bf >> (6 - s);
        int jj = bf & (mh - 1);
        int base = (blk << (7 - s)) + jj;
        int pa = SWZ(rl, base), pb = SWZ(rl, base + mh);
        float2 a = buf[rl][pa];
        float2 b = buf[rl][pb];
        float2 w = tw[jj << s];
        float cs = w.x, sn = w.y;
        float tx = b.x * cs - b.y * sn, ty = b.x * sn + b.y * cs;
        buf[rl][pa] = make_float2(a.x + tx, a.y + ty);
        buf[rl][pb] = make_float2(a.x - tx, a.y - ty);
    }
}

__device__ __forceinline__ void fft16_fwd(float2 (*buf)[128], const float2* tw, int t)
{
    for (int s = 0; s < 7; ++s) { __syncthreads(); fft_stage_dif(buf, tw, t, s); }
    __syncthreads();
}
__device__ __forceinline__ void fft16_inv(float2 (*buf)[128], const float2* tw, int t)
{
    for (int s = 6; s >= 0; --s) { __syncthreads(); fft_stage_dit(buf, tw, t, s); }
    __syncthreads();
}

// P1: z = x + i*sw, row FFT over w, write transposed A[ch][i1][r] (bf16 pair)
__global__ __launch_bounds__(256)
void fft_p1_k(const float* __restrict__ x, const unsigned short* __restrict__ sw,
              unsigned* __restrict__ A)
{
    __shared__ float2 buf[16][128];
    __shared__ float2 tw[64];
    int t = threadIdx.x;
    fft_build_tw(tw, t);
    int ch = blockIdx.x >> 3;
    int rg = blockIdx.x & 7;
    size_t base = (size_t)ch * HW + rg * 2048;
    #pragma unroll
    for (int i = 0; i < 8; ++i) {
        int idx = t + i * 256;
        int rl = idx >> 7, cc = idx & 127;
        buf[rl][SWZ(rl, cc)] = make_float2(x[base + rl * 128 + cc],
                                           bf2f(sw[base + rl * 128 + cc]));
    }
    fft16_fwd(buf, tw, t);
    size_t abase = (size_t)ch * HW + rg * 16;
    #pragma unroll
    for (int i = 0; i < 8; ++i) {
        int idx = t + i * 256;
        int rl = idx & 15, k1 = idx >> 4;
        float2 z = buf[rl][SWZ(rl, k1)];
        A[abase + (size_t)k1 * 128 + rl] = f2bf_pk(z.x, z.y);
    }
}

// P2+P3+P4 fused, in-place on bf16 A
__global__ __launch_bounds__(256)
void fft_p234_k(unsigned* __restrict__ A)
{
    __shared__ float2 buf[16][128];
    __shared__ float2 tw[64];
    int t = threadIdx.x;
    fft_build_tw(tw, t);
    int ch = blockIdx.x >> 3;
    int rg = blockIdx.x & 7;
    size_t cb = (size_t)ch * HW;

    #pragma unroll
    for (int i = 0; i < 8; ++i) {
        int idx = t + i * 256;
        int l = idx >> 7, cc = idx & 127;
        int k1l;
        if (rg == 0) k1l = (l < 2) ? l * 64 : (l < 9 ? l - 1 : 128 - (l - 8));
        else         k1l = (l < 8) ? 8 * rg + l : 128 - (8 * rg + l - 8);
        unsigned z = A[cb + (size_t)brev7(k1l) * 128 + cc];
        buf[l][SWZ(l, cc)] = make_float2(bf2f((unsigned short)(z & 0xFFFF)),
                                         bf2f((unsigned short)(z >> 16)));
    }
    fft16_fwd(buf, tw, t);

    int nItems = (rg == 0) ? 1026 : 1024;
    for (int item = t; item < nItems; item += 256) {
        int lA, lB, k2;
        if (rg == 0) {
            if (item < 896) { int s = item >> 7; k2 = item & 127; lA = 2 + s; lB = 9 + s; }
            else            { int r = item - 896; lA = lB = r / 65; k2 = r % 65; }
        } else {
            int s = item >> 7; k2 = item & 127; lA = s; lB = 8 + s;
        }
        int i2 = brev7(k2), j2 = brev7((128 - k2) & 127);
        int pA = SWZ(lA, i2), pB = SWZ(lB, j2);
        float2 z1 = buf[lA][pA];
        float2 z2 = buf[lB][pB];
        float2 X = make_float2(0.5f * (z1.x + z2.x), 0.5f * (z1.y - z2.y));
        float Dx = z1.x - z2.x, Dy = z1.y + z2.y;
        float2 Wf = make_float2(0.5f * Dy, -0.5f * Dx);
        float2 Y = make_float2(X.x * Wf.x - X.y * Wf.y, X.x * Wf.y + X.y * Wf.x);
        buf[lA][pA] = Y;
        buf[lB][pB] = make_float2(Y.x, -Y.y);
    }
    fft16_inv(buf, tw, t);

    #pragma unroll
    for (int i = 0; i < 8; ++i) {
        int idx = t + i * 256;
        int l = idx >> 7, cc = idx & 127;
        int k1l;
        if (rg == 0) k1l = (l < 2) ? l * 64 : (l < 9 ? l - 1 : 128 - (l - 8));
        else         k1l = (l < 8) ? 8 * rg + l : 128 - (8 * rg + l - 8);
        float2 z = buf[l][SWZ(l, cc)];
        A[cb + (size_t)brev7(k1l) * 128 + cc] = f2bf_pk(z.x, z.y);
    }
}

// P5: inverse FFT over i1 (transposed read), write real out * scale (bf16)
__global__ __launch_bounds__(256)
void fft_p5_k(const unsigned* __restrict__ A, unsigned short* __restrict__ outp)
{
    __shared__ float2 buf[16][128];
    __shared__ float2 tw[64];
    int t = threadIdx.x;
    fft_build_tw(tw, t);
    int ch = blockIdx.x >> 3;
    int rg = blockIdx.x & 7;
    size_t abase = (size_t)ch * HW + rg * 16;
    #pragma unroll
    for (int i = 0; i < 8; ++i) {
        int idx = t + i * 256;
        int rl = idx & 15, i1 = idx >> 4;
        unsigned z = A[abase + (size_t)i1 * 128 + rl];
        buf[rl][SWZ(rl, i1)] = make_float2(bf2f((unsigned short)(z & 0xFFFF)),
                                           bf2f((unsigned short)(z >> 16)));
    }
    fft16_inv(buf, tw, t);
    const float scale = 1.f / 2097152.f;
    size_t obase = (size_t)ch * HW + rg * 2048;
    #pragma unroll
    for (int i = 0; i < 8; ++i) {
        int idx = t + i * 256;
        int rl = idx >> 7, cc = idx & 127;
        outp[obase + rl * 128 + cc] = f2bf(buf[rl][SWZ(rl, cc)].x * scale);
    }
}

// ---------------------------------------------------------------------------
// Workspace plan (128 MiB ws + d_out scratch):
//  ws[0,32):  V bf16 (phase A) -> out_f bf16 (phase B)
//  ws[32,64): out_s bf16
//  ws[64,96): swb bf16 (phase B early) -> pre bf16 (after p1 consumes swb)
//  ws[96,96.25): Wbf 7x32KB pre-swizzled bf16 weights (persistent)
//  d_out: vcb bf16 [0,32) / Gp [32,48) / G,S (phase A);
//         A complex-bf16 [0,64) (phase B); final output (fuse2).
// ---------------------------------------------------------------------------
extern "C" void kernel_launch(void* const* d_in, const int* in_sizes, int n_in,
                              void* d_out, int out_size, void* d_ws, size_t ws_size,
                              hipStream_t stream)
{
    const float* x        = (const float*)d_in[0];
    const float* W_qkv    = (const float*)d_in[1];
    const float* W_dw     = (const float*)d_in[2];
    const float* W_proj_s = (const float*)d_in[3];
    const float* scale_s  = (const float*)d_in[4];
    const float* W_ff1    = (const float*)d_in[5];
    const float* W_ff2    = (const float*)d_in[6];
    const float* W_proj_f = (const float*)d_in[7];
    const float* W_gsf    = (const float*)d_in[8];
    const float* b_gsf    = (const float*)d_in[9];
    const float* W_gfs    = (const float*)d_in[10];
    const float* b_gfs    = (const float*)d_in[11];
    float* out = (float*)d_out;

    char* ws = (char*)d_ws;
    const size_t MB32 = 33554432ull;
    const size_t MB64 = 67108864ull;
    const size_t MB96 = 100663296ull;
    unsigned short* V     = (unsigned short*)(ws);          // 32 MiB phase A
    unsigned short* out_s = (unsigned short*)(ws + MB32);   // 32 MiB
    unsigned short* swb   = (unsigned short*)(ws + MB64);   // 32 MiB bf16
    unsigned short* pre   = (unsigned short*)(ws + MB64);   // 32 MiB (swb dead)
    unsigned short* out_fp= (unsigned short*)(ws);          // 32 MiB (V dead)
    int4* Wbf4            = (int4*)(ws + MB96);             // 224 KiB
    unsigned short* vcb   = (unsigned short*)out;           // 32 MiB d_out lo
    float* Gp  = out + 8388608;                             // 16 MiB d_out[32,48)
    float* G   = out + 8388608 + 4194304;                   // 512 KiB
    float* S   = G + 131072;                                // 64 KiB
    unsigned* A = (unsigned*)out;                           // 64 MiB phase B

    // --- weight pre-conversion (bf16, pre-swizzled) ---
    // slices: 0=W_v 1=W_proj_s 2=W_ff1 3=W_ff2 4=W_proj_f 5=W_gsf 6=W_gfs
    wprep_k<<<56, 256, 0, stream>>>(W_qkv + 256 * 128, W_proj_s, W_ff1, W_ff2,
                                    W_proj_f, W_gsf, W_gfs, Wbf4);

    // --- spatial attention branch ---
    conv_mfma_k<<<2048, 256, 0, stream>>>(x, Wbf4 + 0 * 2048, V);
    dwconv_k<<<16384, 256, 0, stream>>>(V, W_dw, vcb);
    gram_mfma_k<<<256, 256, 0, stream>>>(x, Gp);
    gram_reduce_k<<<512, 256, 0, stream>>>(Gp, G);
    attn_s2_k<<<64, 256, 0, stream>>>(G, W_qkv, scale_s, S);
    proj_s_pv_k<<<2048, 256, 0, stream>>>(V, vcb, S, Wbf4 + 1 * 2048, out_s);

    // --- frequency branch (single pass, A = complex bf16 in d_out) ---
    ff_fused_k<<<2048, 256, 0, stream>>>(x, Wbf4 + 2 * 2048, Wbf4 + 3 * 2048, swb);
    fft_p1_k<<<8192, 256, 0, stream>>>(x, swb, A);
    fft_p234_k<<<8192, 256, 0, stream>>>(A);
    fft_p5_k<<<8192, 256, 0, stream>>>(A, pre);
    conv_mfma_bf_k<<<2048, 256, 0, stream>>>(pre, Wbf4 + 4 * 2048, out_fp);

    // --- fused gates + final output ---
    fuse2_k<<<4096, 256, 0, stream>>>(x, out_s, out_fp,
                                      Wbf4 + 5 * 2048, b_gsf,
                                      Wbf4 + 6 * 2048, b_gfs, out);
}

// Round 14
// 349.367 us; speedup vs baseline: 1.6614x; 1.2002x over previous
//
#include <hip/hip_runtime.h>
#include <math.h>

#define HW 16384

typedef __attribute__((ext_vector_type(8))) short bf16x8;
typedef __attribute__((ext_vector_type(4))) float f32x4;

__device__ __forceinline__ unsigned f2bf_pk(float a, float b)
{
    unsigned ua = __float_as_uint(a), ub = __float_as_uint(b);
    ua = (ua + 0x7FFFu + ((ua >> 16) & 1u)) >> 16;   // RTN-even
    ub = (ub + 0x7FFFu + ((ub >> 16) & 1u)) >> 16;
    return (ua & 0xFFFFu) | (ub << 16);
}
__device__ __forceinline__ unsigned short f2bf(float a)
{
    unsigned ua = __float_as_uint(a);
    ua = (ua + 0x7FFFu + ((ua >> 16) & 1u)) >> 16;
    return (unsigned short)ua;
}
__device__ __forceinline__ float bf2f(unsigned short u)
{
    return __uint_as_float(((unsigned)u) << 16);
}
__device__ __forceinline__ float sigmoidf_(float v) { return 1.f / (1.f + expf(-v)); }

__device__ __forceinline__ float2 cmul(float2 a, float2 b)
{
    return make_float2(a.x * b.x - a.y * b.y, a.x * b.y + a.y * b.x);
}

// LDS swizzle for float2 buf[32][128]: 4-way (floor) on all access patterns.
__device__ __forceinline__ int SWZ2(int r, int j)
{
    return j ^ (r & 7) ^ ((((j >> 4) ^ (r >> 1)) & 1) << 3);
}

// ---------------------------------------------------------------------------
// wprep: convert 7 weight matrices (128x128 fp32) to bf16 in pre-swizzled
// LDS chunk order.
// ---------------------------------------------------------------------------
__global__ __launch_bounds__(256)
void wprep_k(const float* __restrict__ w0, const float* __restrict__ w1,
             const float* __restrict__ w2, const float* __restrict__ w3,
             const float* __restrict__ w4, const float* __restrict__ w5,
             const float* __restrict__ w6, int4* __restrict__ Wbf4)
{
    int m = blockIdx.x >> 3;
    int slot = (blockIdx.x & 7) * 256 + threadIdx.x;   // 0..2047
    const float* src;
    switch (m) {
        case 0: src = w0; break;
        case 1: src = w1; break;
        case 2: src = w2; break;
        case 3: src = w3; break;
        case 4: src = w4; break;
        case 5: src = w5; break;
        default: src = w6; break;
    }
    int o = slot >> 4;
    int c16 = (slot & 15) ^ (o & 7);
    const float* p = src + o * 128 + c16 * 8;
    int4 pk;
    pk.x = f2bf_pk(p[0], p[1]); pk.y = f2bf_pk(p[2], p[3]);
    pk.z = f2bf_pk(p[4], p[5]); pk.w = f2bf_pk(p[6], p[7]);
    Wbf4[m * 2048 + slot] = pk;
}

// ---------------------------------------------------------------------------
// MFMA conv1x1, fp32 in -> bf16 out
// ---------------------------------------------------------------------------
__global__ __launch_bounds__(256)
void conv_mfma_k(const float* __restrict__ in, const int4* __restrict__ wbf,
                 unsigned short* __restrict__ out)
{
    __shared__ short WL[128 * 128];
    __shared__ short XL[64 * 128];
    int t = threadIdx.x;
    int gb = blockIdx.x;
    int b = gb >> 8;
    int n0 = (gb & 255) << 6;

    #pragma unroll
    for (int it = 0; it < 8; ++it)
        ((int4*)WL)[it * 256 + t] = wbf[it * 256 + t];

    const float* inb = in + (size_t)b * 128 * HW + n0;
    int nl = t & 63;
    #pragma unroll
    for (int it = 0; it < 4; ++it) {
        int c8 = (t >> 6) + it * 4;
        float v[8];
        #pragma unroll
        for (int j = 0; j < 8; ++j) v[j] = inb[(size_t)(c8 * 8 + j) * HW + nl];
        int4 p;
        p.x = f2bf_pk(v[0], v[1]); p.y = f2bf_pk(v[2], v[3]);
        p.z = f2bf_pk(v[4], v[5]); p.w = f2bf_pk(v[6], v[7]);
        ((int4*)XL)[nl * 16 + (c8 ^ (nl & 7))] = p;
    }
    __syncthreads();

    int l = t & 63, w = t >> 6, kg = l >> 4, l15 = l & 15, l7 = l15 & 7;
    f32x4 acc[2][4];
    #pragma unroll
    for (int mf = 0; mf < 2; ++mf)
        #pragma unroll
        for (int nf = 0; nf < 4; ++nf) acc[mf][nf] = (f32x4){0.f, 0.f, 0.f, 0.f};
    #pragma unroll
    for (int ks = 0; ks < 4; ++ks) {
        int ch = ks * 4 + kg;
        bf16x8 A0 = ((const bf16x8*)WL)[(w * 32 + l15) * 16 + (ch ^ l7)];
        bf16x8 A1 = ((const bf16x8*)WL)[(w * 32 + 16 + l15) * 16 + (ch ^ l7)];
        #pragma unroll
        for (int nf = 0; nf < 4; ++nf) {
            bf16x8 Bf = ((const bf16x8*)XL)[(nf * 16 + l15) * 16 + (ch ^ l7)];
            acc[0][nf] = __builtin_amdgcn_mfma_f32_16x16x32_bf16(A0, Bf, acc[0][nf], 0, 0, 0);
            acc[1][nf] = __builtin_amdgcn_mfma_f32_16x16x32_bf16(A1, Bf, acc[1][nf], 0, 0, 0);
        }
    }
    #pragma unroll
    for (int mf = 0; mf < 2; ++mf)
        #pragma unroll
        for (int nf = 0; nf < 4; ++nf)
            #pragma unroll
            for (int i = 0; i < 4; ++i) {
                int row = w * 32 + mf * 16 + kg * 4 + i;
                int col = n0 + nf * 16 + l15;
                out[((size_t)b * 128 + row) * HW + col] = f2bf(acc[mf][nf][i]);
            }
}

// ---------------------------------------------------------------------------
// MFMA conv1x1, bf16 in -> bf16 out
// ---------------------------------------------------------------------------
__global__ __launch_bounds__(256)
void conv_mfma_bf_k(const unsigned short* __restrict__ in,
                    const int4* __restrict__ wbf,
                    unsigned short* __restrict__ out)
{
    __shared__ short WL[128 * 128];
    __shared__ short XL[64 * 128];
    int t = threadIdx.x;
    int gb = blockIdx.x;
    int b = gb >> 8;
    int n0 = (gb & 255) << 6;

    #pragma unroll
    for (int it = 0; it < 8; ++it)
        ((int4*)WL)[it * 256 + t] = wbf[it * 256 + t];

    const unsigned short* inb = in + (size_t)b * 128 * HW + n0;
    int nl = t & 63;
    #pragma unroll
    for (int it = 0; it < 4; ++it) {
        int c8 = (t >> 6) + it * 4;
        unsigned u[8];
        #pragma unroll
        for (int j = 0; j < 8; ++j) u[j] = inb[(size_t)(c8 * 8 + j) * HW + nl];
        int4 p;
        p.x = (int)(u[0] | (u[1] << 16)); p.y = (int)(u[2] | (u[3] << 16));
        p.z = (int)(u[4] | (u[5] << 16)); p.w = (int)(u[6] | (u[7] << 16));
        ((int4*)XL)[nl * 16 + (c8 ^ (nl & 7))] = p;
    }
    __syncthreads();

    int l = t & 63, w = t >> 6, kg = l >> 4, l15 = l & 15, l7 = l15 & 7;
    f32x4 acc[2][4];
    #pragma unroll
    for (int mf = 0; mf < 2; ++mf)
        #pragma unroll
        for (int nf = 0; nf < 4; ++nf) acc[mf][nf] = (f32x4){0.f, 0.f, 0.f, 0.f};
    #pragma unroll
    for (int ks = 0; ks < 4; ++ks) {
        int ch = ks * 4 + kg;
        bf16x8 A0 = ((const bf16x8*)WL)[(w * 32 + l15) * 16 + (ch ^ l7)];
        bf16x8 A1 = ((const bf16x8*)WL)[(w * 32 + 16 + l15) * 16 + (ch ^ l7)];
        #pragma unroll
        for (int nf = 0; nf < 4; ++nf) {
            bf16x8 Bf = ((const bf16x8*)XL)[(nf * 16 + l15) * 16 + (ch ^ l7)];
            acc[0][nf] = __builtin_amdgcn_mfma_f32_16x16x32_bf16(A0, Bf, acc[0][nf], 0, 0, 0);
            acc[1][nf] = __builtin_amdgcn_mfma_f32_16x16x32_bf16(A1, Bf, acc[1][nf], 0, 0, 0);
        }
    }
    #pragma unroll
    for (int mf = 0; mf < 2; ++mf)
        #pragma unroll
        for (int nf = 0; nf < 4; ++nf)
            #pragma unroll
            for (int i = 0; i < 4; ++i) {
                int row = w * 32 + mf * 16 + kg * 4 + i;
                int col = n0 + nf * 16 + l15;
                out[((size_t)b * 128 + row) * HW + col] = f2bf(acc[mf][nf][i]);
            }
}

// ---------------------------------------------------------------------------
// depthwise 3x3 SAME, x4 vectorized, bf16 in -> bf16 out
// ---------------------------------------------------------------------------
__global__ __launch_bounds__(256)
void dwconv_k(const unsigned short* __restrict__ V, const float* __restrict__ Wdw,
              unsigned short* __restrict__ vcb)
{
    int tid = blockIdx.x * 256 + threadIdx.x;
    int e4 = tid & 4095;
    int bc = tid >> 12;
    int c = bc & 127;
    int y = e4 >> 5;
    int x0 = (e4 & 31) << 2;
    const unsigned short* vin = V + (size_t)bc * HW;
    float wf[9];
    #pragma unroll
    for (int i = 0; i < 9; ++i) wf[i] = Wdw[c * 9 + i];
    float a0 = 0.f, a1 = 0.f, a2 = 0.f, a3 = 0.f;
    #pragma unroll
    for (int dy = 0; dy < 3; ++dy) {
        int yy = y + dy - 1;
        if (yy < 0 || yy > 127) continue;
        const unsigned short* r = vin + yy * 128;
        uint2 mu = *(const uint2*)(r + x0);
        float m0 = bf2f((unsigned short)(mu.x & 0xFFFF));
        float m1 = bf2f((unsigned short)(mu.x >> 16));
        float m2 = bf2f((unsigned short)(mu.y & 0xFFFF));
        float m3 = bf2f((unsigned short)(mu.y >> 16));
        float left  = (x0 > 0)   ? bf2f(r[x0 - 1]) : 0.f;
        float right = (x0 < 124) ? bf2f(r[x0 + 4]) : 0.f;
        float w0 = wf[dy * 3], w1 = wf[dy * 3 + 1], w2 = wf[dy * 3 + 2];
        a0 += w0 * left + w1 * m0 + w2 * m1;
        a1 += w0 * m0   + w1 * m1 + w2 * m2;
        a2 += w0 * m1   + w1 * m2 + w2 * m3;
        a3 += w0 * m2   + w1 * m3 + w2 * right;
    }
    uint2 r2;
    r2.x = f2bf_pk(a0, a1);
    r2.y = f2bf_pk(a2, a3);
    *(uint2*)(vcb + (size_t)bc * HW + y * 128 + x0) = r2;
}

// ---------------------------------------------------------------------------
// MFMA Gram partials
// ---------------------------------------------------------------------------
__global__ __launch_bounds__(256)
void gram_mfma_k(const float* __restrict__ x, float* __restrict__ Gp)
{
    __shared__ short XL[128 * 128];
    int t = threadIdx.x;
    int blk = blockIdx.x;
    int b = blk >> 5, ks = blk & 31;
    const float* xb = x + (size_t)b * 128 * HW + ks * 512;
    int l = t & 63, w = t >> 6, kg = l >> 4, l15 = l & 15, l7 = l15 & 7;

    f32x4 acc[2][8];
    #pragma unroll
    for (int mf = 0; mf < 2; ++mf)
        #pragma unroll
        for (int nf = 0; nf < 8; ++nf) acc[mf][nf] = (f32x4){0.f, 0.f, 0.f, 0.f};

    for (int kc = 0; kc < 4; ++kc) {
        __syncthreads();
        #pragma unroll
        for (int it = 0; it < 8; ++it) {
            int g = it * 256 + t;
            int row = g >> 4, oct = g & 15;
            const float* p = xb + (size_t)row * HW + kc * 128 + oct * 8;
            int4 pk;
            pk.x = f2bf_pk(p[0], p[1]); pk.y = f2bf_pk(p[2], p[3]);
            pk.z = f2bf_pk(p[4], p[5]); pk.w = f2bf_pk(p[6], p[7]);
            ((int4*)XL)[row * 16 + (oct ^ (row & 7))] = pk;
        }
        __syncthreads();
        #pragma unroll
        for (int s = 0; s < 4; ++s) {
            int oct = s * 4 + kg;
            bf16x8 A0 = ((const bf16x8*)XL)[(w * 32 + l15) * 16 + (oct ^ l7)];
            bf16x8 A1 = ((const bf16x8*)XL)[(w * 32 + 16 + l15) * 16 + (oct ^ l7)];
            #pragma unroll
            for (int nf = 0; nf < 8; ++nf) {
                bf16x8 Bf = ((const bf16x8*)XL)[(nf * 16 + l15) * 16 + (oct ^ l7)];
                acc[0][nf] = __builtin_amdgcn_mfma_f32_16x16x32_bf16(A0, Bf, acc[0][nf], 0, 0, 0);
                acc[1][nf] = __builtin_amdgcn_mfma_f32_16x16x32_bf16(A1, Bf, acc[1][nf], 0, 0, 0);
            }
        }
    }
    float* gp = Gp + (size_t)blk * 16384;
    #pragma unroll
    for (int mf = 0; mf < 2; ++mf)
        #pragma unroll
        for (int nf = 0; nf < 8; ++nf)
            #pragma unroll
            for (int i = 0; i < 4; ++i) {
                int row = w * 32 + mf * 16 + kg * 4 + i;
                int col = nf * 16 + l15;
                gp[row * 128 + col] = acc[mf][nf][i];
            }
}

__global__ void gram_reduce_k(const float* __restrict__ Gp, float* __restrict__ G)
{
    int idx = blockIdx.x * 256 + threadIdx.x;
    int b = idx >> 14;
    int ij = idx & 16383;
    const float* gp = Gp + (size_t)(b * 32) * 16384 + ij;
    float s = 0.f;
    #pragma unroll
    for (int ks = 0; ks < 32; ++ks) s += gp[(size_t)ks * 16384];
    G[idx] = s;
}

// ---------------------------------------------------------------------------
// S_h = softmax( (Wq_h G Wk_h^T) * scale[h] )
// ---------------------------------------------------------------------------
__global__ __launch_bounds__(256)
void attn_s2_k(const float* __restrict__ G, const float* __restrict__ Wqkv,
               const float* __restrict__ scale, float* __restrict__ S)
{
    __shared__ float Wq[16][129];
    __shared__ float Wk[16][129];
    __shared__ float Ts[16][129];
    int bh = blockIdx.x;
    int b = bh >> 3, h = bh & 7;
    int t = threadIdx.x;
    #pragma unroll
    for (int i = 0; i < 8; ++i) {
        int idx = t + i * 256;
        int r = idx >> 7, ci = idx & 127;
        Wq[r][ci] = Wqkv[(size_t)(h * 16 + r) * 128 + ci];
        Wk[r][ci] = Wqkv[(size_t)(128 + h * 16 + r) * 128 + ci];
    }
    __syncthreads();
    const float* Gb = G + (size_t)b * 16384;
    #pragma unroll
    for (int i = 0; i < 8; ++i) {
        int idx = t + i * 256;
        int c = idx >> 7, col = idx & 127;
        float s = 0.f;
        #pragma unroll 8
        for (int ci = 0; ci < 128; ++ci)
            s += Wq[c][ci] * Gb[ci * 128 + col];
        Ts[c][col] = s;
    }
    __syncthreads();
    int c = t >> 4, d = t & 15;
    float s = 0.f;
    #pragma unroll 8
    for (int col = 0; col < 128; ++col)
        s += Ts[c][col] * Wk[d][col];
    s *= scale[h];
    float m = s;
    #pragma unroll
    for (int w = 1; w < 16; w <<= 1)
        m = fmaxf(m, __shfl_xor(m, w, 64));
    float e = expf(s - m);
    float sum = e;
    #pragma unroll
    for (int w = 1; w < 16; w <<= 1)
        sum += __shfl_xor(sum, w, 64);
    S[(size_t)bh * 256 + t] = e / sum;
}

// ---------------------------------------------------------------------------
// proj_s with fused PV
// ---------------------------------------------------------------------------
__global__ __launch_bounds__(256)
void proj_s_pv_k(const unsigned short* __restrict__ V,
                 const unsigned short* __restrict__ vcb,
                 const float* __restrict__ S, const int4* __restrict__ wbf,
                 unsigned short* __restrict__ out_s)
{
    __shared__ short WL[128 * 128];
    __shared__ short XL[64 * 128];
    __shared__ float SL[2048];
    int t = threadIdx.x;
    int gb = blockIdx.x;
    int b = gb >> 8;
    int n0 = (gb & 255) << 6;

    #pragma unroll
    for (int it = 0; it < 8; ++it)
        ((int4*)WL)[it * 256 + t] = wbf[it * 256 + t];
    #pragma unroll
    for (int i = 0; i < 8; ++i)
        SL[i * 256 + t] = S[(size_t)b * 2048 + i * 256 + t];
    __syncthreads();

    int col = t & 63, w = t >> 6;
    #pragma unroll
    for (int hh = 0; hh < 2; ++hh) {
        int h = w * 2 + hh;
        float v[16];
        #pragma unroll
        for (int d = 0; d < 16; ++d)
            v[d] = bf2f(V[((size_t)(b * 128 + h * 16 + d)) * HW + n0 + col]);
        float o[16];
        #pragma unroll
        for (int c = 0; c < 16; ++c) {
            const float* sl = SL + h * 256 + c * 16;
            float s = 0.f;
            #pragma unroll
            for (int d = 0; d < 16; ++d) s += sl[d] * v[d];
            o[c] = s + bf2f(vcb[((size_t)(b * 128 + h * 16 + c)) * HW + n0 + col]);
        }
        #pragma unroll
        for (int oc = 0; oc < 2; ++oc) {
            int octet = h * 2 + oc;
            int4 p;
            p.x = f2bf_pk(o[oc * 8 + 0], o[oc * 8 + 1]);
            p.y = f2bf_pk(o[oc * 8 + 2], o[oc * 8 + 3]);
            p.z = f2bf_pk(o[oc * 8 + 4], o[oc * 8 + 5]);
            p.w = f2bf_pk(o[oc * 8 + 6], o[oc * 8 + 7]);
            ((int4*)XL)[col * 16 + (octet ^ (col & 7))] = p;
        }
    }
    __syncthreads();

    int l = t & 63, kg = l >> 4, l15 = l & 15, l7 = l15 & 7;
    f32x4 acc[2][4];
    #pragma unroll
    for (int mf = 0; mf < 2; ++mf)
        #pragma unroll
        for (int nf = 0; nf < 4; ++nf) acc[mf][nf] = (f32x4){0.f, 0.f, 0.f, 0.f};
    #pragma unroll
    for (int ks = 0; ks < 4; ++ks) {
        int ch = ks * 4 + kg;
        bf16x8 A0 = ((const bf16x8*)WL)[(w * 32 + l15) * 16 + (ch ^ l7)];
        bf16x8 A1 = ((const bf16x8*)WL)[(w * 32 + 16 + l15) * 16 + (ch ^ l7)];
        #pragma unroll
        for (int nf = 0; nf < 4; ++nf) {
            bf16x8 Bf = ((const bf16x8*)XL)[(nf * 16 + l15) * 16 + (ch ^ l7)];
            acc[0][nf] = __builtin_amdgcn_mfma_f32_16x16x32_bf16(A0, Bf, acc[0][nf], 0, 0, 0);
            acc[1][nf] = __builtin_amdgcn_mfma_f32_16x16x32_bf16(A1, Bf, acc[1][nf], 0, 0, 0);
        }
    }
    #pragma unroll
    for (int mf = 0; mf < 2; ++mf)
        #pragma unroll
        for (int nf = 0; nf < 4; ++nf)
            #pragma unroll
            for (int i = 0; i < 4; ++i) {
                int row = w * 32 + mf * 16 + kg * 4 + i;
                int colg = n0 + nf * 16 + l15;
                out_s[((size_t)b * 128 + row) * HW + colg] = f2bf(acc[mf][nf][i]);
            }
}

// ---------------------------------------------------------------------------
// fused ff1 (GELU) + ff2
// ---------------------------------------------------------------------------
__global__ __launch_bounds__(256)
void ff_fused_k(const float* __restrict__ x, const int4* __restrict__ w1bf,
                const int4* __restrict__ w2bf, unsigned short* __restrict__ outp)
{
    __shared__ short WL[128 * 128];
    __shared__ short XL[64 * 128];
    int t = threadIdx.x;
    int gb = blockIdx.x;
    int b = gb >> 8;
    int n0 = (gb & 255) << 6;

    #pragma unroll
    for (int it = 0; it < 8; ++it)
        ((int4*)WL)[it * 256 + t] = w1bf[it * 256 + t];

    const float* inb = x + (size_t)b * 128 * HW + n0;
    int nl = t & 63;
    #pragma unroll
    for (int it = 0; it < 4; ++it) {
        int c8 = (t >> 6) + it * 4;
        float v[8];
        #pragma unroll
        for (int j = 0; j < 8; ++j) v[j] = inb[(size_t)(c8 * 8 + j) * HW + nl];
        int4 p;
        p.x = f2bf_pk(v[0], v[1]); p.y = f2bf_pk(v[2], v[3]);
        p.z = f2bf_pk(v[4], v[5]); p.w = f2bf_pk(v[6], v[7]);
        ((int4*)XL)[nl * 16 + (c8 ^ (nl & 7))] = p;
    }
    __syncthreads();

    int l = t & 63, w = t >> 6, kg = l >> 4, l15 = l & 15, l7 = l15 & 7;
    f32x4 acc[2][4];
    #pragma unroll
    for (int mf = 0; mf < 2; ++mf)
        #pragma unroll
        for (int nf = 0; nf < 4; ++nf) acc[mf][nf] = (f32x4){0.f, 0.f, 0.f, 0.f};
    #pragma unroll
    for (int ks = 0; ks < 4; ++ks) {
        int ch = ks * 4 + kg;
        bf16x8 A0 = ((const bf16x8*)WL)[(w * 32 + l15) * 16 + (ch ^ l7)];
        bf16x8 A1 = ((const bf16x8*)WL)[(w * 32 + 16 + l15) * 16 + (ch ^ l7)];
        #pragma unroll
        for (int nf = 0; nf < 4; ++nf) {
            bf16x8 Bf = ((const bf16x8*)XL)[(nf * 16 + l15) * 16 + (ch ^ l7)];
            acc[0][nf] = __builtin_amdgcn_mfma_f32_16x16x32_bf16(A0, Bf, acc[0][nf], 0, 0, 0);
            acc[1][nf] = __builtin_amdgcn_mfma_f32_16x16x32_bf16(A1, Bf, acc[1][nf], 0, 0, 0);
        }
    }
    __syncthreads();

    #pragma unroll
    for (int it = 0; it < 8; ++it)
        ((int4*)WL)[it * 256 + t] = w2bf[it * 256 + t];
    #pragma unroll
    for (int mf = 0; mf < 2; ++mf)
        #pragma unroll
        for (int nf = 0; nf < 4; ++nf) {
            float g4[4];
            #pragma unroll
            for (int i = 0; i < 4; ++i) {
                float v = acc[mf][nf][i];
                g4[i] = 0.5f * v * (1.0f + erff(v * 0.70710678118654752f));
            }
            int col = nf * 16 + l15;
            int r0 = w * 32 + mf * 16 + kg * 4;
            int octet = r0 >> 3;
            uint2 pk2;
            pk2.x = f2bf_pk(g4[0], g4[1]);
            pk2.y = f2bf_pk(g4[2], g4[3]);
            ((uint2*)XL)[(col * 16 + (octet ^ (col & 7))) * 2 + (kg & 1)] = pk2;
        }
    __syncthreads();

    f32x4 acc2[2][4];
    #pragma unroll
    for (int mf = 0; mf < 2; ++mf)
        #pragma unroll
        for (int nf = 0; nf < 4; ++nf) acc2[mf][nf] = (f32x4){0.f, 0.f, 0.f, 0.f};
    #pragma unroll
    for (int ks = 0; ks < 4; ++ks) {
        int ch = ks * 4 + kg;
        bf16x8 A0 = ((const bf16x8*)WL)[(w * 32 + l15) * 16 + (ch ^ l7)];
        bf16x8 A1 = ((const bf16x8*)WL)[(w * 32 + 16 + l15) * 16 + (ch ^ l7)];
        #pragma unroll
        for (int nf = 0; nf < 4; ++nf) {
            bf16x8 Bf = ((const bf16x8*)XL)[(nf * 16 + l15) * 16 + (ch ^ l7)];
            acc2[0][nf] = __builtin_amdgcn_mfma_f32_16x16x32_bf16(A0, Bf, acc2[0][nf], 0, 0, 0);
            acc2[1][nf] = __builtin_amdgcn_mfma_f32_16x16x32_bf16(A1, Bf, acc2[1][nf], 0, 0, 0);
        }
    }
    #pragma unroll
    for (int mf = 0; mf < 2; ++mf)
        #pragma unroll
        for (int nf = 0; nf < 4; ++nf)
            #pragma unroll
            for (int i = 0; i < 4; ++i) {
                int row = w * 32 + mf * 16 + kg * 4 + i;
                int col = n0 + nf * 16 + l15;
                outp[((size_t)b * 128 + row) * HW + col] = f2bf(acc2[mf][nf][i]);
            }
}

// ---------------------------------------------------------------------------
// fused gates + final
// ---------------------------------------------------------------------------
__global__ __launch_bounds__(256)
void fuse2_k(const float* __restrict__ x, const unsigned short* __restrict__ outs,
             const unsigned short* __restrict__ outf,
             const int4* __restrict__ wgsf_bf, const float* __restrict__ bgsf,
             const int4* __restrict__ wgfs_bf, const float* __restrict__ bgfs,
             float* __restrict__ out)
{
    __shared__ short WS[64 * 128];
    __shared__ short WF[64 * 128];
    __shared__ short XS[64 * 128];
    __shared__ short XF[64 * 128];
    int t = threadIdx.x;
    int gb = blockIdx.x;
    int half = gb & 1;
    int nt = (gb >> 1) & 255;
    int b = gb >> 9;
    int n0 = nt << 6;

    #pragma unroll
    for (int it = 0; it < 4; ++it) {
        ((int4*)WS)[it * 256 + t] = wgsf_bf[half * 1024 + it * 256 + t];
        ((int4*)WF)[it * 256 + t] = wgfs_bf[half * 1024 + it * 256 + t];
    }
    const unsigned short* sb = outs + (size_t)b * 128 * HW + n0;
    const unsigned short* fb = outf + (size_t)b * 128 * HW + n0;
    int nl = t & 63;
    #pragma unroll
    for (int it = 0; it < 4; ++it) {
        int c8 = (t >> 6) + it * 4;
        unsigned us[8], uf[8];
        #pragma unroll
        for (int j = 0; j < 8; ++j) {
            size_t a = (size_t)(c8 * 8 + j) * HW + nl;
            us[j] = sb[a];
            uf[j] = fb[a];
        }
        int4 ps, pf;
        ps.x = (int)(us[0] | (us[1] << 16)); ps.y = (int)(us[2] | (us[3] << 16));
        ps.z = (int)(us[4] | (us[5] << 16)); ps.w = (int)(us[6] | (us[7] << 16));
        pf.x = (int)(uf[0] | (uf[1] << 16)); pf.y = (int)(uf[2] | (uf[3] << 16));
        pf.z = (int)(uf[4] | (uf[5] << 16)); pf.w = (int)(uf[6] | (uf[7] << 16));
        ((int4*)XS)[nl * 16 + (c8 ^ (nl & 7))] = ps;
        ((int4*)XF)[nl * 16 + (c8 ^ (nl & 7))] = pf;
    }
    __syncthreads();

    int l = t & 63, w = t >> 6, kg = l >> 4, l15 = l & 15, l7 = l15 & 7;
    f32x4 aS[4], aF[4];
    #pragma unroll
    for (int nf = 0; nf < 4; ++nf) {
        aS[nf] = (f32x4){0.f, 0.f, 0.f, 0.f};
        aF[nf] = (f32x4){0.f, 0.f, 0.f, 0.f};
    }
    #pragma unroll
    for (int ks = 0; ks < 4; ++ks) {
        int ch = ks * 4 + kg;
        bf16x8 As = ((const bf16x8*)WS)[(w * 16 + l15) * 16 + (ch ^ l7)];
        bf16x8 Af = ((const bf16x8*)WF)[(w * 16 + l15) * 16 + (ch ^ l7)];
        #pragma unroll
        for (int nf = 0; nf < 4; ++nf) {
            bf16x8 Bs = ((const bf16x8*)XS)[(nf * 16 + l15) * 16 + (ch ^ l7)];
            bf16x8 Bf = ((const bf16x8*)XF)[(nf * 16 + l15) * 16 + (ch ^ l7)];
            aS[nf] = __builtin_amdgcn_mfma_f32_16x16x32_bf16(As, Bs, aS[nf], 0, 0, 0);
            aF[nf] = __builtin_amdgcn_mfma_f32_16x16x32_bf16(Af, Bf, aF[nf], 0, 0, 0);
        }
    }
    #pragma unroll
    for (int nf = 0; nf < 4; ++nf)
        #pragma unroll
        for (int i = 0; i < 4; ++i) {
            int row = half * 64 + w * 16 + kg * 4 + i;
            int cc = nf * 16 + l15;
            float gf = sigmoidf_(aS[nf][i] + bgsf[row]);
            float gs = sigmoidf_(aF[nf][i] + bgfs[row]);
            size_t gi = ((size_t)(b * 128) + row) * HW + n0 + cc;
            float os = bf2f(outs[gi]);
            float of = bf2f(outf[gi]);
            out[gi] = x[gi] + os * gs + of * gf;
        }
}

// ---------------------------------------------------------------------------
// Register FFT-128 (natural in/out), 128 = 16x8 Cooley-Tukey.
// Thread (row = t>>3, n2 = t&7); buf float2[32][128] with SWZ2.
// Phase1: 16 stride-8 inputs -> DFT-16 (regs) -> twiddle W128^(n2*k1).
// Exchange via LDS; Phase2: two DFT-8s -> X natural (wa: k1=n2, wb: k1=n2+8),
// X[k1+16*BREV3[p]] = w[p].
// ---------------------------------------------------------------------------
__device__ __forceinline__ void dft16(float2* v)
{
    const float C1 = 0.92387953251f, S1 = 0.38268343236f, R2 = 0.70710678119f;
    const float2 W16[8] = {
        {1.f, 0.f}, {C1, -S1}, {R2, -R2}, {S1, -C1},
        {0.f, -1.f}, {-S1, -C1}, {-R2, -R2}, {-C1, -S1}};
    #pragma unroll
    for (int i = 0; i < 8; ++i) {
        float2 a = v[i], b = v[i + 8];
        v[i] = make_float2(a.x + b.x, a.y + b.y);
        float2 d = make_float2(a.x - b.x, a.y - b.y);
        v[i + 8] = cmul(d, W16[i]);
    }
    #pragma unroll
    for (int blk = 0; blk < 16; blk += 8)
        #pragma unroll
        for (int i = 0; i < 4; ++i) {
            float2 a = v[blk + i], b = v[blk + i + 4];
            v[blk + i] = make_float2(a.x + b.x, a.y + b.y);
            float2 d = make_float2(a.x - b.x, a.y - b.y);
            v[blk + i + 4] = cmul(d, W16[2 * i]);
        }
    #pragma unroll
    for (int blk = 0; blk < 16; blk += 4) {
        float2 a0 = v[blk], b0 = v[blk + 2];
        v[blk] = make_float2(a0.x + b0.x, a0.y + b0.y);
        v[blk + 2] = make_float2(a0.x - b0.x, a0.y - b0.y);
        float2 a1 = v[blk + 1], b1 = v[blk + 3];
        v[blk + 1] = make_float2(a1.x + b1.x, a1.y + b1.y);
        float2 d = make_float2(a1.x - b1.x, a1.y - b1.y);
        v[blk + 3] = make_float2(d.y, -d.x);          // * (0,-1)
    }
    #pragma unroll
    for (int blk = 0; blk < 16; blk += 2) {
        float2 a = v[blk], b = v[blk + 1];
        v[blk] = make_float2(a.x + b.x, a.y + b.y);
        v[blk + 1] = make_float2(a.x - b.x, a.y - b.y);
    }
}

__device__ __forceinline__ void dft8(float2* v)
{
    const float R2 = 0.70710678119f;
    const float2 W8[4] = {{1.f, 0.f}, {R2, -R2}, {0.f, -1.f}, {-R2, -R2}};
    #pragma unroll
    for (int i = 0; i < 4; ++i) {
        float2 a = v[i], b = v[i + 4];
        v[i] = make_float2(a.x + b.x, a.y + b.y);
        float2 d = make_float2(a.x - b.x, a.y - b.y);
        v[i + 4] = cmul(d, W8[i]);
    }
    #pragma unroll
    for (int blk = 0; blk < 8; blk += 4) {
        float2 a0 = v[blk], b0 = v[blk + 2];
        v[blk] = make_float2(a0.x + b0.x, a0.y + b0.y);
        v[blk + 2] = make_float2(a0.x - b0.x, a0.y - b0.y);
        float2 a1 = v[blk + 1], b1 = v[blk + 3];
        v[blk + 1] = make_float2(a1.x + b1.x, a1.y + b1.y);
        float2 d = make_float2(a1.x - b1.x, a1.y - b1.y);
        v[blk + 3] = make_float2(d.y, -d.x);
    }
    #pragma unroll
    for (int blk = 0; blk < 8; blk += 2) {
        float2 a = v[blk], b = v[blk + 1];
        v[blk] = make_float2(a.x + b.x, a.y + b.y);
        v[blk + 1] = make_float2(a.x - b.x, a.y - b.y);
    }
}

// forward 128-pt over buf rows; cj: conjugate inputs (for inverse trick).
// Leaves wa (k1=n2), wb (k1=n2+8): X[k1+16*BREV3[p]] = w[p]. 2 syncs inside.
__device__ __forceinline__ void fwd128(float2 (*buf)[128], const float2* tw,
                                       int row, int n2, bool cj,
                                       float2* wa, float2* wb)
{
    const int BREV4[16] = {0,8,4,12,2,10,6,14,1,9,5,13,3,11,7,15};
    float2 v[16];
    #pragma unroll
    for (int n1 = 0; n1 < 16; ++n1) {
        float2 a = buf[row][SWZ2(row, 8 * n1 + n2)];
        v[n1] = cj ? make_float2(a.x, -a.y) : a;
    }
    dft16(v);
    __syncthreads();                       // all input reads done
    #pragma unroll
    for (int p = 0; p < 16; ++p) {
        int k1 = BREV4[p];
        buf[row][SWZ2(row, 16 * n2 + k1)] = cmul(v[p], tw[n2 * k1]);
    }
    __syncthreads();
    #pragma unroll
    for (int m = 0; m < 8; ++m) wa[m] = buf[row][SWZ2(row, 16 * m + n2)];
    #pragma unroll
    for (int m = 0; m < 8; ++m) wb[m] = buf[row][SWZ2(row, 16 * m + n2 + 8)];
    dft8(wa);
    dft8(wb);
}

// row list for p234 blocks: 32 k_w rows forming Hermitian pairs.
__device__ __forceinline__ int rowL(int g, int i)
{
    if (g == 0) {
        if (i < 16) return i;
        if (i < 31) return 127 - (i - 16);
        return 64;
    }
    return (i < 16) ? (16 * g + i) : (128 - (16 * g + (i - 16)));
}

// P1: z = x + i*sw, FFT over w (natural), store transposed A[ch][k][r] bf16.
__global__ __launch_bounds__(256)
void fft_p1_k(const float* __restrict__ x, const unsigned short* __restrict__ sw,
              unsigned* __restrict__ A)
{
    __shared__ float2 buf[32][128];
    __shared__ float2 tw[128];
    const int BREV3[8] = {0,4,2,6,1,5,3,7};
    int t = threadIdx.x;
    if (t < 128) {
        float sn, cs;
        sincosf(0.049087385212340519f * (float)t, &sn, &cs);
        tw[t] = make_float2(cs, -sn);
    }
    int ch = blockIdx.x >> 2;
    int rg = blockIdx.x & 3;
    size_t base = (size_t)ch * HW + rg * 4096;
    #pragma unroll
    for (int i = 0; i < 16; ++i) {
        int idx = t + i * 256;
        int r = idx >> 7, cc = idx & 127;
        buf[r][SWZ2(r, cc)] = make_float2(x[base + r * 128 + cc],
                                          bf2f(sw[base + r * 128 + cc]));
    }
    __syncthreads();
    int row = t >> 3, n2 = t & 7;
    float2 wa[8], wb[8];
    fwd128(buf, tw, row, n2, false, wa, wb);
    size_t cb = (size_t)ch * HW + rg * 32 + row;
    #pragma unroll
    for (int p = 0; p < 8; ++p) {
        int ka = n2 + 16 * BREV3[p];
        int kb = n2 + 8 + 16 * BREV3[p];
        A[cb + (size_t)ka * 128] = f2bf_pk(wa[p].x, wa[p].y);
        A[cb + (size_t)kb * 128] = f2bf_pk(wb[p].x, wb[p].y);
    }
}

// P234: fwd FFT over r, Hermitian product (natural pairing), inverse, store.
__global__ __launch_bounds__(256)
void fft_p234_k(unsigned* __restrict__ A)
{
    __shared__ float2 buf[32][128];
    __shared__ float2 tw[128];
    const int BREV3[8] = {0,4,2,6,1,5,3,7};
    int t = threadIdx.x;
    if (t < 128) {
        float sn, cs;
        sincosf(0.049087385212340519f * (float)t, &sn, &cs);
        tw[t] = make_float2(cs, -sn);
    }
    int ch = blockIdx.x >> 2;
    int g = blockIdx.x & 3;
    size_t cb = (size_t)ch * HW;

    #pragma unroll
    for (int i = 0; i < 16; ++i) {
        int idx = t + i * 256;
        int r = idx >> 7, cc = idx & 127;
        unsigned z = A[cb + (size_t)rowL(g, r) * 128 + cc];
        buf[r][SWZ2(r, cc)] = make_float2(bf2f((unsigned short)(z & 0xFFFF)),
                                          bf2f((unsigned short)(z >> 16)));
    }
    __syncthreads();
    int row = t >> 3, n2 = t & 7;
    float2 wa[8], wb[8];
    fwd128(buf, tw, row, n2, false, wa, wb);
    __syncthreads();                          // Z reads done
    #pragma unroll
    for (int p = 0; p < 8; ++p) {
        buf[row][SWZ2(row, n2 + 16 * BREV3[p])] = wa[p];
        buf[row][SWZ2(row, n2 + 8 + 16 * BREV3[p])] = wb[p];
    }
    __syncthreads();

    // Hermitian product in natural order
    int nItems = (g == 0) ? 2050 : 2048;
    for (int item = t; item < nItems; item += 256) {
        int rA, rB, k2;
        if (g == 0) {
            if (item < 1920)      { int j = item >> 7; rA = 1 + j; rB = 16 + j; k2 = item & 127; }
            else if (item < 1985) { rA = rB = 0;  k2 = item - 1920; }
            else                  { rA = rB = 31; k2 = item - 1985; }
        } else {
            int j = item >> 7; rA = j; rB = 16 + j; k2 = item & 127;
        }
        int pk2 = (128 - k2) & 127;
        int pA = SWZ2(rA, k2), pB = SWZ2(rB, pk2);
        float2 z1 = buf[rA][pA];
        float2 z2 = buf[rB][pB];
        float2 X = make_float2(0.5f * (z1.x + z2.x), 0.5f * (z1.y - z2.y));
        float Dx = z1.x - z2.x, Dy = z1.y + z2.y;
        float2 Wf = make_float2(0.5f * Dy, -0.5f * Dx);
        float2 Y = cmul(X, Wf);
        buf[rA][pA] = Y;
        buf[rB][pB] = make_float2(Y.x, -Y.y);
    }
    __syncthreads();

    // inverse = conj -> fwd -> conj; store direct to global
    fwd128(buf, tw, row, n2, true, wa, wb);
    size_t rb = cb + (size_t)rowL(g, row) * 128;
    #pragma unroll
    for (int p = 0; p < 8; ++p) {
        int ka = n2 + 16 * BREV3[p];
        int kb = n2 + 8 + 16 * BREV3[p];
        A[rb + ka] = f2bf_pk(wa[p].x, -wa[p].y);
        A[rb + kb] = f2bf_pk(wb[p].x, -wb[p].y);
    }
}

// P5: inverse FFT over k_w (conj at load), write real * scale (bf16).
__global__ __launch_bounds__(256)
void fft_p5_k(const unsigned* __restrict__ A, unsigned short* __restrict__ outp)
{
    __shared__ float2 buf[32][128];
    __shared__ float2 tw[128];
    const int BREV3[8] = {0,4,2,6,1,5,3,7};
    int t = threadIdx.x;
    if (t < 128) {
        float sn, cs;
        sincosf(0.049087385212340519f * (float)t, &sn, &cs);
        tw[t] = make_float2(cs, -sn);
    }
    int ch = blockIdx.x >> 2;
    int rg = blockIdx.x & 3;
    size_t cb = (size_t)ch * HW;
    int rbase = rg * 32;
    #pragma unroll
    for (int i = 0; i < 16; ++i) {
        int idx = t + i * 256;
        int rl = idx & 31, kw = idx >> 5;
        unsigned z = A[cb + (size_t)kw * 128 + rbase + rl];
        buf[rl][SWZ2(rl, kw)] = make_float2(bf2f((unsigned short)(z & 0xFFFF)),
                                            -bf2f((unsigned short)(z >> 16)));
    }
    __syncthreads();
    int row = t >> 3, n2 = t & 7;
    float2 wa[8], wb[8];
    fwd128(buf, tw, row, n2, false, wa, wb);
    const float scale = 1.f / 2097152.f;   // 1/(128^3)
    size_t ob = cb + (size_t)(rbase + row) * 128;
    #pragma unroll
    for (int p = 0; p < 8; ++p) {
        int ka = n2 + 16 * BREV3[p];
        int kb = n2 + 8 + 16 * BREV3[p];
        outp[ob + ka] = f2bf(wa[p].x * scale);
        outp[ob + kb] = f2bf(wb[p].x * scale);
    }
}

// ---------------------------------------------------------------------------
extern "C" void kernel_launch(void* const* d_in, const int* in_sizes, int n_in,
                              void* d_out, int out_size, void* d_ws, size_t ws_size,
                              hipStream_t stream)
{
    const float* x        = (const float*)d_in[0];
    const float* W_qkv    = (const float*)d_in[1];
    const float* W_dw     = (const float*)d_in[2];
    const float* W_proj_s = (const float*)d_in[3];
    const float* scale_s  = (const float*)d_in[4];
    const float* W_ff1    = (const float*)d_in[5];
    const float* W_ff2    = (const float*)d_in[6];
    const float* W_proj_f = (const float*)d_in[7];
    const float* W_gsf    = (const float*)d_in[8];
    const float* b_gsf    = (const float*)d_in[9];
    const float* W_gfs    = (const float*)d_in[10];
    const float* b_gfs    = (const float*)d_in[11];
    float* out = (float*)d_out;

    char* ws = (char*)d_ws;
    const size_t MB32 = 33554432ull;
    const size_t MB64 = 67108864ull;
    const size_t MB96 = 100663296ull;
    unsigned short* V     = (unsigned short*)(ws);          // 32 MiB phase A
    unsigned short* out_s = (unsigned short*)(ws + MB32);   // 32 MiB
    unsigned short* swb   = (unsigned short*)(ws + MB64);   // 32 MiB bf16
    unsigned short* pre   = (unsigned short*)(ws + MB64);   // 32 MiB (swb dead)
    unsigned short* out_fp= (unsigned short*)(ws);          // 32 MiB (V dead)
    int4* Wbf4            = (int4*)(ws + MB96);             // 224 KiB
    unsigned short* vcb   = (unsigned short*)out;           // 32 MiB d_out lo
    float* Gp  = out + 8388608;                             // 16 MiB
    float* G   = out + 8388608 + 4194304;                   // 512 KiB
    float* S   = G + 131072;                                // 64 KiB
    unsigned* A = (unsigned*)out;                           // 64 MiB phase B

    // slices: 0=W_v 1=W_proj_s 2=W_ff1 3=W_ff2 4=W_proj_f 5=W_gsf 6=W_gfs
    wprep_k<<<56, 256, 0, stream>>>(W_qkv + 256 * 128, W_proj_s, W_ff1, W_ff2,
                                    W_proj_f, W_gsf, W_gfs, Wbf4);

    // --- spatial attention branch ---
    conv_mfma_k<<<2048, 256, 0, stream>>>(x, Wbf4 + 0 * 2048, V);
    dwconv_k<<<16384, 256, 0, stream>>>(V, W_dw, vcb);
    gram_mfma_k<<<256, 256, 0, stream>>>(x, Gp);
    gram_reduce_k<<<512, 256, 0, stream>>>(Gp, G);
    attn_s2_k<<<64, 256, 0, stream>>>(G, W_qkv, scale_s, S);
    proj_s_pv_k<<<2048, 256, 0, stream>>>(V, vcb, S, Wbf4 + 1 * 2048, out_s);

    // --- frequency branch (register FFT, natural order, A = complex bf16) ---
    ff_fused_k<<<2048, 256, 0, stream>>>(x, Wbf4 + 2 * 2048, Wbf4 + 3 * 2048, swb);
    fft_p1_k<<<4096, 256, 0, stream>>>(x, swb, A);
    fft_p234_k<<<4096, 256, 0, stream>>>(A);
    fft_p5_k<<<4096, 256, 0, stream>>>(A, pre);
    conv_mfma_bf_k<<<2048, 256, 0, stream>>>(pre, Wbf4 + 4 * 2048, out_fp);

    // --- fused gates + final output ---
    fuse2_k<<<4096, 256, 0, stream>>>(x, out_s, out_fp,
                                      Wbf4 + 5 * 2048, b_gsf,
                                      Wbf4 + 6 * 2048, b_gfs, out);
}

// Round 15
// 330.464 us; speedup vs baseline: 1.7564x; 1.0572x over previous
//
#include <hip/hip_runtime.h>
#include <math.h>

#define HW 16384

typedef __attribute__((ext_vector_type(8))) short bf16x8;
typedef __attribute__((ext_vector_type(4))) float f32x4;

__device__ __forceinline__ unsigned f2bf_pk(float a, float b)
{
    unsigned ua = __float_as_uint(a), ub = __float_as_uint(b);
    ua = (ua + 0x7FFFu + ((ua >> 16) & 1u)) >> 16;   // RTN-even
    ub = (ub + 0x7FFFu + ((ub >> 16) & 1u)) >> 16;
    return (ua & 0xFFFFu) | (ub << 16);
}
__device__ __forceinline__ unsigned short f2bf(float a)
{
    unsigned ua = __float_as_uint(a);
    ua = (ua + 0x7FFFu + ((ua >> 16) & 1u)) >> 16;
    return (unsigned short)ua;
}
__device__ __forceinline__ float bf2f(unsigned short u)
{
    return __uint_as_float(((unsigned)u) << 16);
}
__device__ __forceinline__ float sigmoidf_(float v) { return 1.f / (1.f + expf(-v)); }

__device__ __forceinline__ float2 cmul(float2 a, float2 b)
{
    return make_float2(a.x * b.x - a.y * b.y, a.x * b.y + a.y * b.x);
}

// ---------------------------------------------------------------------------
// wprep: 7 weight matrices -> bf16 in pre-swizzled LDS chunk order.
// ---------------------------------------------------------------------------
__global__ __launch_bounds__(256)
void wprep_k(const float* __restrict__ w0, const float* __restrict__ w1,
             const float* __restrict__ w2, const float* __restrict__ w3,
             const float* __restrict__ w4, const float* __restrict__ w5,
             const float* __restrict__ w6, int4* __restrict__ Wbf4)
{
    int m = blockIdx.x >> 3;
    int slot = (blockIdx.x & 7) * 256 + threadIdx.x;   // 0..2047
    const float* src;
    switch (m) {
        case 0: src = w0; break;
        case 1: src = w1; break;
        case 2: src = w2; break;
        case 3: src = w3; break;
        case 4: src = w4; break;
        case 5: src = w5; break;
        default: src = w6; break;
    }
    int o = slot >> 4;
    int c16 = (slot & 15) ^ (o & 7);
    const float* p = src + o * 128 + c16 * 8;
    int4 pk;
    pk.x = f2bf_pk(p[0], p[1]); pk.y = f2bf_pk(p[2], p[3]);
    pk.z = f2bf_pk(p[4], p[5]); pk.w = f2bf_pk(p[6], p[7]);
    Wbf4[m * 2048 + slot] = pk;
}

// ---------------------------------------------------------------------------
// MFMA conv1x1, fp32 in -> bf16 out
// ---------------------------------------------------------------------------
__global__ __launch_bounds__(256)
void conv_mfma_k(const float* __restrict__ in, const int4* __restrict__ wbf,
                 unsigned short* __restrict__ out)
{
    __shared__ short WL[128 * 128];
    __shared__ short XL[64 * 128];
    int t = threadIdx.x;
    int gb = blockIdx.x;
    int b = gb >> 8;
    int n0 = (gb & 255) << 6;

    #pragma unroll
    for (int it = 0; it < 8; ++it)
        ((int4*)WL)[it * 256 + t] = wbf[it * 256 + t];

    const float* inb = in + (size_t)b * 128 * HW + n0;
    int nl = t & 63;
    #pragma unroll
    for (int it = 0; it < 4; ++it) {
        int c8 = (t >> 6) + it * 4;
        float v[8];
        #pragma unroll
        for (int j = 0; j < 8; ++j) v[j] = inb[(size_t)(c8 * 8 + j) * HW + nl];
        int4 p;
        p.x = f2bf_pk(v[0], v[1]); p.y = f2bf_pk(v[2], v[3]);
        p.z = f2bf_pk(v[4], v[5]); p.w = f2bf_pk(v[6], v[7]);
        ((int4*)XL)[nl * 16 + (c8 ^ (nl & 7))] = p;
    }
    __syncthreads();

    int l = t & 63, w = t >> 6, kg = l >> 4, l15 = l & 15, l7 = l15 & 7;
    f32x4 acc[2][4];
    #pragma unroll
    for (int mf = 0; mf < 2; ++mf)
        #pragma unroll
        for (int nf = 0; nf < 4; ++nf) acc[mf][nf] = (f32x4){0.f, 0.f, 0.f, 0.f};
    #pragma unroll
    for (int ks = 0; ks < 4; ++ks) {
        int ch = ks * 4 + kg;
        bf16x8 A0 = ((const bf16x8*)WL)[(w * 32 + l15) * 16 + (ch ^ l7)];
        bf16x8 A1 = ((const bf16x8*)WL)[(w * 32 + 16 + l15) * 16 + (ch ^ l7)];
        #pragma unroll
        for (int nf = 0; nf < 4; ++nf) {
            bf16x8 Bf = ((const bf16x8*)XL)[(nf * 16 + l15) * 16 + (ch ^ l7)];
            acc[0][nf] = __builtin_amdgcn_mfma_f32_16x16x32_bf16(A0, Bf, acc[0][nf], 0, 0, 0);
            acc[1][nf] = __builtin_amdgcn_mfma_f32_16x16x32_bf16(A1, Bf, acc[1][nf], 0, 0, 0);
        }
    }
    #pragma unroll
    for (int mf = 0; mf < 2; ++mf)
        #pragma unroll
        for (int nf = 0; nf < 4; ++nf)
            #pragma unroll
            for (int i = 0; i < 4; ++i) {
                int row = w * 32 + mf * 16 + kg * 4 + i;
                int col = n0 + nf * 16 + l15;
                out[((size_t)b * 128 + row) * HW + col] = f2bf(acc[mf][nf][i]);
            }
}

// ---------------------------------------------------------------------------
// MFMA conv1x1, bf16 in -> bf16 out
// ---------------------------------------------------------------------------
__global__ __launch_bounds__(256)
void conv_mfma_bf_k(const unsigned short* __restrict__ in,
                    const int4* __restrict__ wbf,
                    unsigned short* __restrict__ out)
{
    __shared__ short WL[128 * 128];
    __shared__ short XL[64 * 128];
    int t = threadIdx.x;
    int gb = blockIdx.x;
    int b = gb >> 8;
    int n0 = (gb & 255) << 6;

    #pragma unroll
    for (int it = 0; it < 8; ++it)
        ((int4*)WL)[it * 256 + t] = wbf[it * 256 + t];

    const unsigned short* inb = in + (size_t)b * 128 * HW + n0;
    int nl = t & 63;
    #pragma unroll
    for (int it = 0; it < 4; ++it) {
        int c8 = (t >> 6) + it * 4;
        unsigned u[8];
        #pragma unroll
        for (int j = 0; j < 8; ++j) u[j] = inb[(size_t)(c8 * 8 + j) * HW + nl];
        int4 p;
        p.x = (int)(u[0] | (u[1] << 16)); p.y = (int)(u[2] | (u[3] << 16));
        p.z = (int)(u[4] | (u[5] << 16)); p.w = (int)(u[6] | (u[7] << 16));
        ((int4*)XL)[nl * 16 + (c8 ^ (nl & 7))] = p;
    }
    __syncthreads();

    int l = t & 63, w = t >> 6, kg = l >> 4, l15 = l & 15, l7 = l15 & 7;
    f32x4 acc[2][4];
    #pragma unroll
    for (int mf = 0; mf < 2; ++mf)
        #pragma unroll
        for (int nf = 0; nf < 4; ++nf) acc[mf][nf] = (f32x4){0.f, 0.f, 0.f, 0.f};
    #pragma unroll
    for (int ks = 0; ks < 4; ++ks) {
        int ch = ks * 4 + kg;
        bf16x8 A0 = ((const bf16x8*)WL)[(w * 32 + l15) * 16 + (ch ^ l7)];
        bf16x8 A1 = ((const bf16x8*)WL)[(w * 32 + 16 + l15) * 16 + (ch ^ l7)];
        #pragma unroll
        for (int nf = 0; nf < 4; ++nf) {
            bf16x8 Bf = ((const bf16x8*)XL)[(nf * 16 + l15) * 16 + (ch ^ l7)];
            acc[0][nf] = __builtin_amdgcn_mfma_f32_16x16x32_bf16(A0, Bf, acc[0][nf], 0, 0, 0);
            acc[1][nf] = __builtin_amdgcn_mfma_f32_16x16x32_bf16(A1, Bf, acc[1][nf], 0, 0, 0);
        }
    }
    #pragma unroll
    for (int mf = 0; mf < 2; ++mf)
        #pragma unroll
        for (int nf = 0; nf < 4; ++nf)
            #pragma unroll
            for (int i = 0; i < 4; ++i) {
                int row = w * 32 + mf * 16 + kg * 4 + i;
                int col = n0 + nf * 16 + l15;
                out[((size_t)b * 128 + row) * HW + col] = f2bf(acc[mf][nf][i]);
            }
}

// ---------------------------------------------------------------------------
// depthwise 3x3 SAME, x4 vectorized, bf16 in -> bf16 out
// ---------------------------------------------------------------------------
__global__ __launch_bounds__(256)
void dwconv_k(const unsigned short* __restrict__ V, const float* __restrict__ Wdw,
              unsigned short* __restrict__ vcb)
{
    int tid = blockIdx.x * 256 + threadIdx.x;
    int e4 = tid & 4095;
    int bc = tid >> 12;
    int c = bc & 127;
    int y = e4 >> 5;
    int x0 = (e4 & 31) << 2;
    const unsigned short* vin = V + (size_t)bc * HW;
    float wf[9];
    #pragma unroll
    for (int i = 0; i < 9; ++i) wf[i] = Wdw[c * 9 + i];
    float a0 = 0.f, a1 = 0.f, a2 = 0.f, a3 = 0.f;
    #pragma unroll
    for (int dy = 0; dy < 3; ++dy) {
        int yy = y + dy - 1;
        if (yy < 0 || yy > 127) continue;
        const unsigned short* r = vin + yy * 128;
        uint2 mu = *(const uint2*)(r + x0);
        float m0 = bf2f((unsigned short)(mu.x & 0xFFFF));
        float m1 = bf2f((unsigned short)(mu.x >> 16));
        float m2 = bf2f((unsigned short)(mu.y & 0xFFFF));
        float m3 = bf2f((unsigned short)(mu.y >> 16));
        float left  = (x0 > 0)   ? bf2f(r[x0 - 1]) : 0.f;
        float right = (x0 < 124) ? bf2f(r[x0 + 4]) : 0.f;
        float w0 = wf[dy * 3], w1 = wf[dy * 3 + 1], w2 = wf[dy * 3 + 2];
        a0 += w0 * left + w1 * m0 + w2 * m1;
        a1 += w0 * m0   + w1 * m1 + w2 * m2;
        a2 += w0 * m1   + w1 * m2 + w2 * m3;
        a3 += w0 * m2   + w1 * m3 + w2 * right;
    }
    uint2 r2;
    r2.x = f2bf_pk(a0, a1);
    r2.y = f2bf_pk(a2, a3);
    *(uint2*)(vcb + (size_t)bc * HW + y * 128 + x0) = r2;
}

// ---------------------------------------------------------------------------
// MFMA Gram partials
// ---------------------------------------------------------------------------
__global__ __launch_bounds__(256)
void gram_mfma_k(const float* __restrict__ x, float* __restrict__ Gp)
{
    __shared__ short XL[128 * 128];
    int t = threadIdx.x;
    int blk = blockIdx.x;
    int b = blk >> 5, ks = blk & 31;
    const float* xb = x + (size_t)b * 128 * HW + ks * 512;
    int l = t & 63, w = t >> 6, kg = l >> 4, l15 = l & 15, l7 = l15 & 7;

    f32x4 acc[2][8];
    #pragma unroll
    for (int mf = 0; mf < 2; ++mf)
        #pragma unroll
        for (int nf = 0; nf < 8; ++nf) acc[mf][nf] = (f32x4){0.f, 0.f, 0.f, 0.f};

    for (int kc = 0; kc < 4; ++kc) {
        __syncthreads();
        #pragma unroll
        for (int it = 0; it < 8; ++it) {
            int g = it * 256 + t;
            int row = g >> 4, oct = g & 15;
            const float* p = xb + (size_t)row * HW + kc * 128 + oct * 8;
            int4 pk;
            pk.x = f2bf_pk(p[0], p[1]); pk.y = f2bf_pk(p[2], p[3]);
            pk.z = f2bf_pk(p[4], p[5]); pk.w = f2bf_pk(p[6], p[7]);
            ((int4*)XL)[row * 16 + (oct ^ (row & 7))] = pk;
        }
        __syncthreads();
        #pragma unroll
        for (int s = 0; s < 4; ++s) {
            int oct = s * 4 + kg;
            bf16x8 A0 = ((const bf16x8*)XL)[(w * 32 + l15) * 16 + (oct ^ l7)];
            bf16x8 A1 = ((const bf16x8*)XL)[(w * 32 + 16 + l15) * 16 + (oct ^ l7)];
            #pragma unroll
            for (int nf = 0; nf < 8; ++nf) {
                bf16x8 Bf = ((const bf16x8*)XL)[(nf * 16 + l15) * 16 + (oct ^ l7)];
                acc[0][nf] = __builtin_amdgcn_mfma_f32_16x16x32_bf16(A0, Bf, acc[0][nf], 0, 0, 0);
                acc[1][nf] = __builtin_amdgcn_mfma_f32_16x16x32_bf16(A1, Bf, acc[1][nf], 0, 0, 0);
            }
        }
    }
    float* gp = Gp + (size_t)blk * 16384;
    #pragma unroll
    for (int mf = 0; mf < 2; ++mf)
        #pragma unroll
        for (int nf = 0; nf < 8; ++nf)
            #pragma unroll
            for (int i = 0; i < 4; ++i) {
                int row = w * 32 + mf * 16 + kg * 4 + i;
                int col = nf * 16 + l15;
                gp[row * 128 + col] = acc[mf][nf][i];
            }
}

__global__ void gram_reduce_k(const float* __restrict__ Gp, float* __restrict__ G)
{
    int idx = blockIdx.x * 256 + threadIdx.x;
    int b = idx >> 14;
    int ij = idx & 16383;
    const float* gp = Gp + (size_t)(b * 32) * 16384 + ij;
    float s = 0.f;
    #pragma unroll
    for (int ks = 0; ks < 32; ++ks) s += gp[(size_t)ks * 16384];
    G[idx] = s;
}

// ---------------------------------------------------------------------------
// S_h = softmax( (Wq_h G Wk_h^T) * scale[h] )
// ---------------------------------------------------------------------------
__global__ __launch_bounds__(256)
void attn_s2_k(const float* __restrict__ G, const float* __restrict__ Wqkv,
               const float* __restrict__ scale, float* __restrict__ S)
{
    __shared__ float Wq[16][129];
    __shared__ float Wk[16][129];
    __shared__ float Ts[16][129];
    int bh = blockIdx.x;
    int b = bh >> 3, h = bh & 7;
    int t = threadIdx.x;
    #pragma unroll
    for (int i = 0; i < 8; ++i) {
        int idx = t + i * 256;
        int r = idx >> 7, ci = idx & 127;
        Wq[r][ci] = Wqkv[(size_t)(h * 16 + r) * 128 + ci];
        Wk[r][ci] = Wqkv[(size_t)(128 + h * 16 + r) * 128 + ci];
    }
    __syncthreads();
    const float* Gb = G + (size_t)b * 16384;
    #pragma unroll
    for (int i = 0; i < 8; ++i) {
        int idx = t + i * 256;
        int c = idx >> 7, col = idx & 127;
        float s = 0.f;
        #pragma unroll 8
        for (int ci = 0; ci < 128; ++ci)
            s += Wq[c][ci] * Gb[ci * 128 + col];
        Ts[c][col] = s;
    }
    __syncthreads();
    int c = t >> 4, d = t & 15;
    float s = 0.f;
    #pragma unroll 8
    for (int col = 0; col < 128; ++col)
        s += Ts[c][col] * Wk[d][col];
    s *= scale[h];
    float m = s;
    #pragma unroll
    for (int w = 1; w < 16; w <<= 1)
        m = fmaxf(m, __shfl_xor(m, w, 64));
    float e = expf(s - m);
    float sum = e;
    #pragma unroll
    for (int w = 1; w < 16; w <<= 1)
        sum += __shfl_xor(sum, w, 64);
    S[(size_t)bh * 256 + t] = e / sum;
}

// ---------------------------------------------------------------------------
// proj_s with fused PV
// ---------------------------------------------------------------------------
__global__ __launch_bounds__(256)
void proj_s_pv_k(const unsigned short* __restrict__ V,
                 const unsigned short* __restrict__ vcb,
                 const float* __restrict__ S, const int4* __restrict__ wbf,
                 unsigned short* __restrict__ out_s)
{
    __shared__ short WL[128 * 128];
    __shared__ short XL[64 * 128];
    __shared__ float SL[2048];
    int t = threadIdx.x;
    int gb = blockIdx.x;
    int b = gb >> 8;
    int n0 = (gb & 255) << 6;

    #pragma unroll
    for (int it = 0; it < 8; ++it)
        ((int4*)WL)[it * 256 + t] = wbf[it * 256 + t];
    #pragma unroll
    for (int i = 0; i < 8; ++i)
        SL[i * 256 + t] = S[(size_t)b * 2048 + i * 256 + t];
    __syncthreads();

    int col = t & 63, w = t >> 6;
    #pragma unroll
    for (int hh = 0; hh < 2; ++hh) {
        int h = w * 2 + hh;
        float v[16];
        #pragma unroll
        for (int d = 0; d < 16; ++d)
            v[d] = bf2f(V[((size_t)(b * 128 + h * 16 + d)) * HW + n0 + col]);
        float o[16];
        #pragma unroll
        for (int c = 0; c < 16; ++c) {
            const float* sl = SL + h * 256 + c * 16;
            float s = 0.f;
            #pragma unroll
            for (int d = 0; d < 16; ++d) s += sl[d] * v[d];
            o[c] = s + bf2f(vcb[((size_t)(b * 128 + h * 16 + c)) * HW + n0 + col]);
        }
        #pragma unroll
        for (int oc = 0; oc < 2; ++oc) {
            int octet = h * 2 + oc;
            int4 p;
            p.x = f2bf_pk(o[oc * 8 + 0], o[oc * 8 + 1]);
            p.y = f2bf_pk(o[oc * 8 + 2], o[oc * 8 + 3]);
            p.z = f2bf_pk(o[oc * 8 + 4], o[oc * 8 + 5]);
            p.w = f2bf_pk(o[oc * 8 + 6], o[oc * 8 + 7]);
            ((int4*)XL)[col * 16 + (octet ^ (col & 7))] = p;
        }
    }
    __syncthreads();

    int l = t & 63, kg = l >> 4, l15 = l & 15, l7 = l15 & 7;
    f32x4 acc[2][4];
    #pragma unroll
    for (int mf = 0; mf < 2; ++mf)
        #pragma unroll
        for (int nf = 0; nf < 4; ++nf) acc[mf][nf] = (f32x4){0.f, 0.f, 0.f, 0.f};
    #pragma unroll
    for (int ks = 0; ks < 4; ++ks) {
        int ch = ks * 4 + kg;
        bf16x8 A0 = ((const bf16x8*)WL)[(w * 32 + l15) * 16 + (ch ^ l7)];
        bf16x8 A1 = ((const bf16x8*)WL)[(w * 32 + 16 + l15) * 16 + (ch ^ l7)];
        #pragma unroll
        for (int nf = 0; nf < 4; ++nf) {
            bf16x8 Bf = ((const bf16x8*)XL)[(nf * 16 + l15) * 16 + (ch ^ l7)];
            acc[0][nf] = __builtin_amdgcn_mfma_f32_16x16x32_bf16(A0, Bf, acc[0][nf], 0, 0, 0);
            acc[1][nf] = __builtin_amdgcn_mfma_f32_16x16x32_bf16(A1, Bf, acc[1][nf], 0, 0, 0);
        }
    }
    #pragma unroll
    for (int mf = 0; mf < 2; ++mf)
        #pragma unroll
        for (int nf = 0; nf < 4; ++nf)
            #pragma unroll
            for (int i = 0; i < 4; ++i) {
                int row = w * 32 + mf * 16 + kg * 4 + i;
                int colg = n0 + nf * 16 + l15;
                out_s[((size_t)b * 128 + row) * HW + colg] = f2bf(acc[mf][nf][i]);
            }
}

// ---------------------------------------------------------------------------
// fused ff1 (GELU) + ff2
// ---------------------------------------------------------------------------
__global__ __launch_bounds__(256)
void ff_fused_k(const float* __restrict__ x, const int4* __restrict__ w1bf,
                const int4* __restrict__ w2bf, unsigned short* __restrict__ outp)
{
    __shared__ short WL[128 * 128];
    __shared__ short XL[64 * 128];
    int t = threadIdx.x;
    int gb = blockIdx.x;
    int b = gb >> 8;
    int n0 = (gb & 255) << 6;

    #pragma unroll
    for (int it = 0; it < 8; ++it)
        ((int4*)WL)[it * 256 + t] = w1bf[it * 256 + t];

    const float* inb = x + (size_t)b * 128 * HW + n0;
    int nl = t & 63;
    #pragma unroll
    for (int it = 0; it < 4; ++it) {
        int c8 = (t >> 6) + it * 4;
        float v[8];
        #pragma unroll
        for (int j = 0; j < 8; ++j) v[j] = inb[(size_t)(c8 * 8 + j) * HW + nl];
        int4 p;
        p.x = f2bf_pk(v[0], v[1]); p.y = f2bf_pk(v[2], v[3]);
        p.z = f2bf_pk(v[4], v[5]); p.w = f2bf_pk(v[6], v[7]);
        ((int4*)XL)[nl * 16 + (c8 ^ (nl & 7))] = p;
    }
    __syncthreads();

    int l = t & 63, w = t >> 6, kg = l >> 4, l15 = l & 15, l7 = l15 & 7;
    f32x4 acc[2][4];
    #pragma unroll
    for (int mf = 0; mf < 2; ++mf)
        #pragma unroll
        for (int nf = 0; nf < 4; ++nf) acc[mf][nf] = (f32x4){0.f, 0.f, 0.f, 0.f};
    #pragma unroll
    for (int ks = 0; ks < 4; ++ks) {
        int ch = ks * 4 + kg;
        bf16x8 A0 = ((const bf16x8*)WL)[(w * 32 + l15) * 16 + (ch ^ l7)];
        bf16x8 A1 = ((const bf16x8*)WL)[(w * 32 + 16 + l15) * 16 + (ch ^ l7)];
        #pragma unroll
        for (int nf = 0; nf < 4; ++nf) {
            bf16x8 Bf = ((const bf16x8*)XL)[(nf * 16 + l15) * 16 + (ch ^ l7)];
            acc[0][nf] = __builtin_amdgcn_mfma_f32_16x16x32_bf16(A0, Bf, acc[0][nf], 0, 0, 0);
            acc[1][nf] = __builtin_amdgcn_mfma_f32_16x16x32_bf16(A1, Bf, acc[1][nf], 0, 0, 0);
        }
    }
    __syncthreads();

    #pragma unroll
    for (int it = 0; it < 8; ++it)
        ((int4*)WL)[it * 256 + t] = w2bf[it * 256 + t];
    #pragma unroll
    for (int mf = 0; mf < 2; ++mf)
        #pragma unroll
        for (int nf = 0; nf < 4; ++nf) {
            float g4[4];
            #pragma unroll
            for (int i = 0; i < 4; ++i) {
                float v = acc[mf][nf][i];
                g4[i] = 0.5f * v * (1.0f + erff(v * 0.70710678118654752f));
            }
            int col = nf * 16 + l15;
            int r0 = w * 32 + mf * 16 + kg * 4;
            int octet = r0 >> 3;
            uint2 pk2;
            pk2.x = f2bf_pk(g4[0], g4[1]);
            pk2.y = f2bf_pk(g4[2], g4[3]);
            ((uint2*)XL)[(col * 16 + (octet ^ (col & 7))) * 2 + (kg & 1)] = pk2;
        }
    __syncthreads();

    f32x4 acc2[2][4];
    #pragma unroll
    for (int mf = 0; mf < 2; ++mf)
        #pragma unroll
        for (int nf = 0; nf < 4; ++nf) acc2[mf][nf] = (f32x4){0.f, 0.f, 0.f, 0.f};
    #pragma unroll
    for (int ks = 0; ks < 4; ++ks) {
        int ch = ks * 4 + kg;
        bf16x8 A0 = ((const bf16x8*)WL)[(w * 32 + l15) * 16 + (ch ^ l7)];
        bf16x8 A1 = ((const bf16x8*)WL)[(w * 32 + 16 + l15) * 16 + (ch ^ l7)];
        #pragma unroll
        for (int nf = 0; nf < 4; ++nf) {
            bf16x8 Bf = ((const bf16x8*)XL)[(nf * 16 + l15) * 16 + (ch ^ l7)];
            acc2[0][nf] = __builtin_amdgcn_mfma_f32_16x16x32_bf16(A0, Bf, acc2[0][nf], 0, 0, 0);
            acc2[1][nf] = __builtin_amdgcn_mfma_f32_16x16x32_bf16(A1, Bf, acc2[1][nf], 0, 0, 0);
        }
    }
    #pragma unroll
    for (int mf = 0; mf < 2; ++mf)
        #pragma unroll
        for (int nf = 0; nf < 4; ++nf)
            #pragma unroll
            for (int i = 0; i < 4; ++i) {
                int row = w * 32 + mf * 16 + kg * 4 + i;
                int col = n0 + nf * 16 + l15;
                outp[((size_t)b * 128 + row) * HW + col] = f2bf(acc2[mf][nf][i]);
            }
}

// ---------------------------------------------------------------------------
// fused gates + final
// ---------------------------------------------------------------------------
__global__ __launch_bounds__(256)
void fuse2_k(const float* __restrict__ x, const unsigned short* __restrict__ outs,
             const unsigned short* __restrict__ outf,
             const int4* __restrict__ wgsf_bf, const float* __restrict__ bgsf,
             const int4* __restrict__ wgfs_bf, const float* __restrict__ bgfs,
             float* __restrict__ out)
{
    __shared__ short WS[64 * 128];
    __shared__ short WF[64 * 128];
    __shared__ short XS[64 * 128];
    __shared__ short XF[64 * 128];
    int t = threadIdx.x;
    int gb = blockIdx.x;
    int half = gb & 1;
    int nt = (gb >> 1) & 255;
    int b = gb >> 9;
    int n0 = nt << 6;

    #pragma unroll
    for (int it = 0; it < 4; ++it) {
        ((int4*)WS)[it * 256 + t] = wgsf_bf[half * 1024 + it * 256 + t];
        ((int4*)WF)[it * 256 + t] = wgfs_bf[half * 1024 + it * 256 + t];
    }
    const unsigned short* sb = outs + (size_t)b * 128 * HW + n0;
    const unsigned short* fb = outf + (size_t)b * 128 * HW + n0;
    int nl = t & 63;
    #pragma unroll
    for (int it = 0; it < 4; ++it) {
        int c8 = (t >> 6) + it * 4;
        unsigned us[8], uf[8];
        #pragma unroll
        for (int j = 0; j < 8; ++j) {
            size_t a = (size_t)(c8 * 8 + j) * HW + nl;
            us[j] = sb[a];
            uf[j] = fb[a];
        }
        int4 ps, pf;
        ps.x = (int)(us[0] | (us[1] << 16)); ps.y = (int)(us[2] | (us[3] << 16));
        ps.z = (int)(us[4] | (us[5] << 16)); ps.w = (int)(us[6] | (us[7] << 16));
        pf.x = (int)(uf[0] | (uf[1] << 16)); pf.y = (int)(uf[2] | (uf[3] << 16));
        pf.z = (int)(uf[4] | (uf[5] << 16)); pf.w = (int)(uf[6] | (uf[7] << 16));
        ((int4*)XS)[nl * 16 + (c8 ^ (nl & 7))] = ps;
        ((int4*)XF)[nl * 16 + (c8 ^ (nl & 7))] = pf;
    }
    __syncthreads();

    int l = t & 63, w = t >> 6, kg = l >> 4, l15 = l & 15, l7 = l15 & 7;
    f32x4 aS[4], aF[4];
    #pragma unroll
    for (int nf = 0; nf < 4; ++nf) {
        aS[nf] = (f32x4){0.f, 0.f, 0.f, 0.f};
        aF[nf] = (f32x4){0.f, 0.f, 0.f, 0.f};
    }
    #pragma unroll
    for (int ks = 0; ks < 4; ++ks) {
        int ch = ks * 4 + kg;
        bf16x8 As = ((const bf16x8*)WS)[(w * 16 + l15) * 16 + (ch ^ l7)];
        bf16x8 Af = ((const bf16x8*)WF)[(w * 16 + l15) * 16 + (ch ^ l7)];
        #pragma unroll
        for (int nf = 0; nf < 4; ++nf) {
            bf16x8 Bs = ((const bf16x8*)XS)[(nf * 16 + l15) * 16 + (ch ^ l7)];
            bf16x8 Bf = ((const bf16x8*)XF)[(nf * 16 + l15) * 16 + (ch ^ l7)];
            aS[nf] = __builtin_amdgcn_mfma_f32_16x16x32_bf16(As, Bs, aS[nf], 0, 0, 0);
            aF[nf] = __builtin_amdgcn_mfma_f32_16x16x32_bf16(Af, Bf, aF[nf], 0, 0, 0);
        }
    }
    #pragma unroll
    for (int nf = 0; nf < 4; ++nf)
        #pragma unroll
        for (int i = 0; i < 4; ++i) {
            int row = half * 64 + w * 16 + kg * 4 + i;
            int cc = nf * 16 + l15;
            float gf = sigmoidf_(aS[nf][i] + bgsf[row]);
            float gs = sigmoidf_(aF[nf][i] + bgfs[row]);
            size_t gi = ((size_t)(b * 128) + row) * HW + n0 + cc;
            float os = bf2f(outs[gi]);
            float of = bf2f(outf[gi]);
            out[gi] = x[gi] + os * gs + of * gf;
        }
}

// ---------------------------------------------------------------------------
// Fully-fused per-channel 2D FFT filter. Z = complex bf16 [128][128] in LDS.
// Swizzle: ZIX(r,j). Each 128-pt line owned by 8 threads of one wave
// (register 16x8 Cooley-Tukey, natural order). Inverse folded as
// conj-at-product + Re-at-end.
// ---------------------------------------------------------------------------
__device__ __forceinline__ int ZIX(int r, int j)
{
    return r * 128 + (j ^ ((r & 3) << 3) ^ (((j >> 4) & 3) << 1));
}
__device__ __forceinline__ float2 zld(const unsigned* Z, int r, int j)
{
    unsigned z = Z[ZIX(r, j)];
    return make_float2(bf2f((unsigned short)(z & 0xFFFF)),
                       bf2f((unsigned short)(z >> 16)));
}
__device__ __forceinline__ void zst(unsigned* Z, int r, int j, float2 v)
{
    Z[ZIX(r, j)] = f2bf_pk(v.x, v.y);
}

__device__ __forceinline__ void dft16(float2* v)
{
    const float C1 = 0.92387953251f, S1 = 0.38268343236f, R2 = 0.70710678119f;
    const float2 W16[8] = {
        {1.f, 0.f}, {C1, -S1}, {R2, -R2}, {S1, -C1},
        {0.f, -1.f}, {-S1, -C1}, {-R2, -R2}, {-C1, -S1}};
    #pragma unroll
    for (int i = 0; i < 8; ++i) {
        float2 a = v[i], b = v[i + 8];
        v[i] = make_float2(a.x + b.x, a.y + b.y);
        float2 d = make_float2(a.x - b.x, a.y - b.y);
        v[i + 8] = cmul(d, W16[i]);
    }
    #pragma unroll
    for (int blk = 0; blk < 16; blk += 8)
        #pragma unroll
        for (int i = 0; i < 4; ++i) {
            float2 a = v[blk + i], b = v[blk + i + 4];
            v[blk + i] = make_float2(a.x + b.x, a.y + b.y);
            float2 d = make_float2(a.x - b.x, a.y - b.y);
            v[blk + i + 4] = cmul(d, W16[2 * i]);
        }
    #pragma unroll
    for (int blk = 0; blk < 16; blk += 4) {
        float2 a0 = v[blk], b0 = v[blk + 2];
        v[blk] = make_float2(a0.x + b0.x, a0.y + b0.y);
        v[blk + 2] = make_float2(a0.x - b0.x, a0.y - b0.y);
        float2 a1 = v[blk + 1], b1 = v[blk + 3];
        v[blk + 1] = make_float2(a1.x + b1.x, a1.y + b1.y);
        float2 d = make_float2(a1.x - b1.x, a1.y - b1.y);
        v[blk + 3] = make_float2(d.y, -d.x);          // * (0,-1)
    }
    #pragma unroll
    for (int blk = 0; blk < 16; blk += 2) {
        float2 a = v[blk], b = v[blk + 1];
        v[blk] = make_float2(a.x + b.x, a.y + b.y);
        v[blk + 1] = make_float2(a.x - b.x, a.y - b.y);
    }
}

__device__ __forceinline__ void dft8(float2* v)
{
    const float R2 = 0.70710678119f;
    const float2 W8[4] = {{1.f, 0.f}, {R2, -R2}, {0.f, -1.f}, {-R2, -R2}};
    #pragma unroll
    for (int i = 0; i < 4; ++i) {
        float2 a = v[i], b = v[i + 4];
        v[i] = make_float2(a.x + b.x, a.y + b.y);
        float2 d = make_float2(a.x - b.x, a.y - b.y);
        v[i + 4] = cmul(d, W8[i]);
    }
    #pragma unroll
    for (int blk = 0; blk < 8; blk += 4) {
        float2 a0 = v[blk], b0 = v[blk + 2];
        v[blk] = make_float2(a0.x + b0.x, a0.y + b0.y);
        v[blk + 2] = make_float2(a0.x - b0.x, a0.y - b0.y);
        float2 a1 = v[blk + 1], b1 = v[blk + 3];
        v[blk + 1] = make_float2(a1.x + b1.x, a1.y + b1.y);
        float2 d = make_float2(a1.x - b1.x, a1.y - b1.y);
        v[blk + 3] = make_float2(d.y, -d.x);
    }
    #pragma unroll
    for (int blk = 0; blk < 8; blk += 2) {
        float2 a = v[blk], b = v[blk + 1];
        v[blk] = make_float2(a.x + b.x, a.y + b.y);
        v[blk + 1] = make_float2(a.x - b.x, a.y - b.y);
    }
}

// FFT-128 along j for one row; thread owns n2 (with 7 siblings in same wave).
__device__ __forceinline__ void fft_line_row(unsigned* Z, const float2* tw,
                                             int row, int n2)
{
    const int BREV4[16] = {0,8,4,12,2,10,6,14,1,9,5,13,3,11,7,15};
    const int BREV3[8] = {0,4,2,6,1,5,3,7};
    float2 v[16];
    #pragma unroll
    for (int n1 = 0; n1 < 16; ++n1) v[n1] = zld(Z, row, 8 * n1 + n2);
    dft16(v);
    #pragma unroll
    for (int p = 0; p < 16; ++p) {
        int k1 = BREV4[p];
        zst(Z, row, 16 * n2 + k1, cmul(v[p], tw[n2 * k1]));
    }
    float2 wa[8], wb[8];
    #pragma unroll
    for (int m = 0; m < 8; ++m) {
        wa[m] = zld(Z, row, 16 * m + n2);
        wb[m] = zld(Z, row, 16 * m + n2 + 8);
    }
    dft8(wa);
    dft8(wb);
    #pragma unroll
    for (int p = 0; p < 8; ++p) {
        zst(Z, row, n2 + 16 * BREV3[p], wa[p]);
        zst(Z, row, n2 + 8 + 16 * BREV3[p], wb[p]);
    }
}

// FFT-128 along r for one column.
__device__ __forceinline__ void fft_line_col(unsigned* Z, const float2* tw,
                                             int col, int n2)
{
    const int BREV4[16] = {0,8,4,12,2,10,6,14,1,9,5,13,3,11,7,15};
    const int BREV3[8] = {0,4,2,6,1,5,3,7};
    float2 v[16];
    #pragma unroll
    for (int n1 = 0; n1 < 16; ++n1) v[n1] = zld(Z, 8 * n1 + n2, col);
    dft16(v);
    #pragma unroll
    for (int p = 0; p < 16; ++p) {
        int k1 = BREV4[p];
        zst(Z, 16 * n2 + k1, col, cmul(v[p], tw[n2 * k1]));
    }
    float2 wa[8], wb[8];
    #pragma unroll
    for (int m = 0; m < 8; ++m) {
        wa[m] = zld(Z, 16 * m + n2, col);
        wb[m] = zld(Z, 16 * m + n2 + 8, col);
    }
    dft8(wa);
    dft8(wb);
    #pragma unroll
    for (int p = 0; p < 8; ++p) {
        zst(Z, n2 + 16 * BREV3[p], col, wa[p]);
        zst(Z, n2 + 8 + 16 * BREV3[p], col, wb[p]);
    }
}

__global__ __launch_bounds__(256)
void fft_all_k(const float* __restrict__ x, const unsigned short* __restrict__ sw,
               unsigned short* __restrict__ outp)
{
    __shared__ unsigned Z[128 * 128];   // 64 KB complex bf16
    __shared__ float2 tw[128];
    const int BREV3[8] = {0,4,2,6,1,5,3,7};
    int t = threadIdx.x;
    if (t < 128) {
        float sn, cs;
        sincosf(0.049087385212340519f * (float)t, &sn, &cs);
        tw[t] = make_float2(cs, -sn);
    }
    size_t base = (size_t)blockIdx.x * HW;

    // stage: Z = x + i*sw
    for (int i = 0; i < 64; ++i) {
        int idx = t + i * 256;
        int r = idx >> 7, j = idx & 127;
        Z[ZIX(r, j)] = f2bf_pk(x[base + idx], bf2f(sw[base + idx]));
    }
    __syncthreads();

    int ln = t >> 3, n2 = t & 7;
    // forward over w (rows), then over h (cols)
    #pragma unroll
    for (int it = 0; it < 4; ++it) fft_line_row(Z, tw, it * 32 + ln, n2);
    __syncthreads();
    #pragma unroll
    for (int it = 0; it < 4; ++it) fft_line_col(Z, tw, it * 32 + ln, n2);
    __syncthreads();

    // Hermitian split + product; store conj(Y) at (kh,kw), Y at pair
    for (int item = t; item < 8194; item += 256) {
        int rA, kA, rB, kB;
        if (item < 8064) {
            rA = 1 + (item >> 7); kA = item & 127;
            rB = 128 - rA; kB = (128 - kA) & 127;
        } else {
            int it2 = item - 8064;
            rA = rB = (it2 < 65) ? 0 : 64;
            kA = (it2 < 65) ? it2 : (it2 - 65);
            kB = (128 - kA) & 127;
        }
        float2 z1 = zld(Z, rA, kA);
        float2 z2 = zld(Z, rB, kB);
        float2 X = make_float2(0.5f * (z1.x + z2.x), 0.5f * (z1.y - z2.y));
        float Dx = z1.x - z2.x, Dy = z1.y + z2.y;
        float2 Wf = make_float2(0.5f * Dy, -0.5f * Dx);
        float2 Y = cmul(X, Wf);
        zst(Z, rA, kA, make_float2(Y.x, -Y.y));   // conj(Y)
        zst(Z, rB, kB, Y);                         // conj at pair
    }
    __syncthreads();

    // "inverse" = forward on conjugated spectrum; Re at the end
    #pragma unroll
    for (int it = 0; it < 4; ++it) fft_line_col(Z, tw, it * 32 + ln, n2);
    __syncthreads();

    const float scale = 1.f / 2097152.f;   // 1/(128^3)
    const int BREV4[16] = {0,8,4,12,2,10,6,14,1,9,5,13,3,11,7,15};
    #pragma unroll
    for (int it = 0; it < 4; ++it) {
        int row = it * 32 + ln;
        float2 v[16];
        #pragma unroll
        for (int n1 = 0; n1 < 16; ++n1) v[n1] = zld(Z, row, 8 * n1 + n2);
        dft16(v);
        #pragma unroll
        for (int p = 0; p < 16; ++p) {
            int k1 = BREV4[p];
            zst(Z, row, 16 * n2 + k1, cmul(v[p], tw[n2 * k1]));
        }
        float2 wa[8], wb[8];
        #pragma unroll
        for (int m = 0; m < 8; ++m) {
            wa[m] = zld(Z, row, 16 * m + n2);
            wb[m] = zld(Z, row, 16 * m + n2 + 8);
        }
        dft8(wa);
        dft8(wb);
        #pragma unroll
        for (int p = 0; p < 8; ++p) {
            outp[base + row * 128 + n2 + 16 * BREV3[p]] = f2bf(wa[p].x * scale);
            outp[base + row * 128 + n2 + 8 + 16 * BREV3[p]] = f2bf(wb[p].x * scale);
        }
    }
}

// ---------------------------------------------------------------------------
// Workspace plan (128 MiB ws + d_out scratch):
//  ws[0,32):  V bf16 (phase A) -> out_f bf16 (phase B)
//  ws[32,64): out_s bf16
//  ws[64,96): swb bf16 -> pre bf16 (per-channel self-alias inside fft_all_k)
//  ws[96,96.25): Wbf 7x32KB pre-swizzled bf16 weights
//  d_out: vcb bf16 [0,32) / Gp [32,48) / G,S (phase A); final output (fuse2).
// ---------------------------------------------------------------------------
extern "C" void kernel_launch(void* const* d_in, const int* in_sizes, int n_in,
                              void* d_out, int out_size, void* d_ws, size_t ws_size,
                              hipStream_t stream)
{
    const float* x        = (const float*)d_in[0];
    const float* W_qkv    = (const float*)d_in[1];
    const float* W_dw     = (const float*)d_in[2];
    const float* W_proj_s = (const float*)d_in[3];
    const float* scale_s  = (const float*)d_in[4];
    const float* W_ff1    = (const float*)d_in[5];
    const float* W_ff2    = (const float*)d_in[6];
    const float* W_proj_f = (const float*)d_in[7];
    const float* W_gsf    = (const float*)d_in[8];
    const float* b_gsf    = (const float*)d_in[9];
    const float* W_gfs    = (const float*)d_in[10];
    const float* b_gfs    = (const float*)d_in[11];
    float* out = (float*)d_out;

    char* ws = (char*)d_ws;
    const size_t MB32 = 33554432ull;
    const size_t MB64 = 67108864ull;
    const size_t MB96 = 100663296ull;
    unsigned short* V     = (unsigned short*)(ws);          // 32 MiB phase A
    unsigned short* out_s = (unsigned short*)(ws + MB32);   // 32 MiB
    unsigned short* swb   = (unsigned short*)(ws + MB64);   // 32 MiB bf16
    unsigned short* pre   = (unsigned short*)(ws + MB64);   // aliases swb (safe)
    unsigned short* out_fp= (unsigned short*)(ws);          // 32 MiB (V dead)
    int4* Wbf4            = (int4*)(ws + MB96);             // 224 KiB
    unsigned short* vcb   = (unsigned short*)out;           // 32 MiB d_out lo
    float* Gp  = out + 8388608;                             // 16 MiB
    float* G   = out + 8388608 + 4194304;                   // 512 KiB
    float* S   = G + 131072;                                // 64 KiB

    // slices: 0=W_v 1=W_proj_s 2=W_ff1 3=W_ff2 4=W_proj_f 5=W_gsf 6=W_gfs
    wprep_k<<<56, 256, 0, stream>>>(W_qkv + 256 * 128, W_proj_s, W_ff1, W_ff2,
                                    W_proj_f, W_gsf, W_gfs, Wbf4);

    // --- spatial attention branch ---
    conv_mfma_k<<<2048, 256, 0, stream>>>(x, Wbf4 + 0 * 2048, V);
    dwconv_k<<<16384, 256, 0, stream>>>(V, W_dw, vcb);
    gram_mfma_k<<<256, 256, 0, stream>>>(x, Gp);
    gram_reduce_k<<<512, 256, 0, stream>>>(Gp, G);
    attn_s2_k<<<64, 256, 0, stream>>>(G, W_qkv, scale_s, S);
    proj_s_pv_k<<<2048, 256, 0, stream>>>(V, vcb, S, Wbf4 + 1 * 2048, out_s);

    // --- frequency branch: ff -> single fused 2D-FFT filter -> proj_f ---
    ff_fused_k<<<2048, 256, 0, stream>>>(x, Wbf4 + 2 * 2048, Wbf4 + 3 * 2048, swb);
    fft_all_k<<<1024, 256, 0, stream>>>(x, swb, pre);
    conv_mfma_bf_k<<<2048, 256, 0, stream>>>(pre, Wbf4 + 4 * 2048, out_fp);

    // --- fused gates + final output ---
    fuse2_k<<<4096, 256, 0, stream>>>(x, out_s, out_fp,
                                      Wbf4 + 5 * 2048, b_gsf,
                                      Wbf4 + 6 * 2048, b_gfs, out);
}